// Round 1
// baseline (1314.652 us; speedup 1.0000x reference)
//
#include <hip/hip_runtime.h>
#include <hip/hip_bf16.h>

// ---- problem constants ----
#define BB      2
#define LSEQ    2048
#define DMODEL  1024
#define DSTATE  128
#define DCONV   4
#define HEADDIM 64
#define DINNER  2048      // EXP*DMODEL
#define NHEADS  32        // DINNER/HEADDIM
#define CONVD   2304      // DINNER + 2*DSTATE
#define DINP    4384      // 2*DINNER + 2*DSTATE + NHEADS
#define CHUNK   256
#define NCH     8         // LSEQ/CHUNK
#define NROWS   4096      // BB*LSEQ
#define EPSF    1e-5f

// ============================================================
// RMSNorm: one block per row, D = 1024 or 2048 (in-place safe)
// ============================================================
__global__ __launch_bounds__(256) void rmsnorm_kernel(
    const float* __restrict__ in, const float* __restrict__ w,
    float* __restrict__ out, int D)
{
    int row = blockIdx.x;
    const float* xr = in + (long)row * D;
    int nv = D >> 10;              // 1 (D=1024) or 2 (D=2048)
    float4 vals[2];
    float ss = 0.f;
    for (int i = 0; i < nv; ++i) {
        vals[i] = *(const float4*)(xr + (threadIdx.x + i * 256) * 4);
        ss += vals[i].x*vals[i].x + vals[i].y*vals[i].y
            + vals[i].z*vals[i].z + vals[i].w*vals[i].w;
    }
    for (int off = 32; off; off >>= 1) ss += __shfl_down(ss, off, 64);
    __shared__ float red[4];
    if ((threadIdx.x & 63) == 0) red[threadIdx.x >> 6] = ss;
    __syncthreads();
    float tot = red[0] + red[1] + red[2] + red[3];
    float scale = rsqrtf(tot / (float)D + EPSF);
    float* orow = out + (long)row * D;
    for (int i = 0; i < nv; ++i) {
        int base = (threadIdx.x + i * 256) * 4;
        float4 v = vals[i];
        float4 wv = *(const float4*)(w + base);
        v.x *= scale * wv.x; v.y *= scale * wv.y;
        v.z *= scale * wv.z; v.w *= scale * wv.w;
        *(float4*)(orow + base) = v;
    }
}

// ============================================================
// Generic fp32 NT GEMM: C[m,n] = sum_k A[m,k]*W[n,k] (+resid)
// 128x128 tile, BK=16, 256 threads, 8x8 per thread, batched.
// K must be a multiple of 16 (true for 1024/2048/128).
// ============================================================
__global__ __launch_bounds__(256) void gemm_nt_kernel(
    const float* __restrict__ A, int lda, long sA,
    const float* __restrict__ W, int ldw, long sW,
    float* __restrict__ C, int ldc, long sC,
    const float* __restrict__ resid, int ldr,
    int M, int N, int K)
{
    __shared__ float As[16][132];   // [k][row], stride 132 keeps f4 align + no conflicts
    __shared__ float Ws[16][132];
    const int t = threadIdx.x;
    const int tx = t & 15, ty = t >> 4;
    A += (long)blockIdx.z * sA;
    W += (long)blockIdx.z * sW;
    C += (long)blockIdx.z * sC;
    int m0 = blockIdx.y * 128, n0 = blockIdx.x * 128;
    float acc[8][8];
#pragma unroll
    for (int i = 0; i < 8; ++i)
#pragma unroll
        for (int j = 0; j < 8; ++j) acc[i][j] = 0.f;

    for (int k0 = 0; k0 < K; k0 += 16) {
#pragma unroll
        for (int u = 0; u < 2; ++u) {
            int idx = t + u * 256;
            int row = idx >> 2, seg = idx & 3;
            int gk = k0 + seg * 4;
            float4 va = make_float4(0.f, 0.f, 0.f, 0.f);
            int gr = m0 + row;
            if (gr < M) va = *(const float4*)(A + (long)gr * lda + gk);
            As[seg*4+0][row] = va.x; As[seg*4+1][row] = va.y;
            As[seg*4+2][row] = va.z; As[seg*4+3][row] = va.w;
            float4 vw = make_float4(0.f, 0.f, 0.f, 0.f);
            int gc = n0 + row;
            if (gc < N) vw = *(const float4*)(W + (long)gc * ldw + gk);
            Ws[seg*4+0][row] = vw.x; Ws[seg*4+1][row] = vw.y;
            Ws[seg*4+2][row] = vw.z; Ws[seg*4+3][row] = vw.w;
        }
        __syncthreads();
#pragma unroll
        for (int kk = 0; kk < 16; ++kk) {
            float a[8], b[8];
            *(float4*)&a[0] = *(const float4*)&As[kk][ty * 8];
            *(float4*)&a[4] = *(const float4*)&As[kk][ty * 8 + 4];
            *(float4*)&b[0] = *(const float4*)&Ws[kk][tx * 8];
            *(float4*)&b[4] = *(const float4*)&Ws[kk][tx * 8 + 4];
#pragma unroll
            for (int i = 0; i < 8; ++i)
#pragma unroll
                for (int j = 0; j < 8; ++j)
                    acc[i][j] += a[i] * b[j];
        }
        __syncthreads();
    }
#pragma unroll
    for (int i = 0; i < 8; ++i) {
        int gr = m0 + ty * 8 + i;
        if (gr >= M) continue;
#pragma unroll
        for (int jq = 0; jq < 2; ++jq) {
            int gc = n0 + tx * 8 + jq * 4;
            if (gc + 3 < N) {
                float4 o;
                o.x = acc[i][jq*4+0]; o.y = acc[i][jq*4+1];
                o.z = acc[i][jq*4+2]; o.w = acc[i][jq*4+3];
                if (resid) {
                    float4 r = *(const float4*)(resid + (long)gr * ldr + gc);
                    o.x += r.x; o.y += r.y; o.z += r.z; o.w += r.w;
                }
                *(float4*)(C + (long)gr * ldc + gc) = o;
            }
        }
    }
}

// ============================================================
// Depthwise causal conv (width 4) + SiLU on the xBC slice
// ============================================================
__global__ __launch_bounds__(256) void conv_silu_kernel(
    const float* __restrict__ zx, const float* __restrict__ cw,
    const float* __restrict__ cb, float* __restrict__ xBCc)
{
    int row = blockIdx.x;                      // 0..4095
    int c = blockIdx.y * 256 + threadIdx.x;    // 0..2303
    int l = row & (LSEQ - 1);
    float acc = cb[c];
#pragma unroll
    for (int k = 0; k < DCONV; ++k) {
        int ls = l + k - (DCONV - 1);
        if (ls >= 0)
            acc += zx[(long)(row + k - (DCONV - 1)) * DINP + DINNER + c] * cw[c * DCONV + k];
    }
    xBCc[(long)row * CONVD + c] = acc / (1.f + __expf(-acc));
}

// ============================================================
// dt = softplus(dt_raw + dt_bias)
// ============================================================
__global__ __launch_bounds__(256) void dt_kernel(
    const float* __restrict__ zx, const float* __restrict__ dt_bias,
    float* __restrict__ dtv)
{
    int idx = blockIdx.x * 256 + threadIdx.x;  // < NROWS*NHEADS
    int row = idx >> 5, h = idx & 31;
    float v = zx[(long)row * DINP + (DINP - NHEADS) + h] + dt_bias[h];
    float sp = (v > 20.f) ? v : log1pf(__expf(v));
    dtv[idx] = sp;
}

// ============================================================
// Per-chunk inclusive cumsum of dA = -dt*exp(A_log); block = (bc,h)
// ============================================================
__global__ __launch_bounds__(256) void acs_kernel(
    const float* __restrict__ dtv, const float* __restrict__ A_log,
    float* __restrict__ Acs)
{
    int bc = blockIdx.x, h = blockIdx.y;
    int l = threadIdx.x;
    int row = bc * CHUNK + l;
    float a = -dtv[row * NHEADS + h] * __expf(A_log[h]);
    __shared__ float buf[2][CHUNK];
    buf[0][l] = a; __syncthreads();
    int src = 0;
    for (int off = 1; off < CHUNK; off <<= 1) {
        float v = buf[src][l];
        if (l >= off) v += buf[src][l - off];
        buf[src ^ 1][l] = v;
        __syncthreads();
        src ^= 1;
    }
    Acs[(bc * NHEADS + h) * CHUNK + l] = buf[src][l];
}

// ============================================================
// Chunk states: state[bc][h][n][p] = sum_l B[l,n]*exp(T-Acs_l)*dt_l*xs[l,p]
// block = (bc, h); wave g = n-group of 32, lane p 0..63
// ============================================================
__global__ __launch_bounds__(256) void chunk_state_kernel(
    const float* __restrict__ xBCc, const float* __restrict__ dtv,
    const float* __restrict__ Acs, float* __restrict__ state)
{
    int bc = blockIdx.x, h = blockIdx.y;
    int t = threadIdx.x;
    int g = t >> 6;        // wave id -> n base g*32 (wave-uniform)
    int p = t & 63;
    __shared__ float acs_s[CHUNK];
    __shared__ float scale_s[CHUNK];
    __shared__ float Xs[64][64];
    __shared__ float Bs[64][128];
    const float* acs = Acs + (bc * NHEADS + h) * CHUNK;
    acs_s[t] = acs[t];
    __syncthreads();
    float T = acs_s[CHUNK - 1];
    int row0 = bc * CHUNK;
    scale_s[t] = __expf(T - acs_s[t]) * dtv[(row0 + t) * NHEADS + h];
    __syncthreads();
    float acc[32];
#pragma unroll
    for (int j = 0; j < 32; ++j) acc[j] = 0.f;

    for (int lt = 0; lt < 4; ++lt) {
        // stage Xs (64x64) and Bs (64x128)
#pragma unroll
        for (int j = 0; j < 4; ++j) {
            int i = t + j * 256;           // f4 index over 1024
            int lr = i >> 4, p4 = i & 15;
            *(float4*)&Xs[lr][p4 * 4] =
                *(const float4*)(xBCc + (long)(row0 + lt * 64 + lr) * CONVD + h * HEADDIM + p4 * 4);
        }
#pragma unroll
        for (int j = 0; j < 8; ++j) {
            int i = t + j * 256;           // f4 index over 2048
            int lr = i >> 5, n4 = i & 31;
            *(float4*)&Bs[lr][n4 * 4] =
                *(const float4*)(xBCc + (long)(row0 + lt * 64 + lr) * CONVD + DINNER + n4 * 4);
        }
        __syncthreads();
        for (int lp = 0; lp < 64; ++lp) {
            float w = scale_s[lt * 64 + lp] * Xs[lp][p];
#pragma unroll
            for (int n4 = 0; n4 < 8; ++n4) {
                float4 bv = *(const float4*)&Bs[lp][g * 32 + n4 * 4];  // wave-broadcast
                acc[n4*4+0] += w * bv.x; acc[n4*4+1] += w * bv.y;
                acc[n4*4+2] += w * bv.z; acc[n4*4+3] += w * bv.w;
            }
        }
        __syncthreads();
    }
    // store: layout [bc][h][n][p], coalesced over p
    float* out = state + ((long)(bc * NHEADS + h) * DSTATE + g * 32) * HEADDIM + p;
#pragma unroll
    for (int j = 0; j < 32; ++j)
        out[j * HEADDIM] = acc[j];
}

// ============================================================
// Inter-chunk scan (in place): entering state per chunk.
// One thread per (b,h,element); 8 sequential chunk steps.
// ============================================================
__global__ __launch_bounds__(256) void state_scan_kernel(
    float* __restrict__ state, const float* __restrict__ Acs)
{
    long flat = (long)blockIdx.x * 256 + threadIdx.x;   // < BB*NHEADS*8192
    int e = (int)(flat & 8191);
    int bh = (int)(flat >> 13);
    int b = bh >> 5, h = bh & 31;
    float S = 0.f;
    for (int c = 0; c < NCH; ++c) {
        int bc = b * NCH + c;
        long idx = ((long)(bc * NHEADS + h)) * 8192 + e;
        float T = Acs[(bc * NHEADS + h) * CHUNK + CHUNK - 1];
        float tmp = state[idx];
        state[idx] = S;               // entering state for chunk c
        S = S * __expf(T) + tmp;
    }
}

// ============================================================
// Y kernel: diag (G-masked) + off (C·S_enter) + D*xh, gated by silu(z)
// block = (bc, h); thread = l (0..255); Y[64] accum over p
// ============================================================
__global__ __launch_bounds__(256) void ssd_y_kernel(
    const float* __restrict__ xBCc, const float* __restrict__ dtv,
    const float* __restrict__ Acs, const float* __restrict__ Gt,
    const float* __restrict__ state, const float* __restrict__ zx,
    const float* __restrict__ Dh, float* __restrict__ y)
{
    int bc = blockIdx.x, h = blockIdx.y;
    int l = threadIdx.x;
    __shared__ float acs_s[CHUNK];
    __shared__ float dts[CHUNK];
    __shared__ float Slds[DSTATE * HEADDIM];  // [n][p]
    __shared__ float XC[256 * 17];            // union: Xd tile [s][p] (64x64) / C tile [l][j] (256x17)
    int row0 = bc * CHUNK;
    acs_s[l] = Acs[(bc * NHEADS + h) * CHUNK + l];
    dts[l] = dtv[(row0 + l) * NHEADS + h];
    {
        const float* spt = state + (long)(bc * NHEADS + h) * (DSTATE * HEADDIM);
#pragma unroll
        for (int j = 0; j < 8; ++j) {
            int i = threadIdx.x + j * 256;
            *(float4*)&Slds[i * 4] = *(const float4*)(spt + i * 4);
        }
    }
    __syncthreads();
    float acs_l = acs_s[l];
    float Y[64];
#pragma unroll
    for (int i = 0; i < 64; ++i) Y[i] = 0.f;
    const float* gt = Gt + (long)bc * (CHUNK * CHUNK);

    // ---- diagonal (within-chunk) part ----
    for (int st = 0; st < 4; ++st) {
#pragma unroll
        for (int j = 0; j < 4; ++j) {
            int i = threadIdx.x + j * 256;     // f4 over 1024
            int s = i >> 4, p4 = i & 15;
            float4 v = *(const float4*)(xBCc + (long)(row0 + st * 64 + s) * CONVD + h * HEADDIM + p4 * 4);
            float d = dts[st * 64 + s];
            v.x *= d; v.y *= d; v.z *= d; v.w *= d;
            *(float4*)&XC[s * 64 + p4 * 4] = v;
        }
        __syncthreads();
        if (st * 64 <= l) {            // wave-uniform
            int smax = l - st * 64; if (smax > 63) smax = 63;
            for (int s2 = 0; s2 <= smax; ++s2) {
                int s = st * 64 + s2;
                float w = gt[(long)s * CHUNK + l] * __expf(acs_l - acs_s[s]);
                const float4* xr = (const float4*)&XC[s2 * 64];
#pragma unroll
                for (int p4 = 0; p4 < 16; ++p4) {
                    float4 xv = xr[p4];
                    Y[p4*4+0] += w * xv.x; Y[p4*4+1] += w * xv.y;
                    Y[p4*4+2] += w * xv.z; Y[p4*4+3] += w * xv.w;
                }
            }
        }
        __syncthreads();
    }

    // ---- off-diagonal: Y += exp(Acs_l) * C[l,:] . S_enter[:, p] ----
    float eAl = __expf(acs_l);
    for (int nb = 0; nb < 8; ++nb) {
#pragma unroll
        for (int j = 0; j < 4; ++j) {
            int i = threadIdx.x + j * 256;      // f4 over 1024
            int lr = i >> 2, j4 = i & 3;
            float4 v = *(const float4*)(xBCc + (long)(row0 + lr) * CONVD + DINNER + DSTATE + nb * 16 + j4 * 4);
            XC[lr * 17 + j4 * 4 + 0] = v.x; XC[lr * 17 + j4 * 4 + 1] = v.y;
            XC[lr * 17 + j4 * 4 + 2] = v.z; XC[lr * 17 + j4 * 4 + 3] = v.w;
        }
        __syncthreads();
#pragma unroll
        for (int j = 0; j < 16; ++j) {
            int n = nb * 16 + j;
            float w = XC[l * 17 + j] * eAl;
            const float4* sr = (const float4*)&Slds[n * HEADDIM];
#pragma unroll
            for (int p4 = 0; p4 < 16; ++p4) {
                float4 sv = sr[p4];
                Y[p4*4+0] += w * sv.x; Y[p4*4+1] += w * sv.y;
                Y[p4*4+2] += w * sv.z; Y[p4*4+3] += w * sv.w;
            }
        }
        __syncthreads();
    }

    // ---- epilogue: + D*xh, gate with silu(z) ----
    float Dv = Dh[h];
    int row = row0 + l;
#pragma unroll
    for (int p4 = 0; p4 < 16; ++p4) {
        float4 xv = *(const float4*)(xBCc + (long)row * CONVD + h * HEADDIM + p4 * 4);
        float4 zv = *(const float4*)(zx + (long)row * DINP + h * HEADDIM + p4 * 4);
        float4 o;
        o.x = (Y[p4*4+0] + Dv * xv.x) * (zv.x / (1.f + __expf(-zv.x)));
        o.y = (Y[p4*4+1] + Dv * xv.y) * (zv.y / (1.f + __expf(-zv.y)));
        o.z = (Y[p4*4+2] + Dv * xv.z) * (zv.z / (1.f + __expf(-zv.z)));
        o.w = (Y[p4*4+3] + Dv * xv.w) * (zv.w / (1.f + __expf(-zv.w)));
        *(float4*)(y + (long)row * DINNER + h * HEADDIM + p4 * 4) = o;
    }
}

// ============================================================
// launch
// ============================================================
extern "C" void kernel_launch(void* const* d_in, const int* in_sizes, int n_in,
                              void* d_out, int out_size, void* d_ws, size_t ws_size,
                              hipStream_t stream)
{
    (void)in_sizes; (void)n_in; (void)out_size; (void)ws_size;
    const float* x          = (const float*)d_in[0];
    const float* norm_w     = (const float*)d_in[1];
    const float* in_proj_w  = (const float*)d_in[2];
    const float* conv_w     = (const float*)d_in[3];
    const float* conv_b     = (const float*)d_in[4];
    const float* dt_bias    = (const float*)d_in[5];
    const float* A_log      = (const float*)d_in[6];
    const float* Dh         = (const float*)d_in[7];
    const float* gnorm_w    = (const float*)d_in[8];
    const float* out_proj_w = (const float*)d_in[9];
    float* out = (float*)d_out;
    float* ws = (float*)d_ws;

    // workspace layout (floats); total 53,870,592 floats = 215.5 MB
    float* xn_y  = ws;                     // 8,388,608  (xn first, y later)
    float* zxb   = xn_y  + 8388608;        // 17,956,864
    float* xBCc  = zxb   + 17956864;       // 9,437,184
    float* dtv   = xBCc  + 9437184;        // 131,072
    float* acs   = dtv   + 131072;         // 131,072
    float* Gt    = acs   + 131072;         // 1,048,576  (Gt[bc][s][l] = B_s . C_l)
    float* state = Gt    + 1048576;        // 16,777,216 ([bc][h][n][p])

    // 1. xn = RMSNorm(x) * norm_w
    rmsnorm_kernel<<<dim3(NROWS), 256, 0, stream>>>(x, norm_w, xn_y, DMODEL);

    // 2. zxbcdt = xn @ in_proj_w^T   (M=4096, N=4384, K=1024)
    gemm_nt_kernel<<<dim3(35, 32, 1), 256, 0, stream>>>(
        xn_y, DMODEL, 0, in_proj_w, DMODEL, 0, zxb, DINP, 0,
        nullptr, 0, NROWS, DINP, DMODEL);

    // 3. causal depthwise conv + SiLU on xBC slice
    conv_silu_kernel<<<dim3(NROWS, 9), 256, 0, stream>>>(zxb, conv_w, conv_b, xBCc);

    // 4. dt = softplus(dt + dt_bias)
    dt_kernel<<<dim3(NROWS * NHEADS / 256), 256, 0, stream>>>(zxb, dt_bias, dtv);

    // 5. per-chunk cumsum of dA
    acs_kernel<<<dim3(BB * NCH, NHEADS), 256, 0, stream>>>(dtv, A_log, acs);

    // 6. Gt[bc][s][l] = B_s . C_l  (batched NT GEMM, M=N=256, K=128)
    gemm_nt_kernel<<<dim3(2, 2, BB * NCH), 256, 0, stream>>>(
        xBCc + DINNER, CONVD, (long)CHUNK * CONVD,
        xBCc + DINNER + DSTATE, CONVD, (long)CHUNK * CONVD,
        Gt, CHUNK, (long)CHUNK * CHUNK,
        nullptr, 0, CHUNK, CHUNK, DSTATE);

    // 7. chunk states
    chunk_state_kernel<<<dim3(BB * NCH, NHEADS), 256, 0, stream>>>(xBCc, dtv, acs, state);

    // 8. inter-chunk scan -> entering states (in place)
    state_scan_kernel<<<dim3(BB * NHEADS * 8192 / 256), 256, 0, stream>>>(state, acs);

    // 9. Y = diag + off + D*xh, gated with silu(z) -> y (reuses xn region)
    ssd_y_kernel<<<dim3(BB * NCH, NHEADS), 256, 0, stream>>>(
        xBCc, dtv, acs, Gt, state, zxb, Dh, xn_y);

    // 10. gnorm (in place on y)
    rmsnorm_kernel<<<dim3(NROWS), 256, 0, stream>>>(xn_y, gnorm_w, xn_y, DINNER);

    // 11. out = x + y @ out_proj_w^T  (M=4096, N=1024, K=2048)
    gemm_nt_kernel<<<dim3(8, 32, 1), 256, 0, stream>>>(
        xn_y, DINNER, 0, out_proj_w, DINNER, 0, out, DMODEL, 0,
        x, DMODEL, NROWS, DMODEL, DINNER);
}

// Round 2
// 528.580 us; speedup vs baseline: 2.4871x; 2.4871x over previous
//
#include <hip/hip_runtime.h>
#include <hip/hip_bf16.h>

// ---- problem constants ----
#define BB      2
#define LSEQ    2048
#define DMODEL  1024
#define DSTATE  128
#define DCONV   4
#define HEADDIM 64
#define DINNER  2048      // EXP*DMODEL
#define NHEADS  32        // DINNER/HEADDIM
#define CONVD   2304      // DINNER + 2*DSTATE
#define DINP    4384      // 2*DINNER + 2*DSTATE + NHEADS
#define NPAD_IN 4480      // 35*128, padded in_proj rows
#define CHUNK   256
#define NCH     8         // LSEQ/CHUNK
#define NROWS   4096      // BB*LSEQ
#define EPSF    1e-5f

typedef __attribute__((ext_vector_type(8))) short bf16x8;
typedef __attribute__((ext_vector_type(4))) float f32x4;

#define ASYNC_COPY16(gptr, lptr) \
    __builtin_amdgcn_global_load_lds((const __attribute__((address_space(1))) void*)(gptr), \
                                     (__attribute__((address_space(3))) void*)(lptr), 16, 0, 0)

__device__ __forceinline__ ushort f2bf(float f) {
    __hip_bfloat16 h = __float2bfloat16(f);
    return *(ushort*)&h;
}
__device__ __forceinline__ float bf2f(ushort u) {
    return __uint_as_float(((unsigned)u) << 16);
}

// ============================================================
// Weight convert fp32 -> bf16 with row padding (zeros for n >= N)
// ============================================================
__global__ __launch_bounds__(256) void cvt_w_kernel(
    const float* __restrict__ src, ushort* __restrict__ dst,
    int N, int kshift)
{
    long i4 = ((long)blockIdx.x * 256 + threadIdx.x) * 4;
    int n = (int)(i4 >> kshift);
    long k = i4 & ((1L << kshift) - 1);
    ushort4 o;
    if (n < N) {
        float4 v = *(const float4*)(src + ((long)n << kshift) + k);
        o.x = f2bf(v.x); o.y = f2bf(v.y); o.z = f2bf(v.z); o.w = f2bf(v.w);
    } else {
        o.x = o.y = o.z = o.w = 0;
    }
    *(ushort4*)(dst + i4) = o;
}

// ============================================================
// RMSNorm -> bf16 output (D=1024)
// ============================================================
__global__ __launch_bounds__(256) void rmsnorm_bf16_kernel(
    const float* __restrict__ in, const float* __restrict__ w,
    ushort* __restrict__ out, int D)
{
    int row = blockIdx.x;
    const float* xr = in + (long)row * D;
    int nv = D >> 10;
    float4 vals[2];
    float ss = 0.f;
    for (int i = 0; i < nv; ++i) {
        vals[i] = *(const float4*)(xr + (threadIdx.x + i * 256) * 4);
        ss += vals[i].x*vals[i].x + vals[i].y*vals[i].y
            + vals[i].z*vals[i].z + vals[i].w*vals[i].w;
    }
    for (int off = 32; off; off >>= 1) ss += __shfl_down(ss, off, 64);
    __shared__ float red[4];
    if ((threadIdx.x & 63) == 0) red[threadIdx.x >> 6] = ss;
    __syncthreads();
    float tot = red[0] + red[1] + red[2] + red[3];
    float scale = rsqrtf(tot / (float)D + EPSF);
    ushort* orow = out + (long)row * D;
    for (int i = 0; i < nv; ++i) {
        int base = (threadIdx.x + i * 256) * 4;
        float4 v = vals[i];
        float4 wv = *(const float4*)(w + base);
        ushort4 o;
        o.x = f2bf(v.x * scale * wv.x); o.y = f2bf(v.y * scale * wv.y);
        o.z = f2bf(v.z * scale * wv.z); o.w = f2bf(v.w * scale * wv.w);
        *(ushort4*)(orow + base) = o;
    }
}

// ============================================================
// bf16 MFMA NT GEMM: C[m,n] = sum_k A[m,k]*W[n,k] (+resid)
// 128x128 tile, BK=64, 256 threads, mfma_f32_16x16x32_bf16.
// global_load_lds(16B) staging with XOR-swizzled LDS slots:
//   slot(row,kseg) = row*8 + (kseg ^ (row&7)), kseg = 16B unit of BK.
// The swizzle is applied on the GLOBAL source address (per-lane), so
// the wave-uniform-base constraint of global_load_lds is satisfied,
// and fragment ds_read_b128 is 2-way-aliased only (free).
// Requires: M%128==0, K%64==0, W has ceil(N/128)*128 rows (padded).
// ============================================================
__global__ __launch_bounds__(256) void gemm_bf16_kernel(
    const ushort* __restrict__ A, const ushort* __restrict__ W,
    float* __restrict__ C, int ldc, const float* __restrict__ resid,
    int M, int N, int K)
{
    __shared__ ushort As[128 * 64];
    __shared__ ushort Bs[128 * 64];
    const int t = threadIdx.x;
    const int lane = t & 63;
    const int w = t >> 6;
    const int wm = w & 1, wn = w >> 1;
    const int lm = lane & 15, quad = lane >> 4;
    const int m0 = blockIdx.y * 128, n0 = blockIdx.x * 128;

    // staging source pointers (4 slots of 256 threads each per operand)
    const ushort* ga[4]; const ushort* gw[4];
#pragma unroll
    for (int i = 0; i < 4; ++i) {
        int s = i * 256 + t;
        int row = s >> 3;
        int kseg = (s & 7) ^ (row & 7);
        ga[i] = A + (long)(m0 + row) * K + kseg * 8;
        gw[i] = W + (long)(n0 + row) * K + kseg * 8;
    }

    f32x4 acc[4][4];
    f32x4 zero4 = {0.f, 0.f, 0.f, 0.f};
#pragma unroll
    for (int i = 0; i < 4; ++i)
#pragma unroll
        for (int j = 0; j < 4; ++j) acc[i][j] = zero4;

    // fragment LDS slot precompute
    int arow8[4], arow7[4], brow8[4], brow7[4];
#pragma unroll
    for (int i = 0; i < 4; ++i) {
        int ar = wm * 64 + i * 16 + lm;
        arow8[i] = ar * 8; arow7[i] = ar & 7;
        int br = wn * 64 + i * 16 + lm;
        brow8[i] = br * 8; brow7[i] = br & 7;
    }

    for (int k0 = 0; k0 < K; k0 += 64) {
#pragma unroll
        for (int i = 0; i < 4; ++i) {
            ASYNC_COPY16(ga[i], &As[(i * 256 + w * 64) * 8]);
            ASYNC_COPY16(gw[i], &Bs[(i * 256 + w * 64) * 8]);
            ga[i] += 64; gw[i] += 64;
        }
        __syncthreads();   // drains vmcnt -> staged data visible
#pragma unroll
        for (int ks = 0; ks < 2; ++ks) {
            bf16x8 af[4], bfr[4];
#pragma unroll
            for (int i = 0; i < 4; ++i) {
                af[i]  = *(const bf16x8*)&As[(arow8[i] + ((ks * 4 + quad) ^ arow7[i])) * 8];
                bfr[i] = *(const bf16x8*)&Bs[(brow8[i] + ((ks * 4 + quad) ^ brow7[i])) * 8];
            }
#pragma unroll
            for (int im = 0; im < 4; ++im)
#pragma unroll
                for (int in = 0; in < 4; ++in)
                    acc[im][in] = __builtin_amdgcn_mfma_f32_16x16x32_bf16(
                        af[im], bfr[in], acc[im][in], 0, 0, 0);
        }
        __syncthreads();   // all waves done reading before restage
    }

    // epilogue: D lane mapping col(n)=lane&15, row(m)=quad*4+reg
#pragma unroll
    for (int in = 0; in < 4; ++in) {
        int col = n0 + wn * 64 + in * 16 + lm;
        if (col >= N) continue;
#pragma unroll
        for (int im = 0; im < 4; ++im) {
            int r0 = m0 + wm * 64 + im * 16 + quad * 4;
            f32x4 v = acc[im][in];
#pragma unroll
            for (int i = 0; i < 4; ++i) {
                long idx = (long)(r0 + i) * ldc + col;
                float o = v[i];
                if (resid) o += resid[idx];
                C[idx] = o;
            }
        }
    }
}

// ============================================================
// fp32 NT GEMM (kept for the small Gt = B.C^T batched matmul)
// ============================================================
__global__ __launch_bounds__(256) void gemm_nt_kernel(
    const float* __restrict__ A, int lda, long sA,
    const float* __restrict__ W, int ldw, long sW,
    float* __restrict__ C, int ldc, long sC,
    int M, int N, int K)
{
    __shared__ float As[16][132];
    __shared__ float Ws[16][132];
    const int t = threadIdx.x;
    const int tx = t & 15, ty = t >> 4;
    A += (long)blockIdx.z * sA;
    W += (long)blockIdx.z * sW;
    C += (long)blockIdx.z * sC;
    int m0 = blockIdx.y * 128, n0 = blockIdx.x * 128;
    float acc[8][8];
#pragma unroll
    for (int i = 0; i < 8; ++i)
#pragma unroll
        for (int j = 0; j < 8; ++j) acc[i][j] = 0.f;

    for (int k0 = 0; k0 < K; k0 += 16) {
#pragma unroll
        for (int u = 0; u < 2; ++u) {
            int idx = t + u * 256;
            int row = idx >> 2, seg = idx & 3;
            int gk = k0 + seg * 4;
            float4 va = make_float4(0.f, 0.f, 0.f, 0.f);
            int gr = m0 + row;
            if (gr < M) va = *(const float4*)(A + (long)gr * lda + gk);
            As[seg*4+0][row] = va.x; As[seg*4+1][row] = va.y;
            As[seg*4+2][row] = va.z; As[seg*4+3][row] = va.w;
            float4 vw = make_float4(0.f, 0.f, 0.f, 0.f);
            int gc = n0 + row;
            if (gc < N) vw = *(const float4*)(W + (long)gc * ldw + gk);
            Ws[seg*4+0][row] = vw.x; Ws[seg*4+1][row] = vw.y;
            Ws[seg*4+2][row] = vw.z; Ws[seg*4+3][row] = vw.w;
        }
        __syncthreads();
#pragma unroll
        for (int kk = 0; kk < 16; ++kk) {
            float a[8], b[8];
            *(float4*)&a[0] = *(const float4*)&As[kk][ty * 8];
            *(float4*)&a[4] = *(const float4*)&As[kk][ty * 8 + 4];
            *(float4*)&b[0] = *(const float4*)&Ws[kk][tx * 8];
            *(float4*)&b[4] = *(const float4*)&Ws[kk][tx * 8 + 4];
#pragma unroll
            for (int i = 0; i < 8; ++i)
#pragma unroll
                for (int j = 0; j < 8; ++j)
                    acc[i][j] += a[i] * b[j];
        }
        __syncthreads();
    }
#pragma unroll
    for (int i = 0; i < 8; ++i) {
        int gr = m0 + ty * 8 + i;
        if (gr >= M) continue;
#pragma unroll
        for (int jq = 0; jq < 2; ++jq) {
            int gc = n0 + tx * 8 + jq * 4;
            if (gc + 3 < N) {
                float4 o;
                o.x = acc[i][jq*4+0]; o.y = acc[i][jq*4+1];
                o.z = acc[i][jq*4+2]; o.w = acc[i][jq*4+3];
                *(float4*)(C + (long)gr * ldc + gc) = o;
            }
        }
    }
}

// ============================================================
// Depthwise causal conv (width 4) + SiLU on the xBC slice
// ============================================================
__global__ __launch_bounds__(256) void conv_silu_kernel(
    const float* __restrict__ zx, const float* __restrict__ cw,
    const float* __restrict__ cb, float* __restrict__ xBCc)
{
    int row = blockIdx.x;
    int c = blockIdx.y * 256 + threadIdx.x;
    int l = row & (LSEQ - 1);
    float acc = cb[c];
#pragma unroll
    for (int k = 0; k < DCONV; ++k) {
        int ls = l + k - (DCONV - 1);
        if (ls >= 0)
            acc += zx[(long)(row + k - (DCONV - 1)) * DINP + DINNER + c] * cw[c * DCONV + k];
    }
    xBCc[(long)row * CONVD + c] = acc / (1.f + __expf(-acc));
}

// ============================================================
// dt = softplus(dt_raw + dt_bias)
// ============================================================
__global__ __launch_bounds__(256) void dt_kernel(
    const float* __restrict__ zx, const float* __restrict__ dt_bias,
    float* __restrict__ dtv)
{
    int idx = blockIdx.x * 256 + threadIdx.x;
    int row = idx >> 5, h = idx & 31;
    float v = zx[(long)row * DINP + (DINP - NHEADS) + h] + dt_bias[h];
    float sp = (v > 20.f) ? v : log1pf(__expf(v));
    dtv[idx] = sp;
}

// ============================================================
// Per-chunk inclusive cumsum of dA
// ============================================================
__global__ __launch_bounds__(256) void acs_kernel(
    const float* __restrict__ dtv, const float* __restrict__ A_log,
    float* __restrict__ Acs)
{
    int bc = blockIdx.x, h = blockIdx.y;
    int l = threadIdx.x;
    int row = bc * CHUNK + l;
    float a = -dtv[row * NHEADS + h] * __expf(A_log[h]);
    __shared__ float buf[2][CHUNK];
    buf[0][l] = a; __syncthreads();
    int src = 0;
    for (int off = 1; off < CHUNK; off <<= 1) {
        float v = buf[src][l];
        if (l >= off) v += buf[src][l - off];
        buf[src ^ 1][l] = v;
        __syncthreads();
        src ^= 1;
    }
    Acs[(bc * NHEADS + h) * CHUNK + l] = buf[src][l];
}

// ============================================================
// Chunk states
// ============================================================
__global__ __launch_bounds__(256) void chunk_state_kernel(
    const float* __restrict__ xBCc, const float* __restrict__ dtv,
    const float* __restrict__ Acs, float* __restrict__ state)
{
    int bc = blockIdx.x, h = blockIdx.y;
    int t = threadIdx.x;
    int g = t >> 6;
    int p = t & 63;
    __shared__ float acs_s[CHUNK];
    __shared__ float scale_s[CHUNK];
    __shared__ float Xs[64][64];
    __shared__ float Bs[64][128];
    const float* acs = Acs + (bc * NHEADS + h) * CHUNK;
    acs_s[t] = acs[t];
    __syncthreads();
    float T = acs_s[CHUNK - 1];
    int row0 = bc * CHUNK;
    scale_s[t] = __expf(T - acs_s[t]) * dtv[(row0 + t) * NHEADS + h];
    __syncthreads();
    float acc[32];
#pragma unroll
    for (int j = 0; j < 32; ++j) acc[j] = 0.f;

    for (int lt = 0; lt < 4; ++lt) {
#pragma unroll
        for (int j = 0; j < 4; ++j) {
            int i = t + j * 256;
            int lr = i >> 4, p4 = i & 15;
            *(float4*)&Xs[lr][p4 * 4] =
                *(const float4*)(xBCc + (long)(row0 + lt * 64 + lr) * CONVD + h * HEADDIM + p4 * 4);
        }
#pragma unroll
        for (int j = 0; j < 8; ++j) {
            int i = t + j * 256;
            int lr = i >> 5, n4 = i & 31;
            *(float4*)&Bs[lr][n4 * 4] =
                *(const float4*)(xBCc + (long)(row0 + lt * 64 + lr) * CONVD + DINNER + n4 * 4);
        }
        __syncthreads();
        for (int lp = 0; lp < 64; ++lp) {
            float w = scale_s[lt * 64 + lp] * Xs[lp][p];
#pragma unroll
            for (int n4 = 0; n4 < 8; ++n4) {
                float4 bv = *(const float4*)&Bs[lp][g * 32 + n4 * 4];
                acc[n4*4+0] += w * bv.x; acc[n4*4+1] += w * bv.y;
                acc[n4*4+2] += w * bv.z; acc[n4*4+3] += w * bv.w;
            }
        }
        __syncthreads();
    }
    float* out = state + ((long)(bc * NHEADS + h) * DSTATE + g * 32) * HEADDIM + p;
#pragma unroll
    for (int j = 0; j < 32; ++j)
        out[j * HEADDIM] = acc[j];
}

// ============================================================
// Inter-chunk scan (in place)
// ============================================================
__global__ __launch_bounds__(256) void state_scan_kernel(
    float* __restrict__ state, const float* __restrict__ Acs)
{
    long flat = (long)blockIdx.x * 256 + threadIdx.x;
    int e = (int)(flat & 8191);
    int bh = (int)(flat >> 13);
    int b = bh >> 5, h = bh & 31;
    float S = 0.f;
    for (int c = 0; c < NCH; ++c) {
        int bc = b * NCH + c;
        long idx = ((long)(bc * NHEADS + h)) * 8192 + e;
        float T = Acs[(bc * NHEADS + h) * CHUNK + CHUNK - 1];
        float tmp = state[idx];
        state[idx] = S;
        S = S * __expf(T) + tmp;
    }
}

// ============================================================
// Y kernel: diag + off + D*xh, gated by silu(z); writes bf16 y
// and accumulates per-row sum-of-squares for the fused gnorm.
// ============================================================
__global__ __launch_bounds__(256) void ssd_y_kernel(
    const float* __restrict__ xBCc, const float* __restrict__ dtv,
    const float* __restrict__ Acs, const float* __restrict__ Gt,
    const float* __restrict__ state, const float* __restrict__ zx,
    const float* __restrict__ Dh, ushort* __restrict__ ybf,
    float* __restrict__ ssq)
{
    int bc = blockIdx.x, h = blockIdx.y;
    int l = threadIdx.x;
    __shared__ float acs_s[CHUNK];
    __shared__ float dts[CHUNK];
    __shared__ float Slds[DSTATE * HEADDIM];
    __shared__ float XC[256 * 17];
    int row0 = bc * CHUNK;
    acs_s[l] = Acs[(bc * NHEADS + h) * CHUNK + l];
    dts[l] = dtv[(row0 + l) * NHEADS + h];
    {
        const float* spt = state + (long)(bc * NHEADS + h) * (DSTATE * HEADDIM);
#pragma unroll
        for (int j = 0; j < 8; ++j) {
            int i = threadIdx.x + j * 256;
            *(float4*)&Slds[i * 4] = *(const float4*)(spt + i * 4);
        }
    }
    __syncthreads();
    float acs_l = acs_s[l];
    float Y[64];
#pragma unroll
    for (int i = 0; i < 64; ++i) Y[i] = 0.f;
    const float* gt = Gt + (long)bc * (CHUNK * CHUNK);

    // diagonal part
    for (int st = 0; st < 4; ++st) {
#pragma unroll
        for (int j = 0; j < 4; ++j) {
            int i = threadIdx.x + j * 256;
            int s = i >> 4, p4 = i & 15;
            float4 v = *(const float4*)(xBCc + (long)(row0 + st * 64 + s) * CONVD + h * HEADDIM + p4 * 4);
            float d = dts[st * 64 + s];
            v.x *= d; v.y *= d; v.z *= d; v.w *= d;
            *(float4*)&XC[s * 64 + p4 * 4] = v;
        }
        __syncthreads();
        if (st * 64 <= l) {
            int smax = l - st * 64; if (smax > 63) smax = 63;
            for (int s2 = 0; s2 <= smax; ++s2) {
                int s = st * 64 + s2;
                float w = gt[(long)s * CHUNK + l] * __expf(acs_l - acs_s[s]);
                const float4* xr = (const float4*)&XC[s2 * 64];
#pragma unroll
                for (int p4 = 0; p4 < 16; ++p4) {
                    float4 xv = xr[p4];
                    Y[p4*4+0] += w * xv.x; Y[p4*4+1] += w * xv.y;
                    Y[p4*4+2] += w * xv.z; Y[p4*4+3] += w * xv.w;
                }
            }
        }
        __syncthreads();
    }

    // off-diagonal part
    float eAl = __expf(acs_l);
    for (int nb = 0; nb < 8; ++nb) {
#pragma unroll
        for (int j = 0; j < 4; ++j) {
            int i = threadIdx.x + j * 256;
            int lr = i >> 2, j4 = i & 3;
            float4 v = *(const float4*)(xBCc + (long)(row0 + lr) * CONVD + DINNER + DSTATE + nb * 16 + j4 * 4);
            XC[lr * 17 + j4 * 4 + 0] = v.x; XC[lr * 17 + j4 * 4 + 1] = v.y;
            XC[lr * 17 + j4 * 4 + 2] = v.z; XC[lr * 17 + j4 * 4 + 3] = v.w;
        }
        __syncthreads();
#pragma unroll
        for (int j = 0; j < 16; ++j) {
            int n = nb * 16 + j;
            float w = XC[l * 17 + j] * eAl;
            const float4* sr = (const float4*)&Slds[n * HEADDIM];
#pragma unroll
            for (int p4 = 0; p4 < 16; ++p4) {
                float4 sv = sr[p4];
                Y[p4*4+0] += w * sv.x; Y[p4*4+1] += w * sv.y;
                Y[p4*4+2] += w * sv.z; Y[p4*4+3] += w * sv.w;
            }
        }
        __syncthreads();
    }

    // epilogue: + D*xh, gate silu(z), bf16 store + ssq atomic
    float Dv = Dh[h];
    int row = row0 + l;
    float ss = 0.f;
    ushort* yr = ybf + (long)row * DINNER + h * HEADDIM;
#pragma unroll
    for (int p4 = 0; p4 < 16; ++p4) {
        float4 xv = *(const float4*)(xBCc + (long)row * CONVD + h * HEADDIM + p4 * 4);
        float4 zv = *(const float4*)(zx + (long)row * DINP + h * HEADDIM + p4 * 4);
        float o0 = (Y[p4*4+0] + Dv * xv.x) * (zv.x / (1.f + __expf(-zv.x)));
        float o1 = (Y[p4*4+1] + Dv * xv.y) * (zv.y / (1.f + __expf(-zv.y)));
        float o2 = (Y[p4*4+2] + Dv * xv.z) * (zv.z / (1.f + __expf(-zv.z)));
        float o3 = (Y[p4*4+3] + Dv * xv.w) * (zv.w / (1.f + __expf(-zv.w)));
        ss += o0*o0 + o1*o1 + o2*o2 + o3*o3;
        ushort4 u;
        u.x = f2bf(o0); u.y = f2bf(o1); u.z = f2bf(o2); u.w = f2bf(o3);
        *(ushort4*)(yr + p4 * 4) = u;
    }
    atomicAdd(&ssq[row], ss);
}

// ============================================================
// gnorm scale (bf16 in-place): y *= rsqrt(mean(y^2)+eps) * gw
// ============================================================
__global__ __launch_bounds__(256) void gscale_kernel(
    ushort* __restrict__ ybf, const float* __restrict__ ssq,
    const float* __restrict__ gw)
{
    long i4 = ((long)blockIdx.x * 256 + threadIdx.x) * 4;
    int row = (int)(i4 >> 11);
    int c = (int)(i4 & 2047);
    float s = rsqrtf(ssq[row] * (1.f / (float)DINNER) + EPSF);
    ushort4 u = *(ushort4*)(ybf + i4);
    float4 g = *(const float4*)(gw + c);
    u.x = f2bf(bf2f(u.x) * s * g.x);
    u.y = f2bf(bf2f(u.y) * s * g.y);
    u.z = f2bf(bf2f(u.z) * s * g.z);
    u.w = f2bf(bf2f(u.w) * s * g.w);
    *(ushort4*)(ybf + i4) = u;
}

// ============================================================
// launch
// ============================================================
extern "C" void kernel_launch(void* const* d_in, const int* in_sizes, int n_in,
                              void* d_out, int out_size, void* d_ws, size_t ws_size,
                              hipStream_t stream)
{
    (void)in_sizes; (void)n_in; (void)out_size; (void)ws_size;
    const float* x          = (const float*)d_in[0];
    const float* norm_w     = (const float*)d_in[1];
    const float* in_proj_w  = (const float*)d_in[2];
    const float* conv_w     = (const float*)d_in[3];
    const float* conv_b     = (const float*)d_in[4];
    const float* dt_bias    = (const float*)d_in[5];
    const float* A_log      = (const float*)d_in[6];
    const float* Dh         = (const float*)d_in[7];
    const float* gnorm_w    = (const float*)d_in[8];
    const float* out_proj_w = (const float*)d_in[9];
    float* out = (float*)d_out;
    float* ws = (float*)d_ws;

    // workspace layout (float slots); total 50,925,568 = 203.7 MB
    float* zxb   = ws;                       // 17,956,864
    float* xBCc  = zxb   + 17956864;         // 9,437,184
    float* dtv   = xBCc  + 9437184;          // 131,072
    float* acs   = dtv   + 131072;           // 131,072
    float* Gt    = acs   + 131072;           // 1,048,576
    float* state = Gt    + 1048576;          // 16,777,216
    float* regU  = state + 16777216;         // 4,390,912 (xn_bf+wi_bf, later ybf)
    float* wo_f  = regU  + 4390912;          // 1,048,576 (wo_bf)
    float* ssq   = wo_f  + 1048576;          // 4,096

    ushort* xn_bf = (ushort*)regU;                    // 4096x1024   [dead after in_proj]
    ushort* wi_bf = (ushort*)(regU + 2097152);        // 4480x1024   [dead after in_proj]
    ushort* ybf   = (ushort*)regU;                    // 4096x2048   [born at ssd_y]
    ushort* wo_bf = (ushort*)wo_f;                    // 1024x2048

    // 0. zero ssq; convert weights to bf16 (in_proj padded to 4480 rows)
    hipMemsetAsync(ssq, 0, NROWS * sizeof(float), stream);
    cvt_w_kernel<<<dim3(NPAD_IN * DMODEL / 1024), 256, 0, stream>>>(
        in_proj_w, wi_bf, DINP, 10);
    cvt_w_kernel<<<dim3(DMODEL * DINNER / 1024), 256, 0, stream>>>(
        out_proj_w, wo_bf, DMODEL, 11);

    // 1. xn = RMSNorm(x) * norm_w -> bf16
    rmsnorm_bf16_kernel<<<dim3(NROWS), 256, 0, stream>>>(x, norm_w, xn_bf, DMODEL);

    // 2. zxbcdt = xn @ in_proj_w^T (MFMA bf16; M=4096, N=4384(pad 4480), K=1024)
    gemm_bf16_kernel<<<dim3(NPAD_IN / 128, NROWS / 128), 256, 0, stream>>>(
        xn_bf, wi_bf, zxb, DINP, nullptr, NROWS, DINP, DMODEL);

    // 3. causal depthwise conv + SiLU
    conv_silu_kernel<<<dim3(NROWS, 9), 256, 0, stream>>>(zxb, conv_w, conv_b, xBCc);

    // 4. dt = softplus(dt + dt_bias)
    dt_kernel<<<dim3(NROWS * NHEADS / 256), 256, 0, stream>>>(zxb, dt_bias, dtv);

    // 5. per-chunk cumsum of dA
    acs_kernel<<<dim3(BB * NCH, NHEADS), 256, 0, stream>>>(dtv, A_log, acs);

    // 6. Gt[bc][s][l] = B_s . C_l (fp32, batched)
    gemm_nt_kernel<<<dim3(2, 2, BB * NCH), 256, 0, stream>>>(
        xBCc + DINNER, CONVD, (long)CHUNK * CONVD,
        xBCc + DINNER + DSTATE, CONVD, (long)CHUNK * CONVD,
        Gt, CHUNK, (long)CHUNK * CHUNK,
        CHUNK, CHUNK, DSTATE);

    // 7. chunk states
    chunk_state_kernel<<<dim3(BB * NCH, NHEADS), 256, 0, stream>>>(xBCc, dtv, acs, state);

    // 8. inter-chunk scan
    state_scan_kernel<<<dim3(BB * NHEADS * 8192 / 256), 256, 0, stream>>>(state, acs);

    // 9. Y (diag+off+Dxh, gated) -> bf16 ybf + ssq atomics
    ssd_y_kernel<<<dim3(BB * NCH, NHEADS), 256, 0, stream>>>(
        xBCc, dtv, acs, Gt, state, zxb, Dh, ybf, ssq);

    // 10. fused gnorm scale (bf16 in place)
    gscale_kernel<<<dim3(NROWS * DINNER / 1024), 256, 0, stream>>>(ybf, ssq, gnorm_w);

    // 11. out = x + y @ out_proj_w^T (MFMA bf16; M=4096, N=1024, K=2048)
    gemm_bf16_kernel<<<dim3(DMODEL / 128, NROWS / 128), 256, 0, stream>>>(
        ybf, wo_bf, out, DMODEL, x, NROWS, DMODEL, DINNER);
}

// Round 3
// 403.181 us; speedup vs baseline: 3.2607x; 1.3110x over previous
//
#include <hip/hip_runtime.h>
#include <hip/hip_bf16.h>

// ---- problem constants ----
#define BB      2
#define LSEQ    2048
#define DMODEL  1024
#define DSTATE  128
#define DCONV   4
#define HEADDIM 64
#define DINNER  2048      // EXP*DMODEL
#define NHEADS  32        // DINNER/HEADDIM
#define CONVD   2304      // DINNER + 2*DSTATE
#define DINP    4384      // 2*DINNER + 2*DSTATE + NHEADS
#define NPAD_IN 4480      // 35*128, padded in_proj rows
#define CHUNK   256
#define NCH     8         // LSEQ/CHUNK
#define NROWS   4096      // BB*LSEQ
#define EPSF    1e-5f

typedef __attribute__((ext_vector_type(8))) short bf16x8;
typedef __attribute__((ext_vector_type(4))) float f32x4;

#define ASYNC_COPY16(gptr, lptr) \
    __builtin_amdgcn_global_load_lds((const __attribute__((address_space(1))) void*)(gptr), \
                                     (__attribute__((address_space(3))) void*)(lptr), 16, 0, 0)

__device__ __forceinline__ ushort f2bf(float f) {
    __hip_bfloat16 h = __float2bfloat16(f);
    return *(ushort*)&h;
}
__device__ __forceinline__ float bf2f(ushort u) {
    return __uint_as_float(((unsigned)u) << 16);
}
__device__ __forceinline__ short fb(float f) { return (short)f2bf(f); }

// ============================================================
// Weight convert fp32 -> bf16 with row padding (zeros for n >= N)
// ============================================================
__global__ __launch_bounds__(256) void cvt_w_kernel(
    const float* __restrict__ src, ushort* __restrict__ dst,
    int N, int kshift)
{
    long i4 = ((long)blockIdx.x * 256 + threadIdx.x) * 4;
    int n = (int)(i4 >> kshift);
    long k = i4 & ((1L << kshift) - 1);
    ushort4 o;
    if (n < N) {
        float4 v = *(const float4*)(src + ((long)n << kshift) + k);
        o.x = f2bf(v.x); o.y = f2bf(v.y); o.z = f2bf(v.z); o.w = f2bf(v.w);
    } else {
        o.x = o.y = o.z = o.w = 0;
    }
    *(ushort4*)(dst + i4) = o;
}

// ============================================================
// RMSNorm fp32 in -> bf16 out (D=1024)
// ============================================================
__global__ __launch_bounds__(256) void rmsnorm_bf16_kernel(
    const float* __restrict__ in, const float* __restrict__ w,
    ushort* __restrict__ out, int D)
{
    int row = blockIdx.x;
    const float* xr = in + (long)row * D;
    int nv = D >> 10;
    float4 vals[2];
    float ss = 0.f;
    for (int i = 0; i < nv; ++i) {
        vals[i] = *(const float4*)(xr + (threadIdx.x + i * 256) * 4);
        ss += vals[i].x*vals[i].x + vals[i].y*vals[i].y
            + vals[i].z*vals[i].z + vals[i].w*vals[i].w;
    }
    for (int off = 32; off; off >>= 1) ss += __shfl_down(ss, off, 64);
    __shared__ float red[4];
    if ((threadIdx.x & 63) == 0) red[threadIdx.x >> 6] = ss;
    __syncthreads();
    float tot = red[0] + red[1] + red[2] + red[3];
    float scale = rsqrtf(tot / (float)D + EPSF);
    ushort* orow = out + (long)row * D;
    for (int i = 0; i < nv; ++i) {
        int base = (threadIdx.x + i * 256) * 4;
        float4 v = vals[i];
        float4 wv = *(const float4*)(w + base);
        ushort4 o;
        o.x = f2bf(v.x * scale * wv.x); o.y = f2bf(v.y * scale * wv.y);
        o.z = f2bf(v.z * scale * wv.z); o.w = f2bf(v.w * scale * wv.w);
        *(ushort4*)(orow + base) = o;
    }
}

// ============================================================
// bf16 MFMA NT GEMM (batched, strided): C[m,n]=sum_k A[m,k]*W[n,k] (+resid)
// 128x128 tile, BK=64, 256 threads, mfma_f32_16x16x32_bf16.
// XOR-swizzled global_load_lds(16B) staging (see round-2 notes).
// Requires: M%128==0, K%64==0, W padded to ceil(N/128)*128 rows.
// ============================================================
__global__ __launch_bounds__(256) void gemm_bf16_kernel(
    const ushort* __restrict__ A, int lda, long sA,
    const ushort* __restrict__ W, int ldw, long sW,
    float* __restrict__ C, int ldc, long sC,
    const float* __restrict__ resid,
    int M, int N, int K)
{
    __shared__ ushort As[128 * 64];
    __shared__ ushort Bs[128 * 64];
    const int t = threadIdx.x;
    const int lane = t & 63;
    const int w = t >> 6;
    const int wm = w & 1, wn = w >> 1;
    const int lm = lane & 15, quad = lane >> 4;
    const int m0 = blockIdx.y * 128, n0 = blockIdx.x * 128;
    A += (long)blockIdx.z * sA;
    W += (long)blockIdx.z * sW;
    C += (long)blockIdx.z * sC;

    const ushort* ga[4]; const ushort* gw[4];
#pragma unroll
    for (int i = 0; i < 4; ++i) {
        int s = i * 256 + t;
        int row = s >> 3;
        int kseg = (s & 7) ^ (row & 7);
        ga[i] = A + (long)(m0 + row) * lda + kseg * 8;
        gw[i] = W + (long)(n0 + row) * ldw + kseg * 8;
    }

    f32x4 acc[4][4];
    f32x4 zero4 = {0.f, 0.f, 0.f, 0.f};
#pragma unroll
    for (int i = 0; i < 4; ++i)
#pragma unroll
        for (int j = 0; j < 4; ++j) acc[i][j] = zero4;

    int arow8[4], arow7[4], brow8[4], brow7[4];
#pragma unroll
    for (int i = 0; i < 4; ++i) {
        int ar = wm * 64 + i * 16 + lm;
        arow8[i] = ar * 8; arow7[i] = ar & 7;
        int br = wn * 64 + i * 16 + lm;
        brow8[i] = br * 8; brow7[i] = br & 7;
    }

    for (int k0 = 0; k0 < K; k0 += 64) {
#pragma unroll
        for (int i = 0; i < 4; ++i) {
            ASYNC_COPY16(ga[i], &As[(i * 256 + w * 64) * 8]);
            ASYNC_COPY16(gw[i], &Bs[(i * 256 + w * 64) * 8]);
            ga[i] += 64; gw[i] += 64;
        }
        __syncthreads();
#pragma unroll
        for (int ks = 0; ks < 2; ++ks) {
            bf16x8 af[4], bfr[4];
#pragma unroll
            for (int i = 0; i < 4; ++i) {
                af[i]  = *(const bf16x8*)&As[(arow8[i] + ((ks * 4 + quad) ^ arow7[i])) * 8];
                bfr[i] = *(const bf16x8*)&Bs[(brow8[i] + ((ks * 4 + quad) ^ brow7[i])) * 8];
            }
#pragma unroll
            for (int im = 0; im < 4; ++im)
#pragma unroll
                for (int in = 0; in < 4; ++in)
                    acc[im][in] = __builtin_amdgcn_mfma_f32_16x16x32_bf16(
                        af[im], bfr[in], acc[im][in], 0, 0, 0);
        }
        __syncthreads();
    }

#pragma unroll
    for (int in = 0; in < 4; ++in) {
        int col = n0 + wn * 64 + in * 16 + lm;
        if (col >= N) continue;
#pragma unroll
        for (int im = 0; im < 4; ++im) {
            int r0 = m0 + wm * 64 + im * 16 + quad * 4;
            f32x4 v = acc[im][in];
#pragma unroll
            for (int i = 0; i < 4; ++i) {
                long idx = (long)(r0 + i) * ldc + col;
                float o = v[i];
                if (resid) o += resid[idx];
                C[idx] = o;
            }
        }
    }
}

// ============================================================
// Depthwise causal conv (width 4) + SiLU -> bf16 xBC
// ============================================================
__global__ __launch_bounds__(256) void conv_silu_kernel(
    const float* __restrict__ zx, const float* __restrict__ cw,
    const float* __restrict__ cb, ushort* __restrict__ xBC_bf)
{
    int row = blockIdx.x;
    int c = blockIdx.y * 256 + threadIdx.x;
    int l = row & (LSEQ - 1);
    float acc = cb[c];
#pragma unroll
    for (int k = 0; k < DCONV; ++k) {
        int ls = l + k - (DCONV - 1);
        if (ls >= 0)
            acc += zx[(long)(row + k - (DCONV - 1)) * DINP + DINNER + c] * cw[c * DCONV + k];
    }
    xBC_bf[(long)row * CONVD + c] = f2bf(acc / (1.f + __expf(-acc)));
}

// ============================================================
// dt = softplus(dt_raw + dt_bias)
// ============================================================
__global__ __launch_bounds__(256) void dt_kernel(
    const float* __restrict__ zx, const float* __restrict__ dt_bias,
    float* __restrict__ dtv)
{
    int idx = blockIdx.x * 256 + threadIdx.x;
    int row = idx >> 5, h = idx & 31;
    float v = zx[(long)row * DINP + (DINP - NHEADS) + h] + dt_bias[h];
    float sp = (v > 20.f) ? v : log1pf(__expf(v));
    dtv[idx] = sp;
}

// ============================================================
// Per-chunk inclusive cumsum of dA
// ============================================================
__global__ __launch_bounds__(256) void acs_kernel(
    const float* __restrict__ dtv, const float* __restrict__ A_log,
    float* __restrict__ Acs)
{
    int bc = blockIdx.x, h = blockIdx.y;
    int l = threadIdx.x;
    int row = bc * CHUNK + l;
    float a = -dtv[row * NHEADS + h] * __expf(A_log[h]);
    __shared__ float buf[2][CHUNK];
    buf[0][l] = a; __syncthreads();
    int src = 0;
    for (int off = 1; off < CHUNK; off <<= 1) {
        float v = buf[src][l];
        if (l >= off) v += buf[src][l - off];
        buf[src ^ 1][l] = v;
        __syncthreads();
        src ^= 1;
    }
    Acs[(bc * NHEADS + h) * CHUNK + l] = buf[src][l];
}

// ============================================================
// Prep: per (bc, tile) LDS-transpose to K-contiguous bf16 operands.
//   yt<32 : Xdt_t[bc][c][l]=dt_l*x, Xcs_t[bc][c][l]=exp(T-acs_l)*dt_l*x
//   yt>=32: Bt[bc][n][l] = B[l][n]
// ============================================================
#define XT_PAD 264
__global__ __launch_bounds__(256) void prep_transpose_kernel(
    const ushort* __restrict__ xBC_bf, const float* __restrict__ dtv,
    const float* __restrict__ acs, ushort* __restrict__ Xdt_t,
    ushort* __restrict__ Xcs_t, ushort* __restrict__ Bt)
{
    int bc = blockIdx.x, yt = blockIdx.y;
    int t = threadIdx.x;
    int row0 = bc * CHUNK;
    __shared__ ushort t_dt[64 * XT_PAD];
    __shared__ ushort t_cs[64 * XT_PAD];
    __shared__ float dl[CHUNK], cl[CHUNK];
    bool isB = (yt >= 32);
    int src_c0 = isB ? (DINNER + (yt - 32) * 64) : (yt * 64);
    if (!isB) {
        int h = yt;
        float a = acs[(bc * NHEADS + h) * CHUNK + t];
        float d = dtv[(row0 + t) * NHEADS + h];
        float T = acs[(bc * NHEADS + h) * CHUNK + CHUNK - 1];
        dl[t] = d;
        cl[t] = __expf(T - a) * d;
    }
    __syncthreads();
    for (int iter = 0; iter < 8; ++iter) {
        int l = iter * 32 + (t >> 3);
        int cc = (t & 7) * 8;
        ushort u[8];
        *(ushort4*)&u[0] = *(const ushort4*)(xBC_bf + (long)(row0 + l) * CONVD + src_c0 + cc);
        *(ushort4*)&u[4] = *(const ushort4*)(xBC_bf + (long)(row0 + l) * CONVD + src_c0 + cc + 4);
        if (isB) {
#pragma unroll
            for (int j = 0; j < 8; ++j) t_dt[(cc + j) * XT_PAD + l] = u[j];
        } else {
            float sd = dl[l], sc = cl[l];
#pragma unroll
            for (int j = 0; j < 8; ++j) {
                float f = bf2f(u[j]);
                t_dt[(cc + j) * XT_PAD + l] = f2bf(f * sd);
                t_cs[(cc + j) * XT_PAD + l] = f2bf(f * sc);
            }
        }
    }
    __syncthreads();
    int r = t >> 2, seg = (t & 3) * 64;
    const ushort* s1 = &t_dt[r * XT_PAD + seg];
    if (isB) {
        ushort* dst = Bt + ((long)bc * DSTATE + (yt - 32) * 64 + r) * CHUNK + seg;
#pragma unroll
        for (int q = 0; q < 16; ++q)
            *(ushort4*)(dst + q * 4) = *(const ushort4*)(s1 + q * 4);
    } else {
        const ushort* s2 = &t_cs[r * XT_PAD + seg];
        ushort* d1 = Xdt_t + ((long)bc * DINNER + yt * 64 + r) * CHUNK + seg;
        ushort* d2 = Xcs_t + ((long)bc * DINNER + yt * 64 + r) * CHUNK + seg;
#pragma unroll
        for (int q = 0; q < 16; ++q) {
            *(ushort4*)(d1 + q * 4) = *(const ushort4*)(s1 + q * 4);
            *(ushort4*)(d2 + q * 4) = *(const ushort4*)(s2 + q * 4);
        }
    }
}

// ============================================================
// Chunk state via MFMA: S_t[p][n] = sum_l Xcs_t[p][l] * Bt[n][l]
// block = (bc,h), 4 waves: wave w covers n in [w*32,(w+1)*32)
// ============================================================
__global__ __launch_bounds__(256) void chunk_state_mfma_kernel(
    const ushort* __restrict__ Xcs_t, const ushort* __restrict__ Bt,
    float* __restrict__ state_t)
{
    int bc = blockIdx.x, h = blockIdx.y;
    int t = threadIdx.x, lane = t & 63, w = t >> 6;
    int lm = lane & 15, quad = lane >> 4;
    const ushort* Xb = Xcs_t + ((long)bc * DINNER + h * HEADDIM) * CHUNK;
    const ushort* Bb = Bt + (long)bc * DSTATE * CHUNK;
    f32x4 acc[4][2];
    f32x4 zero4 = {0.f, 0.f, 0.f, 0.f};
#pragma unroll
    for (int i = 0; i < 4; ++i) { acc[i][0] = zero4; acc[i][1] = zero4; }

    for (int kt = 0; kt < 8; ++kt) {
        int k = kt * 32 + quad * 8;
        bf16x8 af[4], bfr[2];
#pragma unroll
        for (int mi = 0; mi < 4; ++mi)
            af[mi] = *(const bf16x8*)(Xb + (long)(mi * 16 + lm) * CHUNK + k);
#pragma unroll
        for (int nj = 0; nj < 2; ++nj)
            bfr[nj] = *(const bf16x8*)(Bb + (long)(w * 32 + nj * 16 + lm) * CHUNK + k);
#pragma unroll
        for (int mi = 0; mi < 4; ++mi)
#pragma unroll
            for (int nj = 0; nj < 2; ++nj)
                acc[mi][nj] = __builtin_amdgcn_mfma_f32_16x16x32_bf16(
                    af[mi], bfr[nj], acc[mi][nj], 0, 0, 0);
    }
    float* sp = state_t + (long)(bc * NHEADS + h) * (DSTATE * HEADDIM);
#pragma unroll
    for (int mi = 0; mi < 4; ++mi)
#pragma unroll
        for (int nj = 0; nj < 2; ++nj) {
            int n = w * 32 + nj * 16 + lm;
#pragma unroll
            for (int i = 0; i < 4; ++i) {
                int p = mi * 16 + quad * 4 + i;
                sp[p * DSTATE + n] = acc[mi][nj][i];
            }
        }
}

// ============================================================
// Inter-chunk scan (in place, elementwise on [p][n] layout)
// ============================================================
__global__ __launch_bounds__(256) void state_scan_kernel(
    float* __restrict__ state, const float* __restrict__ Acs)
{
    long flat = (long)blockIdx.x * 256 + threadIdx.x;
    int e = (int)(flat & 8191);
    int bh = (int)(flat >> 13);
    int b = bh >> 5, h = bh & 31;
    float S = 0.f;
    for (int c = 0; c < NCH; ++c) {
        int bc = b * NCH + c;
        long idx = ((long)(bc * NHEADS + h)) * 8192 + e;
        float T = Acs[(bc * NHEADS + h) * CHUNK + CHUNK - 1];
        float tmp = state[idx];
        state[idx] = S;
        S = S * __expf(T) + tmp;
    }
}

// ============================================================
// SSD Y via MFMA: Y = P@Xdt + (C*eAl)@S_t^T, then +D*xh, silu(z) gate.
// block = (bc,h); 4 waves, wave w owns l in [w*64,(w+1)*64).
// P[l,s] = G2[l,s]*exp(acs_l-acs_s) for s<=l (built in-register).
// ============================================================
__global__ __launch_bounds__(256) void ssd_y_mfma_kernel(
    const ushort* __restrict__ xBC_bf, const ushort* __restrict__ Xdt_t,
    const float* __restrict__ G2, const float* __restrict__ acs,
    const float* __restrict__ state_t, const float* __restrict__ zxb,
    const float* __restrict__ Dh, ushort* __restrict__ ybf)
{
    int bc = blockIdx.x, h = blockIdx.y;
    int t = threadIdx.x, lane = t & 63, w = t >> 6;
    int lm = lane & 15, quad = lane >> 4;
    int row0 = bc * CHUNK;
    __shared__ float acs_s[CHUNK];
    acs_s[t] = acs[(bc * NHEADS + h) * CHUNK + t];
    __syncthreads();
    int lbase = w * 64;
    float acs_l[4], eAl[4];
#pragma unroll
    for (int mi = 0; mi < 4; ++mi) {
        acs_l[mi] = acs_s[lbase + mi * 16 + lm];
        eAl[mi] = __expf(acs_l[mi]);
    }
    f32x4 acc[4][4];
    f32x4 zero4 = {0.f, 0.f, 0.f, 0.f};
#pragma unroll
    for (int i = 0; i < 4; ++i)
#pragma unroll
        for (int j = 0; j < 4; ++j) acc[i][j] = zero4;

    const ushort* Xb = Xdt_t + ((long)bc * DINNER + h * HEADDIM) * CHUNK;
    const float* g2 = G2 + (long)bc * (CHUNK * CHUNK);

    // ---- phase A: diagonal (causal) ----
    for (int ks = 0; ks <= 2 * w + 1; ++ks) {
        int sq = ks * 32 + quad * 8;
        bf16x8 bfr[4];
#pragma unroll
        for (int ni = 0; ni < 4; ++ni)
            bfr[ni] = *(const bf16x8*)(Xb + (long)(ni * 16 + lm) * CHUNK + sq);
        float a8[8];
#pragma unroll
        for (int j = 0; j < 8; ++j) a8[j] = acs_s[sq + j];
#pragma unroll
        for (int mi = 0; mi < 4; ++mi) {
            int lmin = lbase + mi * 16;
            if (ks * 32 > lmin + 15) continue;       // fully masked tile
            int lv = lmin + lm;
            float al = acs_l[mi];
            const float* gp = g2 + (long)lv * CHUNK + sq;
            f32x4 gA = *(const f32x4*)gp;
            f32x4 gB = *(const f32x4*)(gp + 4);
            bf16x8 af;
#pragma unroll
            for (int j = 0; j < 4; ++j) {
                float v = gA[j] * __expf(al - a8[j]);
                af[j] = (sq + j > lv) ? (short)0 : fb(v);
            }
#pragma unroll
            for (int j = 0; j < 4; ++j) {
                float v = gB[j] * __expf(al - a8[4 + j]);
                af[4 + j] = (sq + 4 + j > lv) ? (short)0 : fb(v);
            }
#pragma unroll
            for (int ni = 0; ni < 4; ++ni)
                acc[mi][ni] = __builtin_amdgcn_mfma_f32_16x16x32_bf16(
                    af, bfr[ni], acc[mi][ni], 0, 0, 0);
        }
    }

    // ---- phase B: off-diagonal (C*eAl @ S_t^T) ----
    const float* sp = state_t + (long)(bc * NHEADS + h) * (DSTATE * HEADDIM);
    const ushort* Cb = xBC_bf + (long)row0 * CONVD + DINNER + DSTATE;
    for (int kt = 0; kt < 4; ++kt) {
        int n0 = kt * 32 + quad * 8;
        bf16x8 bfr[4];
#pragma unroll
        for (int ni = 0; ni < 4; ++ni) {
            const float* s8 = sp + (ni * 16 + lm) * DSTATE + n0;
            f32x4 sA = *(const f32x4*)s8;
            f32x4 sB = *(const f32x4*)(s8 + 4);
            bf16x8 v;
#pragma unroll
            for (int j = 0; j < 4; ++j) { v[j] = fb(sA[j]); v[4 + j] = fb(sB[j]); }
            bfr[ni] = v;
        }
#pragma unroll
        for (int mi = 0; mi < 4; ++mi) {
            int lv = lbase + mi * 16 + lm;
            bf16x8 cu = *(const bf16x8*)(Cb + (long)lv * CONVD + n0);
            bf16x8 ce;
            float e = eAl[mi];
#pragma unroll
            for (int j = 0; j < 8; ++j) ce[j] = fb(bf2f((ushort)cu[j]) * e);
#pragma unroll
            for (int ni = 0; ni < 4; ++ni)
                acc[mi][ni] = __builtin_amdgcn_mfma_f32_16x16x32_bf16(
                    ce, bfr[ni], acc[mi][ni], 0, 0, 0);
        }
    }

    // ---- epilogue: +D*xh, silu(z) gate, bf16 store ----
    float Dv = Dh[h];
#pragma unroll
    for (int mi = 0; mi < 4; ++mi)
#pragma unroll
        for (int i = 0; i < 4; ++i) {
            int l = lbase + mi * 16 + quad * 4 + i;
            long row = row0 + l;
#pragma unroll
            for (int ni = 0; ni < 4; ++ni) {
                int p = ni * 16 + lm;
                float xh = bf2f(xBC_bf[row * CONVD + h * HEADDIM + p]);
                float z = zxb[row * DINP + h * HEADDIM + p];
                float o = (acc[mi][ni][i] + Dv * xh) * (z / (1.f + __expf(-z)));
                ybf[row * DINNER + h * HEADDIM + p] = f2bf(o);
            }
        }
}

// ============================================================
// gnorm: bf16 RMSNorm in-place over D=2048 with weight
// ============================================================
__global__ __launch_bounds__(256) void gnorm_bf16_kernel(
    ushort* __restrict__ y, const float* __restrict__ gw)
{
    int row = blockIdx.x;
    ushort* yr = y + (long)row * DINNER;
    int base = threadIdx.x * 8;
    ushort4 a = *(ushort4*)(yr + base);
    ushort4 b = *(ushort4*)(yr + base + 4);
    float f[8] = {bf2f(a.x), bf2f(a.y), bf2f(a.z), bf2f(a.w),
                  bf2f(b.x), bf2f(b.y), bf2f(b.z), bf2f(b.w)};
    float ss = 0.f;
#pragma unroll
    for (int i = 0; i < 8; ++i) ss += f[i] * f[i];
    for (int off = 32; off; off >>= 1) ss += __shfl_down(ss, off, 64);
    __shared__ float red[4];
    if ((threadIdx.x & 63) == 0) red[threadIdx.x >> 6] = ss;
    __syncthreads();
    float tot = red[0] + red[1] + red[2] + red[3];
    float scale = rsqrtf(tot * (1.f / (float)DINNER) + EPSF);
    float4 g0 = *(const float4*)(gw + base);
    float4 g1 = *(const float4*)(gw + base + 4);
    ushort4 oa, ob;
    oa.x = f2bf(f[0] * scale * g0.x); oa.y = f2bf(f[1] * scale * g0.y);
    oa.z = f2bf(f[2] * scale * g0.z); oa.w = f2bf(f[3] * scale * g0.w);
    ob.x = f2bf(f[4] * scale * g1.x); ob.y = f2bf(f[5] * scale * g1.y);
    ob.z = f2bf(f[6] * scale * g1.z); ob.w = f2bf(f[7] * scale * g1.w);
    *(ushort4*)(yr + base) = oa;
    *(ushort4*)(yr + base + 4) = ob;
}

// ============================================================
// launch
// ============================================================
extern "C" void kernel_launch(void* const* d_in, const int* in_sizes, int n_in,
                              void* d_out, int out_size, void* d_ws, size_t ws_size,
                              hipStream_t stream)
{
    (void)in_sizes; (void)n_in; (void)out_size; (void)ws_size;
    const float* x          = (const float*)d_in[0];
    const float* norm_w     = (const float*)d_in[1];
    const float* in_proj_w  = (const float*)d_in[2];
    const float* conv_w     = (const float*)d_in[3];
    const float* conv_b     = (const float*)d_in[4];
    const float* dt_bias    = (const float*)d_in[5];
    const float* A_log      = (const float*)d_in[6];
    const float* Dh         = (const float*)d_in[7];
    const float* gnorm_w    = (const float*)d_in[8];
    const float* out_proj_w = (const float*)d_in[9];
    float* out = (float*)d_out;
    float* ws = (float*)d_ws;

    // workspace layout (float slots); total 42,270,720 = 169.1 MB
    float* zxb     = ws;                       // 17,956,864
    float* xbc_f   = zxb     + 17956864;       //  4,718,592 (bf16 4096x2304)
    float* dtv     = xbc_f   + 4718592;        //    131,072
    float* acs     = dtv     + 131072;         //    131,072
    float* G2      = acs     + 131072;         //  1,048,576 ([bc][l][s] fp32)
    float* state_t = G2      + 1048576;        //  4,194,304 ([bc][h][p][n] fp32)
    float* xdt_f   = state_t + 4194304;        //  4,194,304 (bf16 [bc][c][l])
    float* xcs_f   = xdt_f   + 4194304;        //  4,194,304 (bf16 [bc][c][l])
    float* bt_f    = xcs_f   + 4194304;        //    262,144 (bf16 [bc][n][l])
    float* regU    = bt_f    + 262144;         //  4,390,912 (xn_bf+wi_bf, later ybf)
    float* wo_f    = regU    + 4390912;        //  1,048,576 (wo_bf)

    ushort* xBC_bf = (ushort*)xbc_f;
    ushort* Xdt_t  = (ushort*)xdt_f;
    ushort* Xcs_t  = (ushort*)xcs_f;
    ushort* Bt     = (ushort*)bt_f;
    ushort* xn_bf  = (ushort*)regU;                 // 4096x1024 [dead after in_proj]
    ushort* wi_bf  = (ushort*)(regU + 2097152);     // 4480x1024 [dead after in_proj]
    ushort* ybf    = (ushort*)regU;                 // 4096x2048 [born at ssd_y]
    ushort* wo_bf  = (ushort*)wo_f;

    // 0. convert weights to bf16
    cvt_w_kernel<<<dim3(NPAD_IN * DMODEL / 1024), 256, 0, stream>>>(
        in_proj_w, wi_bf, DINP, 10);
    cvt_w_kernel<<<dim3(DMODEL * DINNER / 1024), 256, 0, stream>>>(
        out_proj_w, wo_bf, DMODEL, 11);

    // 1. xn = RMSNorm(x)*norm_w -> bf16
    rmsnorm_bf16_kernel<<<dim3(NROWS), 256, 0, stream>>>(x, norm_w, xn_bf, DMODEL);

    // 2. zxbcdt = xn @ in_proj_w^T (M=4096, N=4384 pad 4480, K=1024)
    gemm_bf16_kernel<<<dim3(NPAD_IN / 128, NROWS / 128), 256, 0, stream>>>(
        xn_bf, DMODEL, 0, wi_bf, DMODEL, 0, zxb, DINP, 0,
        nullptr, NROWS, DINP, DMODEL);

    // 3. conv + SiLU -> bf16 xBC
    conv_silu_kernel<<<dim3(NROWS, 9), 256, 0, stream>>>(zxb, conv_w, conv_b, xBC_bf);

    // 4. dt softplus
    dt_kernel<<<dim3(NROWS * NHEADS / 256), 256, 0, stream>>>(zxb, dt_bias, dtv);

    // 5. per-chunk cumsum
    acs_kernel<<<dim3(BB * NCH, NHEADS), 256, 0, stream>>>(dtv, A_log, acs);

    // 6. prep transposed bf16 operands (Xdt_t, Xcs_t, Bt)
    prep_transpose_kernel<<<dim3(BB * NCH, 34), 256, 0, stream>>>(
        xBC_bf, dtv, acs, Xdt_t, Xcs_t, Bt);

    // 7. G2[bc][l][s] = C_l . B_s (bf16 MFMA, batched; M=N=256, K=128)
    gemm_bf16_kernel<<<dim3(2, 2, BB * NCH), 256, 0, stream>>>(
        xBC_bf + DINNER + DSTATE, CONVD, (long)CHUNK * CONVD,
        xBC_bf + DINNER, CONVD, (long)CHUNK * CONVD,
        G2, CHUNK, (long)CHUNK * CHUNK,
        nullptr, CHUNK, CHUNK, DSTATE);

    // 8. chunk states (MFMA) -> state_t[bc][h][p][n]
    chunk_state_mfma_kernel<<<dim3(BB * NCH, NHEADS), 256, 0, stream>>>(
        Xcs_t, Bt, state_t);

    // 9. inter-chunk scan
    state_scan_kernel<<<dim3(BB * NHEADS * 8192 / 256), 256, 0, stream>>>(state_t, acs);

    // 10. Y (MFMA diag+off) + D*xh, silu(z) gate -> ybf
    ssd_y_mfma_kernel<<<dim3(BB * NCH, NHEADS), 256, 0, stream>>>(
        xBC_bf, Xdt_t, G2, acs, state_t, zxb, Dh, ybf);

    // 11. gnorm (bf16 in place)
    gnorm_bf16_kernel<<<dim3(NROWS), 256, 0, stream>>>(ybf, gnorm_w);

    // 12. out = x + y @ out_proj_w^T (M=4096, N=1024, K=2048)
    gemm_bf16_kernel<<<dim3(DMODEL / 128, NROWS / 128), 256, 0, stream>>>(
        ybf, DINNER, 0, wo_bf, DINNER, 0, out, DMODEL, 0,
        x, NROWS, DMODEL, DINNER);
}

// Round 4
// 390.578 us; speedup vs baseline: 3.3659x; 1.0323x over previous
//
#include <hip/hip_runtime.h>
#include <hip/hip_bf16.h>

// ---- problem constants ----
#define BB      2
#define LSEQ    2048
#define DMODEL  1024
#define DSTATE  128
#define DCONV   4
#define HEADDIM 64
#define DINNER  2048      // EXP*DMODEL
#define NHEADS  32        // DINNER/HEADDIM
#define CONVD   2304      // DINNER + 2*DSTATE
#define DINP    4384      // 2*DINNER + 2*DSTATE + NHEADS
#define NPAD_IN 4480      // 35*128, padded in_proj rows
#define CHUNK   256
#define NCH     8         // LSEQ/CHUNK
#define NROWS   4096      // BB*LSEQ
#define EPSF    1e-5f

typedef __attribute__((ext_vector_type(8))) short bf16x8;
typedef __attribute__((ext_vector_type(4))) float f32x4;

#define ASYNC_COPY16(gptr, lptr) \
    __builtin_amdgcn_global_load_lds((const __attribute__((address_space(1))) void*)(gptr), \
                                     (__attribute__((address_space(3))) void*)(lptr), 16, 0, 0)

__device__ __forceinline__ ushort f2bf(float f) {
    __hip_bfloat16 h = __float2bfloat16(f);
    return *(ushort*)&h;
}
__device__ __forceinline__ float bf2f(ushort u) {
    return __uint_as_float(((unsigned)u) << 16);
}
__device__ __forceinline__ short fb(float f) { return (short)f2bf(f); }

// ============================================================
// Weight convert fp32 -> bf16 with row padding (zeros for n >= N)
// ============================================================
__global__ __launch_bounds__(256) void cvt_w_kernel(
    const float* __restrict__ src, ushort* __restrict__ dst,
    int N, int kshift)
{
    long i4 = ((long)blockIdx.x * 256 + threadIdx.x) * 4;
    int n = (int)(i4 >> kshift);
    long k = i4 & ((1L << kshift) - 1);
    ushort4 o;
    if (n < N) {
        float4 v = *(const float4*)(src + ((long)n << kshift) + k);
        o.x = f2bf(v.x); o.y = f2bf(v.y); o.z = f2bf(v.z); o.w = f2bf(v.w);
    } else {
        o.x = o.y = o.z = o.w = 0;
    }
    *(ushort4*)(dst + i4) = o;
}

// ============================================================
// RMSNorm fp32 in -> bf16 out (D=1024)
// ============================================================
__global__ __launch_bounds__(256) void rmsnorm_bf16_kernel(
    const float* __restrict__ in, const float* __restrict__ w,
    ushort* __restrict__ out, int D)
{
    int row = blockIdx.x;
    const float* xr = in + (long)row * D;
    int nv = D >> 10;
    float4 vals[2];
    float ss = 0.f;
    for (int i = 0; i < nv; ++i) {
        vals[i] = *(const float4*)(xr + (threadIdx.x + i * 256) * 4);
        ss += vals[i].x*vals[i].x + vals[i].y*vals[i].y
            + vals[i].z*vals[i].z + vals[i].w*vals[i].w;
    }
    for (int off = 32; off; off >>= 1) ss += __shfl_down(ss, off, 64);
    __shared__ float red[4];
    if ((threadIdx.x & 63) == 0) red[threadIdx.x >> 6] = ss;
    __syncthreads();
    float tot = red[0] + red[1] + red[2] + red[3];
    float scale = rsqrtf(tot / (float)D + EPSF);
    ushort* orow = out + (long)row * D;
    for (int i = 0; i < nv; ++i) {
        int base = (threadIdx.x + i * 256) * 4;
        float4 v = vals[i];
        float4 wv = *(const float4*)(w + base);
        ushort4 o;
        o.x = f2bf(v.x * scale * wv.x); o.y = f2bf(v.y * scale * wv.y);
        o.z = f2bf(v.z * scale * wv.z); o.w = f2bf(v.w * scale * wv.w);
        *(ushort4*)(orow + base) = o;
    }
}

// ============================================================
// bf16 MFMA NT GEMM (batched, strided, swizzled 1D grid):
//   C[m,n] = sum_k A[m,k]*W[n,k]  (+resid for fp32 out)
// 128x128 tile, BK=64, mfma_f32_16x16x32_bf16, XOR-swizzled
// global_load_lds(16B) staging. Epilogue bounces through LDS so
// global stores are full-cacheline coalesced (bf16 or fp32 out).
// Requires: M%128==0, K%64==0, W padded to ntiles*128 rows, N%8==0.
// ============================================================
__global__ __launch_bounds__(256) void gemm_bf16_kernel(
    const ushort* __restrict__ A, int lda, long sA,
    const ushort* __restrict__ W, int ldw, long sW,
    void* __restrict__ Cout, int ldc, long sC, int c_bf16,
    const float* __restrict__ resid,
    int mtiles, int ntiles, int N, int K)
{
    __shared__ __align__(16) char smem[34816];
    ushort* As = (ushort*)smem;          // 128*64 ushort = 16 KB
    ushort* Bs = As + 128 * 64;          // 16 KB
    ushort* tu = (ushort*)smem;          // epilogue bf16 tile [128][136]
    float*  tf = (float*)smem;           // epilogue fp32 tile [128][68]

    const int t = threadIdx.x;
    const int lane = t & 63;
    const int w = t >> 6;
    const int wm = w & 1, wn = w >> 1;
    const int lm = lane & 15, quad = lane >> 4;

    // grouped swizzle (GM=8) for L2/L3 tile reuse
    int pid = blockIdx.x;
    const int GM = 8;
    int width = GM * ntiles;
    int group = pid / width;
    int first_m = group * GM;
    int gsz = mtiles - first_m; if (gsz > GM) gsz = GM;
    int mt = first_m + (pid % width) % gsz;
    int nt = (pid % width) / gsz;
    const int m0 = mt * 128, n0 = nt * 128;

    A += (long)blockIdx.z * sA;
    W += (long)blockIdx.z * sW;

    const ushort* ga[4]; const ushort* gw[4];
#pragma unroll
    for (int i = 0; i < 4; ++i) {
        int s = i * 256 + t;
        int row = s >> 3;
        int kseg = (s & 7) ^ (row & 7);
        ga[i] = A + (long)(m0 + row) * lda + kseg * 8;
        gw[i] = W + (long)(n0 + row) * ldw + kseg * 8;
    }

    f32x4 acc[4][4];
    f32x4 zero4 = {0.f, 0.f, 0.f, 0.f};
#pragma unroll
    for (int i = 0; i < 4; ++i)
#pragma unroll
        for (int j = 0; j < 4; ++j) acc[i][j] = zero4;

    int arow8[4], arow7[4], brow8[4], brow7[4];
#pragma unroll
    for (int i = 0; i < 4; ++i) {
        int ar = wm * 64 + i * 16 + lm;
        arow8[i] = ar * 8; arow7[i] = ar & 7;
        int br = wn * 64 + i * 16 + lm;
        brow8[i] = br * 8; brow7[i] = br & 7;
    }

    for (int k0 = 0; k0 < K; k0 += 64) {
#pragma unroll
        for (int i = 0; i < 4; ++i) {
            ASYNC_COPY16(ga[i], &As[(i * 256 + w * 64) * 8]);
            ASYNC_COPY16(gw[i], &Bs[(i * 256 + w * 64) * 8]);
            ga[i] += 64; gw[i] += 64;
        }
        __syncthreads();
#pragma unroll
        for (int ks = 0; ks < 2; ++ks) {
            bf16x8 af[4], bfr[4];
#pragma unroll
            for (int i = 0; i < 4; ++i) {
                af[i]  = *(const bf16x8*)&As[(arow8[i] + ((ks * 4 + quad) ^ arow7[i])) * 8];
                bfr[i] = *(const bf16x8*)&Bs[(brow8[i] + ((ks * 4 + quad) ^ brow7[i])) * 8];
            }
#pragma unroll
            for (int im = 0; im < 4; ++im)
#pragma unroll
                for (int in = 0; in < 4; ++in)
                    acc[im][in] = __builtin_amdgcn_mfma_f32_16x16x32_bf16(
                        af[im], bfr[in], acc[im][in], 0, 0, 0);
        }
        __syncthreads();
    }

    // ---- epilogue: LDS bounce -> coalesced full-line stores ----
    if (c_bf16) {
        ushort* C = (ushort*)Cout + (long)blockIdx.z * sC;
#pragma unroll
        for (int mi = 0; mi < 4; ++mi)
#pragma unroll
            for (int ni = 0; ni < 4; ++ni) {
                int c = wn * 64 + ni * 16 + lm;
#pragma unroll
                for (int i = 0; i < 4; ++i) {
                    int r = wm * 64 + mi * 16 + quad * 4 + i;
                    tu[r * 136 + c] = f2bf(acc[mi][ni][i]);
                }
            }
        __syncthreads();
        int r = t >> 1, cb = (t & 1) * 64;
        long rowbase = (long)(m0 + r) * ldc + n0 + cb;
#pragma unroll
        for (int q = 0; q < 8; ++q) {
            int gcol = n0 + cb + q * 8;
            if (gcol < N)
                *(bf16x8*)(C + rowbase + q * 8) =
                    *(const bf16x8*)&tu[r * 136 + cb + q * 8];
        }
    } else {
        float* C = (float*)Cout + (long)blockIdx.z * sC;
#pragma unroll
        for (int p = 0; p < 2; ++p) {
            if (wn == p) {
#pragma unroll
                for (int mi = 0; mi < 4; ++mi)
#pragma unroll
                    for (int ni = 0; ni < 4; ++ni) {
                        int c = ni * 16 + lm;
#pragma unroll
                        for (int i = 0; i < 4; ++i) {
                            int r = wm * 64 + mi * 16 + quad * 4 + i;
                            tf[r * 68 + c] = acc[mi][ni][i];
                        }
                    }
            }
            __syncthreads();
            int r = t >> 1, cb = (t & 1) * 32;
            long gbase = (long)(m0 + r) * ldc + n0 + p * 64 + cb;
#pragma unroll
            for (int q = 0; q < 8; ++q) {
                float4 v = *(const float4*)&tf[r * 68 + cb + q * 4];
                if (resid) {
                    float4 rv = *(const float4*)(resid + gbase + q * 4);
                    v.x += rv.x; v.y += rv.y; v.z += rv.z; v.w += rv.w;
                }
                *(float4*)(C + gbase + q * 4) = v;
            }
            __syncthreads();
        }
    }
}

// ============================================================
// Depthwise causal conv (width 4) + SiLU on bf16 zxb -> bf16 xBC
// ============================================================
__global__ __launch_bounds__(256) void conv_silu_kernel(
    const ushort* __restrict__ zx, const float* __restrict__ cw,
    const float* __restrict__ cb, ushort* __restrict__ xBC_bf)
{
    int row = blockIdx.x;
    int c = blockIdx.y * 256 + threadIdx.x;
    int l = row & (LSEQ - 1);
    float acc = cb[c];
#pragma unroll
    for (int k = 0; k < DCONV; ++k) {
        int ls = l + k - (DCONV - 1);
        if (ls >= 0)
            acc += bf2f(zx[(long)(row + k - (DCONV - 1)) * DINP + DINNER + c]) * cw[c * DCONV + k];
    }
    xBC_bf[(long)row * CONVD + c] = f2bf(acc / (1.f + __expf(-acc)));
}

// ============================================================
// Fused dt softplus + per-chunk inclusive cumsum of dA
// block = (bc, h); also writes dtv
// ============================================================
__global__ __launch_bounds__(256) void acs_kernel(
    const ushort* __restrict__ zx, const float* __restrict__ dt_bias,
    const float* __restrict__ A_log, float* __restrict__ dtv,
    float* __restrict__ Acs)
{
    int bc = blockIdx.x, h = blockIdx.y;
    int l = threadIdx.x;
    int row = bc * CHUNK + l;
    float v = bf2f(zx[(long)row * DINP + (DINP - NHEADS) + h]) + dt_bias[h];
    float d = (v > 20.f) ? v : log1pf(__expf(v));
    dtv[row * NHEADS + h] = d;
    float a = -d * __expf(A_log[h]);
    __shared__ float buf[2][CHUNK];
    buf[0][l] = a; __syncthreads();
    int src = 0;
    for (int off = 1; off < CHUNK; off <<= 1) {
        float vv = buf[src][l];
        if (l >= off) vv += buf[src][l - off];
        buf[src ^ 1][l] = vv;
        __syncthreads();
        src ^= 1;
    }
    Acs[(bc * NHEADS + h) * CHUNK + l] = buf[src][l];
}

// ============================================================
// Prep: per (bc, tile) LDS-transpose to K-contiguous bf16 operands.
// ============================================================
#define XT_PAD 264
__global__ __launch_bounds__(256) void prep_transpose_kernel(
    const ushort* __restrict__ xBC_bf, const float* __restrict__ dtv,
    const float* __restrict__ acs, ushort* __restrict__ Xdt_t,
    ushort* __restrict__ Xcs_t, ushort* __restrict__ Bt)
{
    int bc = blockIdx.x, yt = blockIdx.y;
    int t = threadIdx.x;
    int row0 = bc * CHUNK;
    __shared__ ushort t_dt[64 * XT_PAD];
    __shared__ ushort t_cs[64 * XT_PAD];
    __shared__ float dl[CHUNK], cl[CHUNK];
    bool isB = (yt >= 32);
    int src_c0 = isB ? (DINNER + (yt - 32) * 64) : (yt * 64);
    if (!isB) {
        int h = yt;
        float a = acs[(bc * NHEADS + h) * CHUNK + t];
        float d = dtv[(row0 + t) * NHEADS + h];
        float T = acs[(bc * NHEADS + h) * CHUNK + CHUNK - 1];
        dl[t] = d;
        cl[t] = __expf(T - a) * d;
    }
    __syncthreads();
    for (int iter = 0; iter < 8; ++iter) {
        int l = iter * 32 + (t >> 3);
        int cc = (t & 7) * 8;
        ushort u[8];
        *(ushort4*)&u[0] = *(const ushort4*)(xBC_bf + (long)(row0 + l) * CONVD + src_c0 + cc);
        *(ushort4*)&u[4] = *(const ushort4*)(xBC_bf + (long)(row0 + l) * CONVD + src_c0 + cc + 4);
        if (isB) {
#pragma unroll
            for (int j = 0; j < 8; ++j) t_dt[(cc + j) * XT_PAD + l] = u[j];
        } else {
            float sd = dl[l], sc = cl[l];
#pragma unroll
            for (int j = 0; j < 8; ++j) {
                float f = bf2f(u[j]);
                t_dt[(cc + j) * XT_PAD + l] = f2bf(f * sd);
                t_cs[(cc + j) * XT_PAD + l] = f2bf(f * sc);
            }
        }
    }
    __syncthreads();
    int r = t >> 2, seg = (t & 3) * 64;
    const ushort* s1 = &t_dt[r * XT_PAD + seg];
    if (isB) {
        ushort* dst = Bt + ((long)bc * DSTATE + (yt - 32) * 64 + r) * CHUNK + seg;
#pragma unroll
        for (int q = 0; q < 16; ++q)
            *(ushort4*)(dst + q * 4) = *(const ushort4*)(s1 + q * 4);
    } else {
        const ushort* s2 = &t_cs[r * XT_PAD + seg];
        ushort* d1 = Xdt_t + ((long)bc * DINNER + yt * 64 + r) * CHUNK + seg;
        ushort* d2 = Xcs_t + ((long)bc * DINNER + yt * 64 + r) * CHUNK + seg;
#pragma unroll
        for (int q = 0; q < 16; ++q) {
            *(ushort4*)(d1 + q * 4) = *(const ushort4*)(s1 + q * 4);
            *(ushort4*)(d2 + q * 4) = *(const ushort4*)(s2 + q * 4);
        }
    }
}

// ============================================================
// Chunk state via MFMA: S_t[p][n] = sum_l Xcs_t[p][l] * Bt[n][l]
// ============================================================
__global__ __launch_bounds__(256) void chunk_state_mfma_kernel(
    const ushort* __restrict__ Xcs_t, const ushort* __restrict__ Bt,
    float* __restrict__ state_t)
{
    int bc = blockIdx.x, h = blockIdx.y;
    int t = threadIdx.x, lane = t & 63, w = t >> 6;
    int lm = lane & 15, quad = lane >> 4;
    const ushort* Xb = Xcs_t + ((long)bc * DINNER + h * HEADDIM) * CHUNK;
    const ushort* Bb = Bt + (long)bc * DSTATE * CHUNK;
    f32x4 acc[4][2];
    f32x4 zero4 = {0.f, 0.f, 0.f, 0.f};
#pragma unroll
    for (int i = 0; i < 4; ++i) { acc[i][0] = zero4; acc[i][1] = zero4; }

    for (int kt = 0; kt < 8; ++kt) {
        int k = kt * 32 + quad * 8;
        bf16x8 af[4], bfr[2];
#pragma unroll
        for (int mi = 0; mi < 4; ++mi)
            af[mi] = *(const bf16x8*)(Xb + (long)(mi * 16 + lm) * CHUNK + k);
#pragma unroll
        for (int nj = 0; nj < 2; ++nj)
            bfr[nj] = *(const bf16x8*)(Bb + (long)(w * 32 + nj * 16 + lm) * CHUNK + k);
#pragma unroll
        for (int mi = 0; mi < 4; ++mi)
#pragma unroll
            for (int nj = 0; nj < 2; ++nj)
                acc[mi][nj] = __builtin_amdgcn_mfma_f32_16x16x32_bf16(
                    af[mi], bfr[nj], acc[mi][nj], 0, 0, 0);
    }
    float* sp = state_t + (long)(bc * NHEADS + h) * (DSTATE * HEADDIM);
#pragma unroll
    for (int mi = 0; mi < 4; ++mi)
#pragma unroll
        for (int nj = 0; nj < 2; ++nj) {
            int n = w * 32 + nj * 16 + lm;
#pragma unroll
            for (int i = 0; i < 4; ++i) {
                int p = mi * 16 + quad * 4 + i;
                sp[p * DSTATE + n] = acc[mi][nj][i];
            }
        }
}

// ============================================================
// Inter-chunk scan (in place)
// ============================================================
__global__ __launch_bounds__(256) void state_scan_kernel(
    float* __restrict__ state, const float* __restrict__ Acs)
{
    long flat = (long)blockIdx.x * 256 + threadIdx.x;
    int e = (int)(flat & 8191);
    int bh = (int)(flat >> 13);
    int b = bh >> 5, h = bh & 31;
    float S = 0.f;
    for (int c = 0; c < NCH; ++c) {
        int bc = b * NCH + c;
        long idx = ((long)(bc * NHEADS + h)) * 8192 + e;
        float T = Acs[(bc * NHEADS + h) * CHUNK + CHUNK - 1];
        float tmp = state[idx];
        state[idx] = S;
        S = S * __expf(T) + tmp;
    }
}

// ============================================================
// SSD Y via MFMA: Y = P@Xdt + (C*eAl)@S_t^T, then +D*xh, silu(z) gate.
// ============================================================
__global__ __launch_bounds__(256) void ssd_y_mfma_kernel(
    const ushort* __restrict__ xBC_bf, const ushort* __restrict__ Xdt_t,
    const ushort* __restrict__ G2b, const float* __restrict__ acs,
    const float* __restrict__ state_t, const ushort* __restrict__ zxb,
    const float* __restrict__ Dh, ushort* __restrict__ ybf)
{
    int bc = blockIdx.x, h = blockIdx.y;
    int t = threadIdx.x, lane = t & 63, w = t >> 6;
    int lm = lane & 15, quad = lane >> 4;
    int row0 = bc * CHUNK;
    __shared__ float acs_s[CHUNK];
    acs_s[t] = acs[(bc * NHEADS + h) * CHUNK + t];
    __syncthreads();
    int lbase = w * 64;
    float acs_l[4], eAl[4];
#pragma unroll
    for (int mi = 0; mi < 4; ++mi) {
        acs_l[mi] = acs_s[lbase + mi * 16 + lm];
        eAl[mi] = __expf(acs_l[mi]);
    }
    f32x4 acc[4][4];
    f32x4 zero4 = {0.f, 0.f, 0.f, 0.f};
#pragma unroll
    for (int i = 0; i < 4; ++i)
#pragma unroll
        for (int j = 0; j < 4; ++j) acc[i][j] = zero4;

    const ushort* Xb = Xdt_t + ((long)bc * DINNER + h * HEADDIM) * CHUNK;
    const ushort* g2 = G2b + (long)bc * (CHUNK * CHUNK);

    // ---- phase A: diagonal (causal) ----
    for (int ks = 0; ks <= 2 * w + 1; ++ks) {
        int sq = ks * 32 + quad * 8;
        bf16x8 bfr[4];
#pragma unroll
        for (int ni = 0; ni < 4; ++ni)
            bfr[ni] = *(const bf16x8*)(Xb + (long)(ni * 16 + lm) * CHUNK + sq);
        float a8[8];
#pragma unroll
        for (int j = 0; j < 8; ++j) a8[j] = acs_s[sq + j];
#pragma unroll
        for (int mi = 0; mi < 4; ++mi) {
            int lmin = lbase + mi * 16;
            if (ks * 32 > lmin + 15) continue;
            int lv = lmin + lm;
            float al = acs_l[mi];
            bf16x8 g8 = *(const bf16x8*)(g2 + (long)lv * CHUNK + sq);
            bf16x8 af;
#pragma unroll
            for (int j = 0; j < 8; ++j) {
                float v = bf2f((ushort)g8[j]) * __expf(al - a8[j]);
                af[j] = (sq + j > lv) ? (short)0 : fb(v);
            }
#pragma unroll
            for (int ni = 0; ni < 4; ++ni)
                acc[mi][ni] = __builtin_amdgcn_mfma_f32_16x16x32_bf16(
                    af, bfr[ni], acc[mi][ni], 0, 0, 0);
        }
    }

    // ---- phase B: off-diagonal (C*eAl @ S_t^T) ----
    const float* sp = state_t + (long)(bc * NHEADS + h) * (DSTATE * HEADDIM);
    const ushort* Cb = xBC_bf + (long)row0 * CONVD + DINNER + DSTATE;
    for (int kt = 0; kt < 4; ++kt) {
        int n0 = kt * 32 + quad * 8;
        bf16x8 bfr[4];
#pragma unroll
        for (int ni = 0; ni < 4; ++ni) {
            const float* s8 = sp + (ni * 16 + lm) * DSTATE + n0;
            f32x4 sA = *(const f32x4*)s8;
            f32x4 sB = *(const f32x4*)(s8 + 4);
            bf16x8 v;
#pragma unroll
            for (int j = 0; j < 4; ++j) { v[j] = fb(sA[j]); v[4 + j] = fb(sB[j]); }
            bfr[ni] = v;
        }
#pragma unroll
        for (int mi = 0; mi < 4; ++mi) {
            int lv = lbase + mi * 16 + lm;
            bf16x8 cu = *(const bf16x8*)(Cb + (long)lv * CONVD + n0);
            bf16x8 ce;
            float e = eAl[mi];
#pragma unroll
            for (int j = 0; j < 8; ++j) ce[j] = fb(bf2f((ushort)cu[j]) * e);
#pragma unroll
            for (int ni = 0; ni < 4; ++ni)
                acc[mi][ni] = __builtin_amdgcn_mfma_f32_16x16x32_bf16(
                    ce, bfr[ni], acc[mi][ni], 0, 0, 0);
        }
    }

    // ---- epilogue: +D*xh, silu(z) gate, bf16 store ----
    float Dv = Dh[h];
#pragma unroll
    for (int mi = 0; mi < 4; ++mi)
#pragma unroll
        for (int i = 0; i < 4; ++i) {
            int l = lbase + mi * 16 + quad * 4 + i;
            long row = row0 + l;
#pragma unroll
            for (int ni = 0; ni < 4; ++ni) {
                int p = ni * 16 + lm;
                float xh = bf2f(xBC_bf[row * CONVD + h * HEADDIM + p]);
                float z = bf2f(zxb[row * DINP + h * HEADDIM + p]);
                float o = (acc[mi][ni][i] + Dv * xh) * (z / (1.f + __expf(-z)));
                ybf[row * DINNER + h * HEADDIM + p] = f2bf(o);
            }
        }
}

// ============================================================
// gnorm: bf16 RMSNorm in-place over D=2048 with weight
// ============================================================
__global__ __launch_bounds__(256) void gnorm_bf16_kernel(
    ushort* __restrict__ y, const float* __restrict__ gw)
{
    int row = blockIdx.x;
    ushort* yr = y + (long)row * DINNER;
    int base = threadIdx.x * 8;
    ushort4 a = *(ushort4*)(yr + base);
    ushort4 b = *(ushort4*)(yr + base + 4);
    float f[8] = {bf2f(a.x), bf2f(a.y), bf2f(a.z), bf2f(a.w),
                  bf2f(b.x), bf2f(b.y), bf2f(b.z), bf2f(b.w)};
    float ss = 0.f;
#pragma unroll
    for (int i = 0; i < 8; ++i) ss += f[i] * f[i];
    for (int off = 32; off; off >>= 1) ss += __shfl_down(ss, off, 64);
    __shared__ float red[4];
    if ((threadIdx.x & 63) == 0) red[threadIdx.x >> 6] = ss;
    __syncthreads();
    float tot = red[0] + red[1] + red[2] + red[3];
    float scale = rsqrtf(tot * (1.f / (float)DINNER) + EPSF);
    float4 g0 = *(const float4*)(gw + base);
    float4 g1 = *(const float4*)(gw + base + 4);
    ushort4 oa, ob;
    oa.x = f2bf(f[0] * scale * g0.x); oa.y = f2bf(f[1] * scale * g0.y);
    oa.z = f2bf(f[2] * scale * g0.z); oa.w = f2bf(f[3] * scale * g0.w);
    ob.x = f2bf(f[4] * scale * g1.x); ob.y = f2bf(f[5] * scale * g1.y);
    ob.z = f2bf(f[6] * scale * g1.z); ob.w = f2bf(f[7] * scale * g1.w);
    *(ushort4*)(yr + base) = oa;
    *(ushort4*)(yr + base + 4) = ob;
}

// ============================================================
// launch
// ============================================================
extern "C" void kernel_launch(void* const* d_in, const int* in_sizes, int n_in,
                              void* d_out, int out_size, void* d_ws, size_t ws_size,
                              hipStream_t stream)
{
    (void)in_sizes; (void)n_in; (void)out_size; (void)ws_size;
    const float* x          = (const float*)d_in[0];
    const float* norm_w     = (const float*)d_in[1];
    const float* in_proj_w  = (const float*)d_in[2];
    const float* conv_w     = (const float*)d_in[3];
    const float* conv_b     = (const float*)d_in[4];
    const float* dt_bias    = (const float*)d_in[5];
    const float* A_log      = (const float*)d_in[6];
    const float* Dh         = (const float*)d_in[7];
    const float* gnorm_w    = (const float*)d_in[8];
    const float* out_proj_w = (const float*)d_in[9];
    float* out = (float*)d_out;
    float* ws = (float*)d_ws;

    // workspace layout (float slots); total ~131 MB
    float* zxb_f   = ws;                       //  8,978,432 (bf16 4096x4384)
    float* xbc_f   = zxb_f   + 8978432;        //  4,718,592 (bf16 4096x2304)
    float* dtv     = xbc_f   + 4718592;        //    131,072
    float* acs     = dtv     + 131072;         //    131,072
    float* g2_f    = acs     + 131072;         //    524,288 (bf16 [bc][l][s])
    float* state_t = g2_f    + 524288;         //  4,194,304 ([bc][h][p][n] fp32)
    float* xdt_f   = state_t + 4194304;        //  4,194,304 (bf16 [bc][c][l])
    float* xcs_f   = xdt_f   + 4194304;        //  4,194,304 (bf16 [bc][c][l])
    float* bt_f    = xcs_f   + 4194304;        //    262,144 (bf16 [bc][n][l])
    float* regU    = bt_f    + 262144;         //  4,390,912 (xn_bf+wi_bf, later ybf)
    float* wo_f    = regU    + 4390912;        //  1,048,576 (wo_bf)

    ushort* zxb_bf = (ushort*)zxb_f;
    ushort* xBC_bf = (ushort*)xbc_f;
    ushort* G2b    = (ushort*)g2_f;
    ushort* Xdt_t  = (ushort*)xdt_f;
    ushort* Xcs_t  = (ushort*)xcs_f;
    ushort* Bt     = (ushort*)bt_f;
    ushort* xn_bf  = (ushort*)regU;                 // 4096x1024 [dead after in_proj]
    ushort* wi_bf  = (ushort*)(regU + 2097152);     // 4480x1024 [dead after in_proj]
    ushort* ybf    = (ushort*)regU;                 // 4096x2048 [born at ssd_y]
    ushort* wo_bf  = (ushort*)wo_f;

    // 0. convert weights to bf16
    cvt_w_kernel<<<dim3(NPAD_IN * DMODEL / 1024), 256, 0, stream>>>(
        in_proj_w, wi_bf, DINP, 10);
    cvt_w_kernel<<<dim3(DMODEL * DINNER / 1024), 256, 0, stream>>>(
        out_proj_w, wo_bf, DMODEL, 11);

    // 1. xn = RMSNorm(x)*norm_w -> bf16
    rmsnorm_bf16_kernel<<<dim3(NROWS), 256, 0, stream>>>(x, norm_w, xn_bf, DMODEL);

    // 2. zxbcdt = xn @ in_proj_w^T -> bf16 (M=4096, N=4384 pad 4480, K=1024)
    gemm_bf16_kernel<<<dim3(32 * 35), 256, 0, stream>>>(
        xn_bf, DMODEL, 0, wi_bf, DMODEL, 0,
        zxb_bf, DINP, 0, 1, nullptr, 32, 35, DINP, DMODEL);

    // 3. conv + SiLU -> bf16 xBC
    conv_silu_kernel<<<dim3(NROWS, 9), 256, 0, stream>>>(zxb_bf, conv_w, conv_b, xBC_bf);

    // 4. fused dt softplus + per-chunk cumsum
    acs_kernel<<<dim3(BB * NCH, NHEADS), 256, 0, stream>>>(
        zxb_bf, dt_bias, A_log, dtv, acs);

    // 5. prep transposed bf16 operands (Xdt_t, Xcs_t, Bt)
    prep_transpose_kernel<<<dim3(BB * NCH, 34), 256, 0, stream>>>(
        xBC_bf, dtv, acs, Xdt_t, Xcs_t, Bt);

    // 6. G2[bc][l][s] = C_l . B_s -> bf16 (batched; M=N=256, K=128)
    gemm_bf16_kernel<<<dim3(4, 1, BB * NCH), 256, 0, stream>>>(
        xBC_bf + DINNER + DSTATE, CONVD, (long)CHUNK * CONVD,
        xBC_bf + DINNER, CONVD, (long)CHUNK * CONVD,
        G2b, CHUNK, (long)CHUNK * CHUNK, 1, nullptr, 2, 2, CHUNK, DSTATE);

    // 7. chunk states (MFMA) -> state_t[bc][h][p][n]
    chunk_state_mfma_kernel<<<dim3(BB * NCH, NHEADS), 256, 0, stream>>>(
        Xcs_t, Bt, state_t);

    // 8. inter-chunk scan
    state_scan_kernel<<<dim3(BB * NHEADS * 8192 / 256), 256, 0, stream>>>(state_t, acs);

    // 9. Y (MFMA diag+off) + D*xh, silu(z) gate -> ybf
    ssd_y_mfma_kernel<<<dim3(BB * NCH, NHEADS), 256, 0, stream>>>(
        xBC_bf, Xdt_t, G2b, acs, state_t, zxb_bf, Dh, ybf);

    // 10. gnorm (bf16 in place)
    gnorm_bf16_kernel<<<dim3(NROWS), 256, 0, stream>>>(ybf, gnorm_w);

    // 11. out = x + y @ out_proj_w^T (fp32 out; M=4096, N=1024, K=2048)
    gemm_bf16_kernel<<<dim3(32 * 8), 256, 0, stream>>>(
        ybf, DINNER, 0, wo_bf, DINNER, 0,
        out, DMODEL, 0, 0, x, 32, 8, DMODEL, DINNER);
}

// Round 5
// 331.956 us; speedup vs baseline: 3.9603x; 1.1766x over previous
//
#include <hip/hip_runtime.h>
#include <hip/hip_bf16.h>

// ---- problem constants ----
#define BB      2
#define LSEQ    2048
#define DMODEL  1024
#define DSTATE  128
#define DCONV   4
#define HEADDIM 64
#define DINNER  2048      // EXP*DMODEL
#define NHEADS  32        // DINNER/HEADDIM
#define CONVD   2304      // DINNER + 2*DSTATE
#define DINP    4384      // 2*DINNER + 2*DSTATE + NHEADS
#define NPAD_IN 4416      // 69*64, padded in_proj rows (64-wide n-tiles)
#define CHUNK   256
#define NCH     8         // LSEQ/CHUNK
#define NROWS   4096      // BB*LSEQ
#define EPSF    1e-5f

typedef __attribute__((ext_vector_type(8))) short bf16x8;
typedef __attribute__((ext_vector_type(4))) float f32x4;

#define ASYNC_COPY16(gptr, lptr) \
    __builtin_amdgcn_global_load_lds((const __attribute__((address_space(1))) void*)(gptr), \
                                     (__attribute__((address_space(3))) void*)(lptr), 16, 0, 0)

__device__ __forceinline__ ushort f2bf(float f) {
    __hip_bfloat16 h = __float2bfloat16(f);
    return *(ushort*)&h;
}
__device__ __forceinline__ float bf2f(ushort u) {
    return __uint_as_float(((unsigned)u) << 16);
}
__device__ __forceinline__ short fb(float f) { return (short)f2bf(f); }

// ============================================================
// Prologue: one launch for wi cvt (padded), wo cvt, rmsnorm->bf16.
// grid partition: [0,4416) wi | [4416,6464) wo | [6464,10560) rmsnorm
// ============================================================
__global__ __launch_bounds__(256) void prologue_kernel(
    const float* __restrict__ x, const float* __restrict__ norm_w,
    const float* __restrict__ in_proj_w, const float* __restrict__ out_proj_w,
    ushort* __restrict__ xn_bf, ushort* __restrict__ wi_bf,
    ushort* __restrict__ wo_bf)
{
    int bid = blockIdx.x;
    if (bid < 4416) {                 // wi: 4416x1024 bf16, zero-pad rows >= 4384
        long i4 = ((long)bid * 256 + threadIdx.x) * 4;
        int n = (int)(i4 >> 10);
        long k = i4 & 1023;
        ushort4 o;
        if (n < DINP) {
            float4 v = *(const float4*)(in_proj_w + ((long)n << 10) + k);
            o.x = f2bf(v.x); o.y = f2bf(v.y); o.z = f2bf(v.z); o.w = f2bf(v.w);
        } else { o.x = o.y = o.z = o.w = 0; }
        *(ushort4*)(wi_bf + i4) = o;
    } else if (bid < 6464) {          // wo: 1024x2048 bf16
        long i4 = ((long)(bid - 4416) * 256 + threadIdx.x) * 4;
        float4 v = *(const float4*)(out_proj_w + i4);
        ushort4 o;
        o.x = f2bf(v.x); o.y = f2bf(v.y); o.z = f2bf(v.z); o.w = f2bf(v.w);
        *(ushort4*)(wo_bf + i4) = o;
    } else {                          // rmsnorm row -> bf16
        int row = bid - 6464;
        const float* xr = x + (long)row * DMODEL;
        float4 v = *(const float4*)(xr + threadIdx.x * 4);
        float ss = v.x*v.x + v.y*v.y + v.z*v.z + v.w*v.w;
        for (int off = 32; off; off >>= 1) ss += __shfl_down(ss, off, 64);
        __shared__ float red[4];
        if ((threadIdx.x & 63) == 0) red[threadIdx.x >> 6] = ss;
        __syncthreads();
        float tot = red[0] + red[1] + red[2] + red[3];
        float scale = rsqrtf(tot / (float)DMODEL + EPSF);
        float4 wv = *(const float4*)(norm_w + threadIdx.x * 4);
        ushort4 o;
        o.x = f2bf(v.x * scale * wv.x); o.y = f2bf(v.y * scale * wv.y);
        o.z = f2bf(v.z * scale * wv.z); o.w = f2bf(v.w * scale * wv.w);
        *(ushort4*)(xn_bf + (long)row * DMODEL + threadIdx.x * 4) = o;
    }
}

// ============================================================
// bf16 MFMA NT GEMM (batched, strided, swizzled 1D grid):
//   C[m,n] = sum_k A[m,k]*W[n,k]  (+resid for fp32 out)
// 128x64 tile (wave=64x32, acc 32 AGPR -> 4+ blocks/CU), BK=64,
// mfma_f32_16x16x32_bf16, XOR-swizzled global_load_lds(16B) staging,
// LDS-bounce coalesced epilogue (bf16 or fp32 out).
// Requires: M%128==0, K%64==0, W padded to ntiles*64 rows, N%8==0.
// ============================================================
__global__ __launch_bounds__(256, 4) void gemm_bf16_kernel(
    const ushort* __restrict__ A, int lda, long sA,
    const ushort* __restrict__ W, int ldw, long sW,
    void* __restrict__ Cout, int ldc, long sC, int c_bf16,
    const float* __restrict__ resid,
    int mtiles, int ntiles, int N, int K)
{
    __shared__ __align__(16) char smem[24576];
    ushort* As = (ushort*)smem;          // 128*64 ushort = 16 KB
    ushort* Bs = As + 128 * 64;          //  64*64 ushort =  8 KB
    ushort* tu = (ushort*)smem;          // epilogue bf16 tile [128][72]
    float*  tf = (float*)smem;           // epilogue fp32 tile [64][68]

    const int t = threadIdx.x;
    const int lane = t & 63;
    const int w = t >> 6;
    const int wm = w & 1, wn = w >> 1;
    const int lm = lane & 15, quad = lane >> 4;

    // grouped swizzle (GM=8) for tile reuse
    int pid = blockIdx.x;
    const int GM = 8;
    int width = GM * ntiles;
    int group = pid / width;
    int first_m = group * GM;
    int gsz = mtiles - first_m; if (gsz > GM) gsz = GM;
    int mt = first_m + (pid % width) % gsz;
    int nt = (pid % width) / gsz;
    const int m0 = mt * 128, n0 = nt * 64;

    A += (long)blockIdx.z * sA;
    W += (long)blockIdx.z * sW;

    const ushort* ga[4]; const ushort* gw[2];
#pragma unroll
    for (int i = 0; i < 4; ++i) {
        int s = i * 256 + t;
        int row = s >> 3;
        int kseg = (s & 7) ^ (row & 7);
        ga[i] = A + (long)(m0 + row) * lda + kseg * 8;
    }
#pragma unroll
    for (int i = 0; i < 2; ++i) {
        int s = i * 256 + t;
        int row = s >> 3;
        int kseg = (s & 7) ^ (row & 7);
        gw[i] = W + (long)(n0 + row) * ldw + kseg * 8;
    }

    f32x4 acc[4][2];
    f32x4 zero4 = {0.f, 0.f, 0.f, 0.f};
#pragma unroll
    for (int i = 0; i < 4; ++i) { acc[i][0] = zero4; acc[i][1] = zero4; }

    int arow8[4], arow7[4], brow8[2], brow7[2];
#pragma unroll
    for (int i = 0; i < 4; ++i) {
        int ar = wm * 64 + i * 16 + lm;
        arow8[i] = ar * 8; arow7[i] = ar & 7;
    }
#pragma unroll
    for (int i = 0; i < 2; ++i) {
        int br = wn * 32 + i * 16 + lm;
        brow8[i] = br * 8; brow7[i] = br & 7;
    }

    for (int k0 = 0; k0 < K; k0 += 64) {
#pragma unroll
        for (int i = 0; i < 4; ++i) {
            ASYNC_COPY16(ga[i], &As[(i * 256 + w * 64) * 8]);
            ga[i] += 64;
        }
#pragma unroll
        for (int i = 0; i < 2; ++i) {
            ASYNC_COPY16(gw[i], &Bs[(i * 256 + w * 64) * 8]);
            gw[i] += 64;
        }
        __syncthreads();
#pragma unroll
        for (int ks = 0; ks < 2; ++ks) {
            bf16x8 af[4], bfr[2];
#pragma unroll
            for (int i = 0; i < 4; ++i)
                af[i]  = *(const bf16x8*)&As[(arow8[i] + ((ks * 4 + quad) ^ arow7[i])) * 8];
#pragma unroll
            for (int i = 0; i < 2; ++i)
                bfr[i] = *(const bf16x8*)&Bs[(brow8[i] + ((ks * 4 + quad) ^ brow7[i])) * 8];
#pragma unroll
            for (int im = 0; im < 4; ++im)
#pragma unroll
                for (int in = 0; in < 2; ++in)
                    acc[im][in] = __builtin_amdgcn_mfma_f32_16x16x32_bf16(
                        af[im], bfr[in], acc[im][in], 0, 0, 0);
        }
        __syncthreads();
    }

    // ---- epilogue: LDS bounce -> coalesced full-line stores ----
    if (c_bf16) {
        ushort* C = (ushort*)Cout + (long)blockIdx.z * sC;
#pragma unroll
        for (int mi = 0; mi < 4; ++mi)
#pragma unroll
            for (int ni = 0; ni < 2; ++ni) {
                int c = wn * 32 + ni * 16 + lm;
#pragma unroll
                for (int i = 0; i < 4; ++i) {
                    int r = wm * 64 + mi * 16 + quad * 4 + i;
                    tu[r * 72 + c] = f2bf(acc[mi][ni][i]);
                }
            }
        __syncthreads();
        int r = t >> 1, cb = (t & 1) * 32;
        long rowbase = (long)(m0 + r) * ldc + n0 + cb;
#pragma unroll
        for (int q = 0; q < 4; ++q) {
            int gcol = n0 + cb + q * 8;
            if (gcol < N)
                *(bf16x8*)(C + rowbase + q * 8) =
                    *(const bf16x8*)&tu[r * 72 + cb + q * 8];
        }
    } else {
        float* C = (float*)Cout + (long)blockIdx.z * sC;
#pragma unroll
        for (int p = 0; p < 2; ++p) {
            if (wm == p) {
#pragma unroll
                for (int mi = 0; mi < 4; ++mi)
#pragma unroll
                    for (int ni = 0; ni < 2; ++ni) {
                        int c = wn * 32 + ni * 16 + lm;
#pragma unroll
                        for (int i = 0; i < 4; ++i) {
                            int r = mi * 16 + quad * 4 + i;
                            tf[r * 68 + c] = acc[mi][ni][i];
                        }
                    }
            }
            __syncthreads();
            int r2 = t >> 2, cb = (t & 3) * 16;
            long gbase = (long)(m0 + p * 64 + r2) * ldc + n0 + cb;
#pragma unroll
            for (int q = 0; q < 4; ++q) {
                float4 v = *(const float4*)&tf[r2 * 68 + cb + q * 4];
                if (resid) {
                    float4 rv = *(const float4*)(resid + gbase + q * 4);
                    v.x += rv.x; v.y += rv.y; v.z += rv.z; v.w += rv.w;
                }
                *(float4*)(C + gbase + q * 4) = v;
            }
            __syncthreads();
        }
    }
}

// ============================================================
// Merged: depthwise causal conv+SiLU (blocks < NROWS*9) and
// fused dt-softplus + per-chunk cumsum (next 512 blocks).
// ============================================================
__global__ __launch_bounds__(256) void conv_acs_kernel(
    const ushort* __restrict__ zx, const float* __restrict__ cw,
    const float* __restrict__ cb, ushort* __restrict__ xBC_bf,
    const float* __restrict__ dt_bias, const float* __restrict__ A_log,
    float* __restrict__ dtv, float* __restrict__ Acs)
{
    int bid = blockIdx.x;
    if (bid < NROWS * 9) {
        int row = bid / 9;
        int c = (bid % 9) * 256 + threadIdx.x;
        int l = row & (LSEQ - 1);
        float acc = cb[c];
#pragma unroll
        for (int k = 0; k < DCONV; ++k) {
            int ls = l + k - (DCONV - 1);
            if (ls >= 0)
                acc += bf2f(zx[(long)(row + k - (DCONV - 1)) * DINP + DINNER + c]) * cw[c * DCONV + k];
        }
        xBC_bf[(long)row * CONVD + c] = f2bf(acc / (1.f + __expf(-acc)));
    } else {
        int idx = bid - NROWS * 9;
        int bc = idx >> 5, h = idx & 31;
        int l = threadIdx.x;
        int row = bc * CHUNK + l;
        float v = bf2f(zx[(long)row * DINP + (DINP - NHEADS) + h]) + dt_bias[h];
        float d = (v > 20.f) ? v : log1pf(__expf(v));
        dtv[row * NHEADS + h] = d;
        float a = -d * __expf(A_log[h]);
        __shared__ float buf[2][CHUNK];
        buf[0][l] = a; __syncthreads();
        int src = 0;
        for (int off = 1; off < CHUNK; off <<= 1) {
            float vv = buf[src][l];
            if (l >= off) vv += buf[src][l - off];
            buf[src ^ 1][l] = vv;
            __syncthreads();
            src ^= 1;
        }
        Acs[(bc * NHEADS + h) * CHUNK + l] = buf[src][l];
    }
}

// ============================================================
// Prep: per (bc, tile) LDS-transpose to K-contiguous bf16 operands.
// ============================================================
#define XT_PAD 264
__global__ __launch_bounds__(256) void prep_transpose_kernel(
    const ushort* __restrict__ xBC_bf, const float* __restrict__ dtv,
    const float* __restrict__ acs, ushort* __restrict__ Xdt_t,
    ushort* __restrict__ Xcs_t, ushort* __restrict__ Bt)
{
    int bc = blockIdx.x, yt = blockIdx.y;
    int t = threadIdx.x;
    int row0 = bc * CHUNK;
    __shared__ ushort t_dt[64 * XT_PAD];
    __shared__ ushort t_cs[64 * XT_PAD];
    __shared__ float dl[CHUNK], cl[CHUNK];
    bool isB = (yt >= 32);
    int src_c0 = isB ? (DINNER + (yt - 32) * 64) : (yt * 64);
    if (!isB) {
        int h = yt;
        float a = acs[(bc * NHEADS + h) * CHUNK + t];
        float d = dtv[(row0 + t) * NHEADS + h];
        float T = acs[(bc * NHEADS + h) * CHUNK + CHUNK - 1];
        dl[t] = d;
        cl[t] = __expf(T - a) * d;
    }
    __syncthreads();
    for (int iter = 0; iter < 8; ++iter) {
        int l = iter * 32 + (t >> 3);
        int cc = (t & 7) * 8;
        ushort u[8];
        *(ushort4*)&u[0] = *(const ushort4*)(xBC_bf + (long)(row0 + l) * CONVD + src_c0 + cc);
        *(ushort4*)&u[4] = *(const ushort4*)(xBC_bf + (long)(row0 + l) * CONVD + src_c0 + cc + 4);
        if (isB) {
#pragma unroll
            for (int j = 0; j < 8; ++j) t_dt[(cc + j) * XT_PAD + l] = u[j];
        } else {
            float sd = dl[l], sc = cl[l];
#pragma unroll
            for (int j = 0; j < 8; ++j) {
                float f = bf2f(u[j]);
                t_dt[(cc + j) * XT_PAD + l] = f2bf(f * sd);
                t_cs[(cc + j) * XT_PAD + l] = f2bf(f * sc);
            }
        }
    }
    __syncthreads();
    int r = t >> 2, seg = (t & 3) * 64;
    const ushort* s1 = &t_dt[r * XT_PAD + seg];
    if (isB) {
        ushort* dst = Bt + ((long)bc * DSTATE + (yt - 32) * 64 + r) * CHUNK + seg;
#pragma unroll
        for (int q = 0; q < 16; ++q)
            *(ushort4*)(dst + q * 4) = *(const ushort4*)(s1 + q * 4);
    } else {
        const ushort* s2 = &t_cs[r * XT_PAD + seg];
        ushort* d1 = Xdt_t + ((long)bc * DINNER + yt * 64 + r) * CHUNK + seg;
        ushort* d2 = Xcs_t + ((long)bc * DINNER + yt * 64 + r) * CHUNK + seg;
#pragma unroll
        for (int q = 0; q < 16; ++q) {
            *(ushort4*)(d1 + q * 4) = *(const ushort4*)(s1 + q * 4);
            *(ushort4*)(d2 + q * 4) = *(const ushort4*)(s2 + q * 4);
        }
    }
}

// ============================================================
// Chunk state via MFMA: S_t[p][n] = sum_l Xcs_t[p][l] * Bt[n][l]
// ============================================================
__global__ __launch_bounds__(256) void chunk_state_mfma_kernel(
    const ushort* __restrict__ Xcs_t, const ushort* __restrict__ Bt,
    float* __restrict__ state_t)
{
    int bc = blockIdx.x, h = blockIdx.y;
    int t = threadIdx.x, lane = t & 63, w = t >> 6;
    int lm = lane & 15, quad = lane >> 4;
    const ushort* Xb = Xcs_t + ((long)bc * DINNER + h * HEADDIM) * CHUNK;
    const ushort* Bb = Bt + (long)bc * DSTATE * CHUNK;
    f32x4 acc[4][2];
    f32x4 zero4 = {0.f, 0.f, 0.f, 0.f};
#pragma unroll
    for (int i = 0; i < 4; ++i) { acc[i][0] = zero4; acc[i][1] = zero4; }

    for (int kt = 0; kt < 8; ++kt) {
        int k = kt * 32 + quad * 8;
        bf16x8 af[4], bfr[2];
#pragma unroll
        for (int mi = 0; mi < 4; ++mi)
            af[mi] = *(const bf16x8*)(Xb + (long)(mi * 16 + lm) * CHUNK + k);
#pragma unroll
        for (int nj = 0; nj < 2; ++nj)
            bfr[nj] = *(const bf16x8*)(Bb + (long)(w * 32 + nj * 16 + lm) * CHUNK + k);
#pragma unroll
        for (int mi = 0; mi < 4; ++mi)
#pragma unroll
            for (int nj = 0; nj < 2; ++nj)
                acc[mi][nj] = __builtin_amdgcn_mfma_f32_16x16x32_bf16(
                    af[mi], bfr[nj], acc[mi][nj], 0, 0, 0);
    }
    float* sp = state_t + (long)(bc * NHEADS + h) * (DSTATE * HEADDIM);
#pragma unroll
    for (int mi = 0; mi < 4; ++mi)
#pragma unroll
        for (int nj = 0; nj < 2; ++nj) {
            int n = w * 32 + nj * 16 + lm;
#pragma unroll
            for (int i = 0; i < 4; ++i) {
                int p = mi * 16 + quad * 4 + i;
                sp[p * DSTATE + n] = acc[mi][nj][i];
            }
        }
}

// ============================================================
// Inter-chunk scan (in place)
// ============================================================
__global__ __launch_bounds__(256) void state_scan_kernel(
    float* __restrict__ state, const float* __restrict__ Acs)
{
    long flat = (long)blockIdx.x * 256 + threadIdx.x;
    int e = (int)(flat & 8191);
    int bh = (int)(flat >> 13);
    int b = bh >> 5, h = bh & 31;
    float S = 0.f;
    for (int c = 0; c < NCH; ++c) {
        int bc = b * NCH + c;
        long idx = ((long)(bc * NHEADS + h)) * 8192 + e;
        float T = Acs[(bc * NHEADS + h) * CHUNK + CHUNK - 1];
        float tmp = state[idx];
        state[idx] = S;
        S = S * __expf(T) + tmp;
    }
}

// ============================================================
// SSD Y via MFMA: Y = P@Xdt + (C*eAl)@S_t^T, then +D*xh, silu(z) gate.
// ============================================================
__global__ __launch_bounds__(256) void ssd_y_mfma_kernel(
    const ushort* __restrict__ xBC_bf, const ushort* __restrict__ Xdt_t,
    const ushort* __restrict__ G2b, const float* __restrict__ acs,
    const float* __restrict__ state_t, const ushort* __restrict__ zxb,
    const float* __restrict__ Dh, ushort* __restrict__ ybf)
{
    int bc = blockIdx.x, h = blockIdx.y;
    int t = threadIdx.x, lane = t & 63, w = t >> 6;
    int lm = lane & 15, quad = lane >> 4;
    int row0 = bc * CHUNK;
    __shared__ float acs_s[CHUNK];
    acs_s[t] = acs[(bc * NHEADS + h) * CHUNK + t];
    __syncthreads();
    int lbase = w * 64;
    float acs_l[4], eAl[4];
#pragma unroll
    for (int mi = 0; mi < 4; ++mi) {
        acs_l[mi] = acs_s[lbase + mi * 16 + lm];
        eAl[mi] = __expf(acs_l[mi]);
    }
    f32x4 acc[4][4];
    f32x4 zero4 = {0.f, 0.f, 0.f, 0.f};
#pragma unroll
    for (int i = 0; i < 4; ++i)
#pragma unroll
        for (int j = 0; j < 4; ++j) acc[i][j] = zero4;

    const ushort* Xb = Xdt_t + ((long)bc * DINNER + h * HEADDIM) * CHUNK;
    const ushort* g2 = G2b + (long)bc * (CHUNK * CHUNK);

    // ---- phase A: diagonal (causal) ----
    for (int ks = 0; ks <= 2 * w + 1; ++ks) {
        int sq = ks * 32 + quad * 8;
        bf16x8 bfr[4];
#pragma unroll
        for (int ni = 0; ni < 4; ++ni)
            bfr[ni] = *(const bf16x8*)(Xb + (long)(ni * 16 + lm) * CHUNK + sq);
        float a8[8];
#pragma unroll
        for (int j = 0; j < 8; ++j) a8[j] = acs_s[sq + j];
#pragma unroll
        for (int mi = 0; mi < 4; ++mi) {
            int lmin = lbase + mi * 16;
            if (ks * 32 > lmin + 15) continue;
            int lv = lmin + lm;
            float al = acs_l[mi];
            bf16x8 g8 = *(const bf16x8*)(g2 + (long)lv * CHUNK + sq);
            bf16x8 af;
#pragma unroll
            for (int j = 0; j < 8; ++j) {
                float v = bf2f((ushort)g8[j]) * __expf(al - a8[j]);
                af[j] = (sq + j > lv) ? (short)0 : fb(v);
            }
#pragma unroll
            for (int ni = 0; ni < 4; ++ni)
                acc[mi][ni] = __builtin_amdgcn_mfma_f32_16x16x32_bf16(
                    af, bfr[ni], acc[mi][ni], 0, 0, 0);
        }
    }

    // ---- phase B: off-diagonal (C*eAl @ S_t^T) ----
    const float* sp = state_t + (long)(bc * NHEADS + h) * (DSTATE * HEADDIM);
    const ushort* Cb = xBC_bf + (long)row0 * CONVD + DINNER + DSTATE;
    for (int kt = 0; kt < 4; ++kt) {
        int n0 = kt * 32 + quad * 8;
        bf16x8 bfr[4];
#pragma unroll
        for (int ni = 0; ni < 4; ++ni) {
            const float* s8 = sp + (ni * 16 + lm) * DSTATE + n0;
            f32x4 sA = *(const f32x4*)s8;
            f32x4 sB = *(const f32x4*)(s8 + 4);
            bf16x8 v;
#pragma unroll
            for (int j = 0; j < 4; ++j) { v[j] = fb(sA[j]); v[4 + j] = fb(sB[j]); }
            bfr[ni] = v;
        }
#pragma unroll
        for (int mi = 0; mi < 4; ++mi) {
            int lv = lbase + mi * 16 + lm;
            bf16x8 cu = *(const bf16x8*)(Cb + (long)lv * CONVD + n0);
            bf16x8 ce;
            float e = eAl[mi];
#pragma unroll
            for (int j = 0; j < 8; ++j) ce[j] = fb(bf2f((ushort)cu[j]) * e);
#pragma unroll
            for (int ni = 0; ni < 4; ++ni)
                acc[mi][ni] = __builtin_amdgcn_mfma_f32_16x16x32_bf16(
                    ce, bfr[ni], acc[mi][ni], 0, 0, 0);
        }
    }

    // ---- epilogue: +D*xh, silu(z) gate, bf16 store ----
    float Dv = Dh[h];
#pragma unroll
    for (int mi = 0; mi < 4; ++mi)
#pragma unroll
        for (int i = 0; i < 4; ++i) {
            int l = lbase + mi * 16 + quad * 4 + i;
            long row = row0 + l;
#pragma unroll
            for (int ni = 0; ni < 4; ++ni) {
                int p = ni * 16 + lm;
                float xh = bf2f(xBC_bf[row * CONVD + h * HEADDIM + p]);
                float z = bf2f(zxb[row * DINP + h * HEADDIM + p]);
                float o = (acc[mi][ni][i] + Dv * xh) * (z / (1.f + __expf(-z)));
                ybf[row * DINNER + h * HEADDIM + p] = f2bf(o);
            }
        }
}

// ============================================================
// gnorm: bf16 RMSNorm in-place over D=2048 with weight
// ============================================================
__global__ __launch_bounds__(256) void gnorm_bf16_kernel(
    ushort* __restrict__ y, const float* __restrict__ gw)
{
    int row = blockIdx.x;
    ushort* yr = y + (long)row * DINNER;
    int base = threadIdx.x * 8;
    ushort4 a = *(ushort4*)(yr + base);
    ushort4 b = *(ushort4*)(yr + base + 4);
    float f[8] = {bf2f(a.x), bf2f(a.y), bf2f(a.z), bf2f(a.w),
                  bf2f(b.x), bf2f(b.y), bf2f(b.z), bf2f(b.w)};
    float ss = 0.f;
#pragma unroll
    for (int i = 0; i < 8; ++i) ss += f[i] * f[i];
    for (int off = 32; off; off >>= 1) ss += __shfl_down(ss, off, 64);
    __shared__ float red[4];
    if ((threadIdx.x & 63) == 0) red[threadIdx.x >> 6] = ss;
    __syncthreads();
    float tot = red[0] + red[1] + red[2] + red[3];
    float scale = rsqrtf(tot * (1.f / (float)DINNER) + EPSF);
    float4 g0 = *(const float4*)(gw + base);
    float4 g1 = *(const float4*)(gw + base + 4);
    ushort4 oa, ob;
    oa.x = f2bf(f[0] * scale * g0.x); oa.y = f2bf(f[1] * scale * g0.y);
    oa.z = f2bf(f[2] * scale * g0.z); oa.w = f2bf(f[3] * scale * g0.w);
    ob.x = f2bf(f[4] * scale * g1.x); ob.y = f2bf(f[5] * scale * g1.y);
    ob.z = f2bf(f[6] * scale * g1.z); ob.w = f2bf(f[7] * scale * g1.w);
    *(ushort4*)(yr + base) = oa;
    *(ushort4*)(yr + base + 4) = ob;
}

// ============================================================
// launch
// ============================================================
extern "C" void kernel_launch(void* const* d_in, const int* in_sizes, int n_in,
                              void* d_out, int out_size, void* d_ws, size_t ws_size,
                              hipStream_t stream)
{
    (void)in_sizes; (void)n_in; (void)out_size; (void)ws_size;
    const float* x          = (const float*)d_in[0];
    const float* norm_w     = (const float*)d_in[1];
    const float* in_proj_w  = (const float*)d_in[2];
    const float* conv_w     = (const float*)d_in[3];
    const float* conv_b     = (const float*)d_in[4];
    const float* dt_bias    = (const float*)d_in[5];
    const float* A_log      = (const float*)d_in[6];
    const float* Dh         = (const float*)d_in[7];
    const float* gnorm_w    = (const float*)d_in[8];
    const float* out_proj_w = (const float*)d_in[9];
    float* out = (float*)d_out;
    float* ws = (float*)d_ws;

    // workspace layout (float slots); total ~131 MB
    float* zxb_f   = ws;                       //  8,978,432 (bf16 4096x4384)
    float* xbc_f   = zxb_f   + 8978432;        //  4,718,592 (bf16 4096x2304)
    float* dtv     = xbc_f   + 4718592;        //    131,072
    float* acs     = dtv     + 131072;         //    131,072
    float* g2_f    = acs     + 131072;         //    524,288 (bf16 [bc][l][s])
    float* state_t = g2_f    + 524288;         //  4,194,304 ([bc][h][p][n] fp32)
    float* xdt_f   = state_t + 4194304;        //  4,194,304 (bf16 [bc][c][l])
    float* xcs_f   = xdt_f   + 4194304;        //  4,194,304 (bf16 [bc][c][l])
    float* bt_f    = xcs_f   + 4194304;        //    262,144 (bf16 [bc][n][l])
    float* regU    = bt_f    + 262144;         //  4,390,912 (xn_bf+wi_bf, later ybf)
    float* wo_f    = regU    + 4390912;        //  1,048,576 (wo_bf)

    ushort* zxb_bf = (ushort*)zxb_f;
    ushort* xBC_bf = (ushort*)xbc_f;
    ushort* G2b    = (ushort*)g2_f;
    ushort* Xdt_t  = (ushort*)xdt_f;
    ushort* Xcs_t  = (ushort*)xcs_f;
    ushort* Bt     = (ushort*)bt_f;
    ushort* xn_bf  = (ushort*)regU;                 // 4096x1024 [dead after in_proj]
    ushort* wi_bf  = (ushort*)(regU + 2097152);     // 4416x1024 [dead after in_proj]
    ushort* ybf    = (ushort*)regU;                 // 4096x2048 [born at ssd_y]
    ushort* wo_bf  = (ushort*)wo_f;

    // 0. prologue: wi/wo cvt + rmsnorm (one launch)
    prologue_kernel<<<dim3(10560), 256, 0, stream>>>(
        x, norm_w, in_proj_w, out_proj_w, xn_bf, wi_bf, wo_bf);

    // 1. zxbcdt = xn @ in_proj_w^T -> bf16 (M=4096, N=4384 pad 4416, K=1024)
    gemm_bf16_kernel<<<dim3(32 * 69), 256, 0, stream>>>(
        xn_bf, DMODEL, 0, wi_bf, DMODEL, 0,
        zxb_bf, DINP, 0, 1, nullptr, 32, 69, DINP, DMODEL);

    // 2. conv+SiLU and dt-softplus+cumsum (one launch)
    conv_acs_kernel<<<dim3(NROWS * 9 + BB * NCH * NHEADS), 256, 0, stream>>>(
        zxb_bf, conv_w, conv_b, xBC_bf, dt_bias, A_log, dtv, acs);

    // 3. prep transposed bf16 operands (Xdt_t, Xcs_t, Bt)
    prep_transpose_kernel<<<dim3(BB * NCH, 34), 256, 0, stream>>>(
        xBC_bf, dtv, acs, Xdt_t, Xcs_t, Bt);

    // 4. G2[bc][l][s] = C_l . B_s -> bf16 (batched; M=N=256, K=128)
    gemm_bf16_kernel<<<dim3(8, 1, BB * NCH), 256, 0, stream>>>(
        xBC_bf + DINNER + DSTATE, CONVD, (long)CHUNK * CONVD,
        xBC_bf + DINNER, CONVD, (long)CHUNK * CONVD,
        G2b, CHUNK, (long)CHUNK * CHUNK, 1, nullptr, 2, 4, CHUNK, DSTATE);

    // 5. chunk states (MFMA) -> state_t[bc][h][p][n]
    chunk_state_mfma_kernel<<<dim3(BB * NCH, NHEADS), 256, 0, stream>>>(
        Xcs_t, Bt, state_t);

    // 6. inter-chunk scan
    state_scan_kernel<<<dim3(BB * NHEADS * 8192 / 256), 256, 0, stream>>>(state_t, acs);

    // 7. Y (MFMA diag+off) + D*xh, silu(z) gate -> ybf
    ssd_y_mfma_kernel<<<dim3(BB * NCH, NHEADS), 256, 0, stream>>>(
        xBC_bf, Xdt_t, G2b, acs, state_t, zxb_bf, Dh, ybf);

    // 8. gnorm (bf16 in place)
    gnorm_bf16_kernel<<<dim3(NROWS), 256, 0, stream>>>(ybf, gnorm_w);

    // 9. out = x + y @ out_proj_w^T (fp32 out; M=4096, N=1024, K=2048)
    gemm_bf16_kernel<<<dim3(32 * 16), 256, 0, stream>>>(
        ybf, DINNER, 0, wo_bf, DINNER, 0,
        out, DMODEL, 0, 0, x, 32, 16, DMODEL, DINNER);
}

// Round 7
// 305.642 us; speedup vs baseline: 4.3013x; 1.0861x over previous
//
#include <hip/hip_runtime.h>
#include <hip/hip_bf16.h>

// ---- problem constants ----
#define BB      2
#define LSEQ    2048
#define DMODEL  1024
#define DSTATE  128
#define DCONV   4
#define HEADDIM 64
#define DINNER  2048      // EXP*DMODEL
#define NHEADS  32        // DINNER/HEADDIM
#define CONVD   2304      // DINNER + 2*DSTATE
#define DINP    4384      // 2*DINNER + 2*DSTATE + NHEADS
#define NPAD_IN 4416      // 69*64, padded in_proj rows (64-wide n-tiles)
#define CHUNK   256
#define NCH     8         // LSEQ/CHUNK
#define NROWS   4096      // BB*LSEQ
#define EPSF    1e-5f
#define TPAD    264       // LDS transpose row pitch (ushort)

typedef __attribute__((ext_vector_type(8))) short bf16x8;
typedef __attribute__((ext_vector_type(4))) float f32x4;

#define ASYNC_COPY16(gptr, lptr) \
    __builtin_amdgcn_global_load_lds((const __attribute__((address_space(1))) void*)(gptr), \
                                     (__attribute__((address_space(3))) void*)(lptr), 16, 0, 0)

__device__ __forceinline__ ushort f2bf(float f) {
    __hip_bfloat16 h = __float2bfloat16(f);
    return *(ushort*)&h;
}
__device__ __forceinline__ float bf2f(ushort u) {
    return __uint_as_float(((unsigned)u) << 16);
}
__device__ __forceinline__ short fb(float f) { return (short)f2bf(f); }

// ============================================================
// Prologue: wi cvt (padded), wo cvt (pre-scaled by gnorm_w),
// rmsnorm->bf16, ssq zeroing.
// grid: [0,4416) wi | [4416,6464) wo | [6464,10560) rmsnorm | [10560,10576) ssq=0
// ============================================================
__global__ __launch_bounds__(256) void prologue_kernel(
    const float* __restrict__ x, const float* __restrict__ norm_w,
    const float* __restrict__ in_proj_w, const float* __restrict__ out_proj_w,
    const float* __restrict__ gnorm_w,
    ushort* __restrict__ xn_bf, ushort* __restrict__ wi_bf,
    ushort* __restrict__ wo_bf, float* __restrict__ ssq)
{
    int bid = blockIdx.x;
    if (bid < 4416) {                 // wi: 4416x1024 bf16, zero-pad rows >= 4384
        long i4 = ((long)bid * 256 + threadIdx.x) * 4;
        int n = (int)(i4 >> 10);
        long k = i4 & 1023;
        ushort4 o;
        if (n < DINP) {
            float4 v = *(const float4*)(in_proj_w + ((long)n << 10) + k);
            o.x = f2bf(v.x); o.y = f2bf(v.y); o.z = f2bf(v.z); o.w = f2bf(v.w);
        } else { o.x = o.y = o.z = o.w = 0; }
        *(ushort4*)(wi_bf + i4) = o;
    } else if (bid < 6464) {          // wo': 1024x2048 bf16, folded gnorm_w
        long i4 = ((long)(bid - 4416) * 256 + threadIdx.x) * 4;
        int k = (int)(i4 & 2047);
        float4 v = *(const float4*)(out_proj_w + i4);
        float4 g = *(const float4*)(gnorm_w + k);
        ushort4 o;
        o.x = f2bf(v.x * g.x); o.y = f2bf(v.y * g.y);
        o.z = f2bf(v.z * g.z); o.w = f2bf(v.w * g.w);
        *(ushort4*)(wo_bf + i4) = o;
    } else if (bid < 10560) {         // rmsnorm row -> bf16
        int row = bid - 6464;
        const float* xr = x + (long)row * DMODEL;
        float4 v = *(const float4*)(xr + threadIdx.x * 4);
        float ss = v.x*v.x + v.y*v.y + v.z*v.z + v.w*v.w;
        for (int off = 32; off; off >>= 1) ss += __shfl_down(ss, off, 64);
        __shared__ float red[4];
        if ((threadIdx.x & 63) == 0) red[threadIdx.x >> 6] = ss;
        __syncthreads();
        float tot = red[0] + red[1] + red[2] + red[3];
        float scale = rsqrtf(tot / (float)DMODEL + EPSF);
        float4 wv = *(const float4*)(norm_w + threadIdx.x * 4);
        ushort4 o;
        o.x = f2bf(v.x * scale * wv.x); o.y = f2bf(v.y * scale * wv.y);
        o.z = f2bf(v.z * scale * wv.z); o.w = f2bf(v.w * scale * wv.w);
        *(ushort4*)(xn_bf + (long)row * DMODEL + threadIdx.x * 4) = o;
    } else {                          // ssq = 0 (16 blocks x 256 threads)
        ssq[(bid - 10560) * 256 + threadIdx.x] = 0.f;
    }
}

// ============================================================
// bf16 MFMA NT GEMM (batched, strided, swizzled 1D grid):
//   C[m,n] = sum_k A[m,k]*W[n,k]  (*rowscale[m] +resid, fp32 out)
// 128x64 tile, BK=64, mfma_f32_16x16x32_bf16, XOR-swizzled
// global_load_lds(16B) staging, LDS-bounce coalesced epilogue.
// rowscale: per-output-row ssq -> rsqrt(ssq/DINNER+eps) (fused gnorm).
// ============================================================
__global__ __launch_bounds__(256, 4) void gemm_bf16_kernel(
    const ushort* __restrict__ A, int lda, long sA,
    const ushort* __restrict__ W, int ldw, long sW,
    void* __restrict__ Cout, int ldc, long sC, int c_bf16,
    const float* __restrict__ resid, const float* __restrict__ rowscale,
    int mtiles, int ntiles, int N, int K)
{
    __shared__ __align__(16) char smem[24576];
    ushort* As = (ushort*)smem;          // 128*64 ushort = 16 KB
    ushort* Bs = As + 128 * 64;          //  64*64 ushort =  8 KB
    ushort* tu = (ushort*)smem;          // epilogue bf16 tile [128][72]
    float*  tf = (float*)smem;           // epilogue fp32 tile [64][68]

    const int t = threadIdx.x;
    const int lane = t & 63;
    const int w = t >> 6;
    const int wm = w & 1, wn = w >> 1;
    const int lm = lane & 15, quad = lane >> 4;

    int pid = blockIdx.x;
    const int GM = 8;
    int width = GM * ntiles;
    int group = pid / width;
    int first_m = group * GM;
    int gsz = mtiles - first_m; if (gsz > GM) gsz = GM;
    int mt = first_m + (pid % width) % gsz;
    int nt = (pid % width) / gsz;
    const int m0 = mt * 128, n0 = nt * 64;

    A += (long)blockIdx.z * sA;
    W += (long)blockIdx.z * sW;

    const ushort* ga[4]; const ushort* gw[2];
#pragma unroll
    for (int i = 0; i < 4; ++i) {
        int s = i * 256 + t;
        int row = s >> 3;
        int kseg = (s & 7) ^ (row & 7);
        ga[i] = A + (long)(m0 + row) * lda + kseg * 8;
    }
#pragma unroll
    for (int i = 0; i < 2; ++i) {
        int s = i * 256 + t;
        int row = s >> 3;
        int kseg = (s & 7) ^ (row & 7);
        gw[i] = W + (long)(n0 + row) * ldw + kseg * 8;
    }

    f32x4 acc[4][2];
    f32x4 zero4 = {0.f, 0.f, 0.f, 0.f};
#pragma unroll
    for (int i = 0; i < 4; ++i) { acc[i][0] = zero4; acc[i][1] = zero4; }

    int arow8[4], arow7[4], brow8[2], brow7[2];
#pragma unroll
    for (int i = 0; i < 4; ++i) {
        int ar = wm * 64 + i * 16 + lm;
        arow8[i] = ar * 8; arow7[i] = ar & 7;
    }
#pragma unroll
    for (int i = 0; i < 2; ++i) {
        int br = wn * 32 + i * 16 + lm;
        brow8[i] = br * 8; brow7[i] = br & 7;
    }

    for (int k0 = 0; k0 < K; k0 += 64) {
#pragma unroll
        for (int i = 0; i < 4; ++i) {
            ASYNC_COPY16(ga[i], &As[(i * 256 + w * 64) * 8]);
            ga[i] += 64;
        }
#pragma unroll
        for (int i = 0; i < 2; ++i) {
            ASYNC_COPY16(gw[i], &Bs[(i * 256 + w * 64) * 8]);
            gw[i] += 64;
        }
        __syncthreads();
#pragma unroll
        for (int ks = 0; ks < 2; ++ks) {
            bf16x8 af[4], bfr[2];
#pragma unroll
            for (int i = 0; i < 4; ++i)
                af[i]  = *(const bf16x8*)&As[(arow8[i] + ((ks * 4 + quad) ^ arow7[i])) * 8];
#pragma unroll
            for (int i = 0; i < 2; ++i)
                bfr[i] = *(const bf16x8*)&Bs[(brow8[i] + ((ks * 4 + quad) ^ brow7[i])) * 8];
#pragma unroll
            for (int im = 0; im < 4; ++im)
#pragma unroll
                for (int in = 0; in < 2; ++in)
                    acc[im][in] = __builtin_amdgcn_mfma_f32_16x16x32_bf16(
                        af[im], bfr[in], acc[im][in], 0, 0, 0);
        }
        __syncthreads();
    }

    // ---- epilogue: LDS bounce -> coalesced full-line stores ----
    if (c_bf16) {
        ushort* C = (ushort*)Cout + (long)blockIdx.z * sC;
#pragma unroll
        for (int mi = 0; mi < 4; ++mi)
#pragma unroll
            for (int ni = 0; ni < 2; ++ni) {
                int c = wn * 32 + ni * 16 + lm;
#pragma unroll
                for (int i = 0; i < 4; ++i) {
                    int r = wm * 64 + mi * 16 + quad * 4 + i;
                    tu[r * 72 + c] = f2bf(acc[mi][ni][i]);
                }
            }
        __syncthreads();
        int r = t >> 1, cb = (t & 1) * 32;
        long rowbase = (long)(m0 + r) * ldc + n0 + cb;
#pragma unroll
        for (int q = 0; q < 4; ++q) {
            int gcol = n0 + cb + q * 8;
            if (gcol < N)
                *(bf16x8*)(C + rowbase + q * 8) =
                    *(const bf16x8*)&tu[r * 72 + cb + q * 8];
        }
    } else {
        float* C = (float*)Cout + (long)blockIdx.z * sC;
#pragma unroll
        for (int p = 0; p < 2; ++p) {
            if (wm == p) {
#pragma unroll
                for (int mi = 0; mi < 4; ++mi)
#pragma unroll
                    for (int i = 0; i < 4; ++i) {
                        int r = mi * 16 + quad * 4 + i;
                        float s = 1.f;
                        if (rowscale)
                            s = rsqrtf(rowscale[m0 + p * 64 + r] * (1.f / (float)DINNER) + EPSF);
#pragma unroll
                        for (int ni = 0; ni < 2; ++ni) {
                            int c = wn * 32 + ni * 16 + lm;
                            tf[r * 68 + c] = acc[mi][ni][i] * s;
                        }
                    }
            }
            __syncthreads();
            int r2 = t >> 2, cb = (t & 3) * 16;
            long gbase = (long)(m0 + p * 64 + r2) * ldc + n0 + cb;
#pragma unroll
            for (int q = 0; q < 4; ++q) {
                float4 v = *(const float4*)&tf[r2 * 68 + cb + q * 4];
                if (resid) {
                    float4 rv = *(const float4*)(resid + gbase + q * 4);
                    v.x += rv.x; v.y += rv.y; v.z += rv.z; v.w += rv.w;
                }
                *(float4*)(C + gbase + q * 4) = v;
            }
            __syncthreads();
        }
    }
}

// ============================================================
// Merged: depthwise causal conv+SiLU and dt-softplus + chunk cumsum.
// ============================================================
__global__ __launch_bounds__(256) void conv_acs_kernel(
    const ushort* __restrict__ zx, const float* __restrict__ cw,
    const float* __restrict__ cb, ushort* __restrict__ xBC_bf,
    const float* __restrict__ dt_bias, const float* __restrict__ A_log,
    float* __restrict__ dtv, float* __restrict__ Acs)
{
    int bid = blockIdx.x;
    if (bid < NROWS * 9) {
        int row = bid / 9;
        int c = (bid % 9) * 256 + threadIdx.x;
        int l = row & (LSEQ - 1);
        float acc = cb[c];
#pragma unroll
        for (int k = 0; k < DCONV; ++k) {
            int ls = l + k - (DCONV - 1);
            if (ls >= 0)
                acc += bf2f(zx[(long)(row + k - (DCONV - 1)) * DINP + DINNER + c]) * cw[c * DCONV + k];
        }
        xBC_bf[(long)row * CONVD + c] = f2bf(acc / (1.f + __expf(-acc)));
    } else {
        int idx = bid - NROWS * 9;
        int bc = idx >> 5, h = idx & 31;
        int l = threadIdx.x;
        int row = bc * CHUNK + l;
        float v = bf2f(zx[(long)row * DINP + (DINP - NHEADS) + h]) + dt_bias[h];
        float d = (v > 20.f) ? v : log1pf(__expf(v));
        dtv[row * NHEADS + h] = d;
        float a = -d * __expf(A_log[h]);
        __shared__ float buf[2][CHUNK];
        buf[0][l] = a; __syncthreads();
        int src = 0;
        for (int off = 1; off < CHUNK; off <<= 1) {
            float vv = buf[src][l];
            if (l >= off) vv += buf[src][l - off];
            buf[src ^ 1][l] = vv;
            __syncthreads();
            src ^= 1;
        }
        Acs[(bc * NHEADS + h) * CHUNK + l] = buf[src][l];
    }
}

// ============================================================
// Bt[bc][n][l] = B[l][n] (K-contiguous operand, shared by all heads)
// grid (bc, half): half covers 64 of 128 n
// ============================================================
__global__ __launch_bounds__(256) void prep_b_kernel(
    const ushort* __restrict__ xBC_bf, ushort* __restrict__ Bt)
{
    int bc = blockIdx.x, half = blockIdx.y;
    int t = threadIdx.x;
    int row0 = bc * CHUNK;
    __shared__ ushort tB[64 * TPAD];
    int src_c0 = DINNER + half * 64;
    for (int iter = 0; iter < 8; ++iter) {
        int l = iter * 32 + (t >> 3);
        int cc = (t & 7) * 8;
        ushort u[8];
        *(ushort4*)&u[0] = *(const ushort4*)(xBC_bf + (long)(row0 + l) * CONVD + src_c0 + cc);
        *(ushort4*)&u[4] = *(const ushort4*)(xBC_bf + (long)(row0 + l) * CONVD + src_c0 + cc + 4);
#pragma unroll
        for (int j = 0; j < 8; ++j) tB[(cc + j) * TPAD + l] = u[j];
    }
    __syncthreads();
    int r = t >> 2, seg = (t & 3) * 64;
    ushort* dst = Bt + ((long)bc * DSTATE + half * 64 + r) * CHUNK + seg;
    const ushort* s1 = &tB[r * TPAD + seg];
#pragma unroll
    for (int q = 0; q < 16; ++q)
        *(ushort4*)(dst + q * 4) = *(const ushort4*)(s1 + q * 4);
}

// ============================================================
// Chunk state via MFMA with in-LDS X transpose:
//   S_t[p][n] = sum_l exp(T-acs_l)*dt_l*X[l,p] * Bt[n][l]  -> bf16
// ============================================================
__global__ __launch_bounds__(256) void chunk_state_mfma_kernel(
    const ushort* __restrict__ xBC_bf, const ushort* __restrict__ Bt,
    const float* __restrict__ dtv, const float* __restrict__ acs,
    ushort* __restrict__ state)
{
    int bc = blockIdx.x, h = blockIdx.y;
    int t = threadIdx.x, lane = t & 63, w = t >> 6;
    int lm = lane & 15, quad = lane >> 4;
    int row0 = bc * CHUNK;
    __shared__ ushort xt[64 * TPAD];
    __shared__ float cl[CHUNK];
    {
        float a = acs[(bc * NHEADS + h) * CHUNK + t];
        float T = acs[(bc * NHEADS + h) * CHUNK + CHUNK - 1];
        cl[t] = __expf(T - a) * dtv[(row0 + t) * NHEADS + h];
    }
    __syncthreads();
    for (int iter = 0; iter < 8; ++iter) {
        int l = iter * 32 + (t >> 3);
        int cc = (t & 7) * 8;
        ushort u[8];
        *(ushort4*)&u[0] = *(const ushort4*)(xBC_bf + (long)(row0 + l) * CONVD + h * HEADDIM + cc);
        *(ushort4*)&u[4] = *(const ushort4*)(xBC_bf + (long)(row0 + l) * CONVD + h * HEADDIM + cc + 4);
        float sc = cl[l];
#pragma unroll
        for (int j = 0; j < 8; ++j)
            xt[(cc + j) * TPAD + l] = f2bf(bf2f(u[j]) * sc);
    }
    __syncthreads();

    const ushort* Bb = Bt + (long)bc * DSTATE * CHUNK;
    f32x4 acc[4][2];
    f32x4 zero4 = {0.f, 0.f, 0.f, 0.f};
#pragma unroll
    for (int i = 0; i < 4; ++i) { acc[i][0] = zero4; acc[i][1] = zero4; }

    for (int kt = 0; kt < 8; ++kt) {
        int k = kt * 32 + quad * 8;
        bf16x8 af[4], bfr[2];
#pragma unroll
        for (int mi = 0; mi < 4; ++mi)
            af[mi] = *(const bf16x8*)&xt[(mi * 16 + lm) * TPAD + k];
#pragma unroll
        for (int nj = 0; nj < 2; ++nj)
            bfr[nj] = *(const bf16x8*)(Bb + (long)(w * 32 + nj * 16 + lm) * CHUNK + k);
#pragma unroll
        for (int mi = 0; mi < 4; ++mi)
#pragma unroll
            for (int nj = 0; nj < 2; ++nj)
                acc[mi][nj] = __builtin_amdgcn_mfma_f32_16x16x32_bf16(
                    af[mi], bfr[nj], acc[mi][nj], 0, 0, 0);
    }
    ushort* sp = state + (long)(bc * NHEADS + h) * (DSTATE * HEADDIM);
#pragma unroll
    for (int mi = 0; mi < 4; ++mi)
#pragma unroll
        for (int nj = 0; nj < 2; ++nj) {
            int n = w * 32 + nj * 16 + lm;
#pragma unroll
            for (int i = 0; i < 4; ++i) {
                int p = mi * 16 + quad * 4 + i;
                sp[p * DSTATE + n] = f2bf(acc[mi][nj][i]);
            }
        }
}

// ============================================================
// Inter-chunk scan (in place on bf16 states, fp32 accumulator)
// ============================================================
__global__ __launch_bounds__(256) void state_scan_kernel(
    ushort* __restrict__ state, const float* __restrict__ Acs)
{
    long flat = (long)blockIdx.x * 256 + threadIdx.x;
    int e = (int)(flat & 8191);
    int bh = (int)(flat >> 13);
    int b = bh >> 5, h = bh & 31;
    float S = 0.f;
    for (int c = 0; c < NCH; ++c) {
        int bc = b * NCH + c;
        long idx = ((long)(bc * NHEADS + h)) * 8192 + e;
        float T = Acs[(bc * NHEADS + h) * CHUNK + CHUNK - 1];
        float tmp = bf2f(state[idx]);
        state[idx] = f2bf(S);
        S = S * __expf(T) + tmp;
    }
}

// ============================================================
// SSD Y via MFMA (in-LDS Xdt transpose): Y = P@Xdt + (C*eAl)@S^T,
// then +D*xh, silu(z) gate, bf16 store + per-row ssq atomics.
// ============================================================
__global__ __launch_bounds__(256) void ssd_y_mfma_kernel(
    const ushort* __restrict__ xBC_bf, const ushort* __restrict__ G2b,
    const float* __restrict__ acs, const ushort* __restrict__ state,
    const ushort* __restrict__ zxb, const float* __restrict__ dtv,
    const float* __restrict__ Dh, ushort* __restrict__ ybf,
    float* __restrict__ ssq)
{
    int bc = blockIdx.x, h = blockIdx.y;
    int t = threadIdx.x, lane = t & 63, w = t >> 6;
    int lm = lane & 15, quad = lane >> 4;
    int row0 = bc * CHUNK;
    __shared__ ushort xt[64 * TPAD];
    __shared__ float acs_s[CHUNK];
    __shared__ float dl[CHUNK];
    acs_s[t] = acs[(bc * NHEADS + h) * CHUNK + t];
    dl[t] = dtv[(row0 + t) * NHEADS + h];
    __syncthreads();
    // transpose X chunk (dt-scaled) into LDS [p][l]
    for (int iter = 0; iter < 8; ++iter) {
        int l = iter * 32 + (t >> 3);
        int cc = (t & 7) * 8;
        ushort u[8];
        *(ushort4*)&u[0] = *(const ushort4*)(xBC_bf + (long)(row0 + l) * CONVD + h * HEADDIM + cc);
        *(ushort4*)&u[4] = *(const ushort4*)(xBC_bf + (long)(row0 + l) * CONVD + h * HEADDIM + cc + 4);
        float sd = dl[l];
#pragma unroll
        for (int j = 0; j < 8; ++j)
            xt[(cc + j) * TPAD + l] = f2bf(bf2f(u[j]) * sd);
    }
    __syncthreads();

    int lbase = w * 64;
    float acs_l[4], eAl[4];
#pragma unroll
    for (int mi = 0; mi < 4; ++mi) {
        acs_l[mi] = acs_s[lbase + mi * 16 + lm];
        eAl[mi] = __expf(acs_l[mi]);
    }
    f32x4 acc[4][4];
    f32x4 zero4 = {0.f, 0.f, 0.f, 0.f};
#pragma unroll
    for (int i = 0; i < 4; ++i)
#pragma unroll
        for (int j = 0; j < 4; ++j) acc[i][j] = zero4;

    const ushort* g2 = G2b + (long)bc * (CHUNK * CHUNK);

    // ---- phase A: diagonal (causal) ----
    for (int ks = 0; ks <= 2 * w + 1; ++ks) {
        int sq = ks * 32 + quad * 8;
        bf16x8 bfr[4];
#pragma unroll
        for (int ni = 0; ni < 4; ++ni)
            bfr[ni] = *(const bf16x8*)&xt[(ni * 16 + lm) * TPAD + sq];
        float a8[8];
#pragma unroll
        for (int j = 0; j < 8; ++j) a8[j] = acs_s[sq + j];
#pragma unroll
        for (int mi = 0; mi < 4; ++mi) {
            int lmin = lbase + mi * 16;
            if (ks * 32 > lmin + 15) continue;
            int lv = lmin + lm;
            float al = acs_l[mi];
            bf16x8 g8 = *(const bf16x8*)(g2 + (long)lv * CHUNK + sq);
            bf16x8 af;
#pragma unroll
            for (int j = 0; j < 8; ++j) {
                float v = bf2f((ushort)g8[j]) * __expf(al - a8[j]);
                af[j] = (sq + j > lv) ? (short)0 : fb(v);
            }
#pragma unroll
            for (int ni = 0; ni < 4; ++ni)
                acc[mi][ni] = __builtin_amdgcn_mfma_f32_16x16x32_bf16(
                    af, bfr[ni], acc[mi][ni], 0, 0, 0);
        }
    }

    // ---- phase B: off-diagonal (C*eAl @ S^T), bf16 state loads ----
    const ushort* sp = state + (long)(bc * NHEADS + h) * (DSTATE * HEADDIM);
    const ushort* Cb = xBC_bf + (long)row0 * CONVD + DINNER + DSTATE;
    for (int kt = 0; kt < 4; ++kt) {
        int n0 = kt * 32 + quad * 8;
        bf16x8 bfr[4];
#pragma unroll
        for (int ni = 0; ni < 4; ++ni)
            bfr[ni] = *(const bf16x8*)(sp + (long)(ni * 16 + lm) * DSTATE + n0);
#pragma unroll
        for (int mi = 0; mi < 4; ++mi) {
            int lv = lbase + mi * 16 + lm;
            bf16x8 cu = *(const bf16x8*)(Cb + (long)lv * CONVD + n0);
            bf16x8 ce;
            float e = eAl[mi];
#pragma unroll
            for (int j = 0; j < 8; ++j) ce[j] = fb(bf2f((ushort)cu[j]) * e);
#pragma unroll
            for (int ni = 0; ni < 4; ++ni)
                acc[mi][ni] = __builtin_amdgcn_mfma_f32_16x16x32_bf16(
                    ce, bfr[ni], acc[mi][ni], 0, 0, 0);
        }
    }

    // ---- epilogue: +D*xh, silu(z) gate, bf16 store + ssq ----
    float Dv = Dh[h];
#pragma unroll
    for (int mi = 0; mi < 4; ++mi)
#pragma unroll
        for (int i = 0; i < 4; ++i) {
            int l = lbase + mi * 16 + quad * 4 + i;
            long row = row0 + l;
            float ps = 0.f;
#pragma unroll
            for (int ni = 0; ni < 4; ++ni) {
                int p = ni * 16 + lm;
                float xh = bf2f(xBC_bf[row * CONVD + h * HEADDIM + p]);
                float z = bf2f(zxb[row * DINP + h * HEADDIM + p]);
                float o = (acc[mi][ni][i] + Dv * xh) * (z / (1.f + __expf(-z)));
                ps += o * o;
                ybf[row * DINNER + h * HEADDIM + p] = f2bf(o);
            }
#pragma unroll
            for (int m = 1; m < 16; m <<= 1) ps += __shfl_xor(ps, m, 64);
            if (lm == 0) atomicAdd(&ssq[row], ps);
        }
}

// ============================================================
// launch
// ============================================================
extern "C" void kernel_launch(void* const* d_in, const int* in_sizes, int n_in,
                              void* d_out, int out_size, void* d_ws, size_t ws_size,
                              hipStream_t stream)
{
    (void)in_sizes; (void)n_in; (void)out_size; (void)ws_size;
    const float* x          = (const float*)d_in[0];
    const float* norm_w     = (const float*)d_in[1];
    const float* in_proj_w  = (const float*)d_in[2];
    const float* conv_w     = (const float*)d_in[3];
    const float* conv_b     = (const float*)d_in[4];
    const float* dt_bias    = (const float*)d_in[5];
    const float* A_log      = (const float*)d_in[6];
    const float* Dh         = (const float*)d_in[7];
    const float* gnorm_w    = (const float*)d_in[8];
    const float* out_proj_w = (const float*)d_in[9];
    float* out = (float*)d_out;
    float* ws = (float*)d_ws;

    // workspace layout (float slots); total ~90 MB
    float* zxb_f   = ws;                       //  8,978,432 (bf16 4096x4384)
    float* xbc_f   = zxb_f   + 8978432;        //  4,718,592 (bf16 4096x2304)
    float* dtv     = xbc_f   + 4718592;        //    131,072
    float* acs     = dtv     + 131072;         //    131,072
    float* g2_f    = acs     + 131072;         //    524,288 (bf16 [bc][l][s])
    float* state_f = g2_f    + 524288;         //  2,097,152 (bf16 [bc][h][p][n])
    float* bt_f    = state_f + 2097152;        //    262,144 (bf16 [bc][n][l])
    float* regU    = bt_f    + 262144;         //  4,390,912 (xn_bf+wi_bf, later ybf)
    float* wo_f    = regU    + 4390912;        //  1,048,576 (wo_bf)
    float* ssq     = wo_f    + 1048576;        //      4,096

    ushort* zxb_bf = (ushort*)zxb_f;
    ushort* xBC_bf = (ushort*)xbc_f;
    ushort* G2b    = (ushort*)g2_f;
    ushort* state  = (ushort*)state_f;
    ushort* Bt     = (ushort*)bt_f;
    ushort* xn_bf  = (ushort*)regU;                 // 4096x1024 [dead after in_proj]
    ushort* wi_bf  = (ushort*)(regU + 2097152);     // 4416x1024 [dead after in_proj]
    ushort* ybf    = (ushort*)regU;                 // 4096x2048 [born at ssd_y]
    ushort* wo_bf  = (ushort*)wo_f;

    // 0. prologue (wi cvt, wo'·gw cvt, rmsnorm, ssq=0)
    prologue_kernel<<<dim3(10576), 256, 0, stream>>>(
        x, norm_w, in_proj_w, out_proj_w, gnorm_w, xn_bf, wi_bf, wo_bf, ssq);

    // 1. zxbcdt = xn @ in_proj_w^T -> bf16 (M=4096, N=4384 pad 4416, K=1024)
    gemm_bf16_kernel<<<dim3(32 * 69), 256, 0, stream>>>(
        xn_bf, DMODEL, 0, wi_bf, DMODEL, 0,
        zxb_bf, DINP, 0, 1, nullptr, nullptr, 32, 69, DINP, DMODEL);

    // 2. conv+SiLU and dt-softplus+cumsum
    conv_acs_kernel<<<dim3(NROWS * 9 + BB * NCH * NHEADS), 256, 0, stream>>>(
        zxb_bf, conv_w, conv_b, xBC_bf, dt_bias, A_log, dtv, acs);

    // 3. Bt (shared B^T operand)
    prep_b_kernel<<<dim3(BB * NCH, 2), 256, 0, stream>>>(xBC_bf, Bt);

    // 4. G2[bc][l][s] = C_l . B_s -> bf16 (batched; M=N=256, K=128)
    gemm_bf16_kernel<<<dim3(8, 1, BB * NCH), 256, 0, stream>>>(
        xBC_bf + DINNER + DSTATE, CONVD, (long)CHUNK * CONVD,
        xBC_bf + DINNER, CONVD, (long)CHUNK * CONVD,
        G2b, CHUNK, (long)CHUNK * CHUNK, 1, nullptr, nullptr, 2, 4, CHUNK, DSTATE);

    // 5. chunk states (MFMA, in-LDS transpose) -> bf16 state
    chunk_state_mfma_kernel<<<dim3(BB * NCH, NHEADS), 256, 0, stream>>>(
        xBC_bf, Bt, dtv, acs, state);

    // 6. inter-chunk scan (in place, bf16)
    state_scan_kernel<<<dim3(BB * NHEADS * 8192 / 256), 256, 0, stream>>>(state, acs);

    // 7. Y (MFMA diag+off) + D*xh, silu(z) gate -> ybf + ssq
    ssd_y_mfma_kernel<<<dim3(BB * NCH, NHEADS), 256, 0, stream>>>(
        xBC_bf, G2b, acs, state, zxb_bf, dtv, Dh, ybf, ssq);

    // 8. out = x + rsqrt(ssq/D+eps)*(y @ (gw·Wo)^T)  (fused gnorm)
    gemm_bf16_kernel<<<dim3(32 * 16), 256, 0, stream>>>(
        ybf, DINNER, 0, wo_bf, DINNER, 0,
        out, DMODEL, 0, 0, x, ssq, 32, 16, DMODEL, DINNER);
}

// Round 9
// 304.992 us; speedup vs baseline: 4.3104x; 1.0021x over previous
//
#include <hip/hip_runtime.h>
#include <hip/hip_bf16.h>

// ---- problem constants ----
#define BB      2
#define LSEQ    2048
#define DMODEL  1024
#define DSTATE  128
#define DCONV   4
#define HEADDIM 64
#define DINNER  2048      // EXP*DMODEL
#define NHEADS  32        // DINNER/HEADDIM
#define CONVD   2304      // DINNER + 2*DSTATE
#define DINP    4384      // 2*DINNER + 2*DSTATE + NHEADS
#define CHUNK   256
#define NCH     8         // LSEQ/CHUNK
#define NROWS   4096      // BB*LSEQ
#define EPSF    1e-5f
#define TPAD    264       // LDS transpose row pitch (ushort)

typedef __attribute__((ext_vector_type(8))) short bf16x8;
typedef __attribute__((ext_vector_type(4))) float f32x4;

#define ASYNC_COPY16(gptr, lptr) \
    __builtin_amdgcn_global_load_lds((const __attribute__((address_space(1))) void*)(gptr), \
                                     (__attribute__((address_space(3))) void*)(lptr), 16, 0, 0)

__device__ __forceinline__ ushort f2bf(float f) {
    __hip_bfloat16 h = __float2bfloat16(f);
    return *(ushort*)&h;
}
__device__ __forceinline__ float bf2f(ushort u) {
    return __uint_as_float(((unsigned)u) << 16);
}
__device__ __forceinline__ short fb(float f) { return (short)f2bf(f); }
// truncation (toward zero) float->bf16: 1 op, <=2^-8 rel err — hot paths only
__device__ __forceinline__ short tb(float f) { return (short)(__float_as_uint(f) >> 16); }

// ============================================================
// Prologue: wi cvt (padded), wo cvt (pre-scaled by gnorm_w),
// rmsnorm->bf16, ssq zeroing.
// grid: [0,4416) wi | [4416,6464) wo | [6464,10560) rmsnorm | [10560,10576) ssq=0
// ============================================================
__global__ __launch_bounds__(256) void prologue_kernel(
    const float* __restrict__ x, const float* __restrict__ norm_w,
    const float* __restrict__ in_proj_w, const float* __restrict__ out_proj_w,
    const float* __restrict__ gnorm_w,
    ushort* __restrict__ xn_bf, ushort* __restrict__ wi_bf,
    ushort* __restrict__ wo_bf, float* __restrict__ ssq)
{
    int bid = blockIdx.x;
    if (bid < 4416) {                 // wi: 4416x1024 bf16, zero-pad rows >= 4384
        long i4 = ((long)bid * 256 + threadIdx.x) * 4;
        int n = (int)(i4 >> 10);
        long k = i4 & 1023;
        ushort4 o;
        if (n < DINP) {
            float4 v = *(const float4*)(in_proj_w + ((long)n << 10) + k);
            o.x = f2bf(v.x); o.y = f2bf(v.y); o.z = f2bf(v.z); o.w = f2bf(v.w);
        } else { o.x = o.y = o.z = o.w = 0; }
        *(ushort4*)(wi_bf + i4) = o;
    } else if (bid < 6464) {          // wo': 1024x2048 bf16, folded gnorm_w
        long i4 = ((long)(bid - 4416) * 256 + threadIdx.x) * 4;
        int k = (int)(i4 & 2047);
        float4 v = *(const float4*)(out_proj_w + i4);
        float4 g = *(const float4*)(gnorm_w + k);
        ushort4 o;
        o.x = f2bf(v.x * g.x); o.y = f2bf(v.y * g.y);
        o.z = f2bf(v.z * g.z); o.w = f2bf(v.w * g.w);
        *(ushort4*)(wo_bf + i4) = o;
    } else if (bid < 10560) {         // rmsnorm row -> bf16
        int row = bid - 6464;
        const float* xr = x + (long)row * DMODEL;
        float4 v = *(const float4*)(xr + threadIdx.x * 4);
        float ss = v.x*v.x + v.y*v.y + v.z*v.z + v.w*v.w;
        for (int off = 32; off; off >>= 1) ss += __shfl_down(ss, off, 64);
        __shared__ float red[4];
        if ((threadIdx.x & 63) == 0) red[threadIdx.x >> 6] = ss;
        __syncthreads();
        float tot = red[0] + red[1] + red[2] + red[3];
        float scale = rsqrtf(tot / (float)DMODEL + EPSF);
        float4 wv = *(const float4*)(norm_w + threadIdx.x * 4);
        ushort4 o;
        o.x = f2bf(v.x * scale * wv.x); o.y = f2bf(v.y * scale * wv.y);
        o.z = f2bf(v.z * scale * wv.z); o.w = f2bf(v.w * scale * wv.w);
        *(ushort4*)(xn_bf + (long)row * DMODEL + threadIdx.x * 4) = o;
    } else {                          // ssq = 0
        ssq[(bid - 10560) * 256 + threadIdx.x] = 0.f;
    }
}

// ============================================================
// bf16 MFMA NT GEMM (batched, strided, swizzled 1D grid):
//   C[m,n] = sum_k A[m,k]*W[n,k]  (*rowscale[m] +resid, fp32 out)
// 128x64 tile, BK=64, mfma_f32_16x16x32_bf16, XOR-swizzled
// global_load_lds(16B) staging, LDS-bounce coalesced epilogue.
// ============================================================
__global__ __launch_bounds__(256, 4) void gemm_bf16_kernel(
    const ushort* __restrict__ A, int lda, long sA,
    const ushort* __restrict__ W, int ldw, long sW,
    void* __restrict__ Cout, int ldc, long sC, int c_bf16,
    const float* __restrict__ resid, const float* __restrict__ rowscale,
    int mtiles, int ntiles, int N, int K)
{
    __shared__ __align__(16) char smem[24576];
    ushort* As = (ushort*)smem;          // 128*64 ushort = 16 KB
    ushort* Bs = As + 128 * 64;          //  64*64 ushort =  8 KB
    ushort* tu = (ushort*)smem;          // epilogue bf16 tile [128][72]
    float*  tf = (float*)smem;           // epilogue fp32 tile [64][68]

    const int t = threadIdx.x;
    const int lane = t & 63;
    const int w = t >> 6;
    const int wm = w & 1, wn = w >> 1;
    const int lm = lane & 15, quad = lane >> 4;

    int pid = blockIdx.x;
    const int GM = 8;
    int width = GM * ntiles;
    int group = pid / width;
    int first_m = group * GM;
    int gsz = mtiles - first_m; if (gsz > GM) gsz = GM;
    int mt = first_m + (pid % width) % gsz;
    int nt = (pid % width) / gsz;
    const int m0 = mt * 128, n0 = nt * 64;

    A += (long)blockIdx.z * sA;
    W += (long)blockIdx.z * sW;

    const ushort* ga[4]; const ushort* gw[2];
#pragma unroll
    for (int i = 0; i < 4; ++i) {
        int s = i * 256 + t;
        int row = s >> 3;
        int kseg = (s & 7) ^ (row & 7);
        ga[i] = A + (long)(m0 + row) * lda + kseg * 8;
    }
#pragma unroll
    for (int i = 0; i < 2; ++i) {
        int s = i * 256 + t;
        int row = s >> 3;
        int kseg = (s & 7) ^ (row & 7);
        gw[i] = W + (long)(n0 + row) * ldw + kseg * 8;
    }

    f32x4 acc[4][2];
    f32x4 zero4 = {0.f, 0.f, 0.f, 0.f};
#pragma unroll
    for (int i = 0; i < 4; ++i) { acc[i][0] = zero4; acc[i][1] = zero4; }

    int arow8[4], arow7[4], brow8[2], brow7[2];
#pragma unroll
    for (int i = 0; i < 4; ++i) {
        int ar = wm * 64 + i * 16 + lm;
        arow8[i] = ar * 8; arow7[i] = ar & 7;
    }
#pragma unroll
    for (int i = 0; i < 2; ++i) {
        int br = wn * 32 + i * 16 + lm;
        brow8[i] = br * 8; brow7[i] = br & 7;
    }

    for (int k0 = 0; k0 < K; k0 += 64) {
#pragma unroll
        for (int i = 0; i < 4; ++i) {
            ASYNC_COPY16(ga[i], &As[(i * 256 + w * 64) * 8]);
            ga[i] += 64;
        }
#pragma unroll
        for (int i = 0; i < 2; ++i) {
            ASYNC_COPY16(gw[i], &Bs[(i * 256 + w * 64) * 8]);
            gw[i] += 64;
        }
        __syncthreads();
#pragma unroll
        for (int ks = 0; ks < 2; ++ks) {
            bf16x8 af[4], bfr[2];
#pragma unroll
            for (int i = 0; i < 4; ++i)
                af[i]  = *(const bf16x8*)&As[(arow8[i] + ((ks * 4 + quad) ^ arow7[i])) * 8];
#pragma unroll
            for (int i = 0; i < 2; ++i)
                bfr[i] = *(const bf16x8*)&Bs[(brow8[i] + ((ks * 4 + quad) ^ brow7[i])) * 8];
#pragma unroll
            for (int im = 0; im < 4; ++im)
#pragma unroll
                for (int in = 0; in < 2; ++in)
                    acc[im][in] = __builtin_amdgcn_mfma_f32_16x16x32_bf16(
                        af[im], bfr[in], acc[im][in], 0, 0, 0);
        }
        __syncthreads();
    }

    // ---- epilogue: LDS bounce -> coalesced full-line stores ----
    if (c_bf16) {
        ushort* C = (ushort*)Cout + (long)blockIdx.z * sC;
#pragma unroll
        for (int mi = 0; mi < 4; ++mi)
#pragma unroll
            for (int ni = 0; ni < 2; ++ni) {
                int c = wn * 32 + ni * 16 + lm;
#pragma unroll
                for (int i = 0; i < 4; ++i) {
                    int r = wm * 64 + mi * 16 + quad * 4 + i;
                    tu[r * 72 + c] = f2bf(acc[mi][ni][i]);
                }
            }
        __syncthreads();
        int r = t >> 1, cb = (t & 1) * 32;
        long rowbase = (long)(m0 + r) * ldc + n0 + cb;
#pragma unroll
        for (int q = 0; q < 4; ++q) {
            int gcol = n0 + cb + q * 8;
            if (gcol < N)
                *(bf16x8*)(C + rowbase + q * 8) =
                    *(const bf16x8*)&tu[r * 72 + cb + q * 8];
        }
    } else {
        float* C = (float*)Cout + (long)blockIdx.z * sC;
#pragma unroll
        for (int p = 0; p < 2; ++p) {
            if (wm == p) {
#pragma unroll
                for (int mi = 0; mi < 4; ++mi)
#pragma unroll
                    for (int i = 0; i < 4; ++i) {
                        int r = mi * 16 + quad * 4 + i;
                        float s = 1.f;
                        if (rowscale)
                            s = rsqrtf(rowscale[m0 + p * 64 + r] * (1.f / (float)DINNER) + EPSF);
#pragma unroll
                        for (int ni = 0; ni < 2; ++ni) {
                            int c = wn * 32 + ni * 16 + lm;
                            tf[r * 68 + c] = acc[mi][ni][i] * s;
                        }
                    }
            }
            __syncthreads();
            int r2 = t >> 2, cb = (t & 3) * 16;
            long gbase = (long)(m0 + p * 64 + r2) * ldc + n0 + cb;
#pragma unroll
            for (int q = 0; q < 4; ++q) {
                float4 v = *(const float4*)&tf[r2 * 68 + cb + q * 4];
                if (resid) {
                    float4 rv = *(const float4*)(resid + gbase + q * 4);
                    v.x += rv.x; v.y += rv.y; v.z += rv.z; v.w += rv.w;
                }
                *(float4*)(C + gbase + q * 4) = v;
            }
            __syncthreads();
        }
    }
}

// ============================================================
// Merged: vectorized conv+SiLU (8ch/thread), conv tail, dt+cumsum,
// and prep_b (Bt transpose with inline conv from zxb).
// grid: [0,4096) conv8 | [4096,8192) conv tail | [8192,8704) acs
//       [8704,8736) prep_b
// ============================================================
__global__ __launch_bounds__(256) void conv_acs_kernel(
    const ushort* __restrict__ zx, const float* __restrict__ cw,
    const float* __restrict__ cb, ushort* __restrict__ xBC_bf,
    const float* __restrict__ dt_bias, const float* __restrict__ A_log,
    float* __restrict__ dtv, float* __restrict__ Acs,
    ushort* __restrict__ Bt)
{
    __shared__ ushort tB[64 * TPAD];   // prep_b transpose / acs scan alias
    int bid = blockIdx.x;
    int t = threadIdx.x;
    if (bid < NROWS) {
        // ---- conv, 8 channels/thread (ch 0..2047) ----
        int row = bid;
        int l = row & (LSEQ - 1);
        int c = t * 8;
        float4 cwv[8];
#pragma unroll
        for (int j = 0; j < 8; ++j) cwv[j] = *(const float4*)(cw + (c + j) * 4);
        float acc[8];
        {
            float4 b0 = *(const float4*)(cb + c);
            float4 b1 = *(const float4*)(cb + c + 4);
            acc[0] = b0.x; acc[1] = b0.y; acc[2] = b0.z; acc[3] = b0.w;
            acc[4] = b1.x; acc[5] = b1.y; acc[6] = b1.z; acc[7] = b1.w;
        }
#pragma unroll
        for (int k = 0; k < DCONV; ++k) {
            int ls = l + k - (DCONV - 1);
            if (ls >= 0) {
                const ushort* zr = zx + (long)(row + k - (DCONV - 1)) * DINP + DINNER + c;
                ushort4 a = *(const ushort4*)zr;
                ushort4 b = *(const ushort4*)(zr + 4);
                acc[0] += bf2f(a.x) * ((const float*)&cwv[0])[k];
                acc[1] += bf2f(a.y) * ((const float*)&cwv[1])[k];
                acc[2] += bf2f(a.z) * ((const float*)&cwv[2])[k];
                acc[3] += bf2f(a.w) * ((const float*)&cwv[3])[k];
                acc[4] += bf2f(b.x) * ((const float*)&cwv[4])[k];
                acc[5] += bf2f(b.y) * ((const float*)&cwv[5])[k];
                acc[6] += bf2f(b.z) * ((const float*)&cwv[6])[k];
                acc[7] += bf2f(b.w) * ((const float*)&cwv[7])[k];
            }
        }
        ushort o[8];
#pragma unroll
        for (int j = 0; j < 8; ++j)
            o[j] = f2bf(acc[j] / (1.f + __expf(-acc[j])));
        ushort* dst = xBC_bf + (long)row * CONVD + c;
        *(ushort4*)dst = *(ushort4*)&o[0];
        *(ushort4*)(dst + 4) = *(ushort4*)&o[4];
    } else if (bid < 2 * NROWS) {
        // ---- conv tail: ch 2048..2303, 1 ch/thread ----
        int row = bid - NROWS;
        int c = 2048 + t;
        int l = row & (LSEQ - 1);
        float acc = cb[c];
#pragma unroll
        for (int k = 0; k < DCONV; ++k) {
            int ls = l + k - (DCONV - 1);
            if (ls >= 0)
                acc += bf2f(zx[(long)(row + k - (DCONV - 1)) * DINP + DINNER + c]) * cw[c * DCONV + k];
        }
        xBC_bf[(long)row * CONVD + c] = f2bf(acc / (1.f + __expf(-acc)));
    } else if (bid < 2 * NROWS + BB * NCH * NHEADS) {
        // ---- dt softplus + per-chunk cumsum ----
        int idx = bid - 2 * NROWS;
        int bc = idx >> 5, h = idx & 31;
        int l = t;
        int row = bc * CHUNK + l;
        float v = bf2f(zx[(long)row * DINP + (DINP - NHEADS) + h]) + dt_bias[h];
        float d = (v > 20.f) ? v : log1pf(__expf(v));
        dtv[row * NHEADS + h] = d;
        float a = -d * __expf(A_log[h]);
        float* buf = (float*)tB;          // [2][CHUNK]
        buf[l] = a; __syncthreads();
        int src = 0;
        for (int off = 1; off < CHUNK; off <<= 1) {
            float vv = buf[src * CHUNK + l];
            if (l >= off) vv += buf[src * CHUNK + l - off];
            buf[(src ^ 1) * CHUNK + l] = vv;
            __syncthreads();
            src ^= 1;
        }
        Acs[(bc * NHEADS + h) * CHUNK + l] = buf[src * CHUNK + l];
    } else {
        // ---- prep_b: Bt[bc][n][l] = conv_silu(B)[l][n], inline conv ----
        int idx = bid - (2 * NROWS + BB * NCH * NHEADS);
        int bc = idx >> 1, half = idx & 1;
        int row0 = bc * CHUNK;
        int cc8 = (t & 7) * 8;
        int cxbc = 2048 + half * 64 + cc8;       // xBC channel of first of 8
        float4 cwv[8];
#pragma unroll
        for (int j = 0; j < 8; ++j) cwv[j] = *(const float4*)(cw + (cxbc + j) * 4);
        float cb0[8];
        {
            float4 b0 = *(const float4*)(cb + cxbc);
            float4 b1 = *(const float4*)(cb + cxbc + 4);
            cb0[0] = b0.x; cb0[1] = b0.y; cb0[2] = b0.z; cb0[3] = b0.w;
            cb0[4] = b1.x; cb0[5] = b1.y; cb0[6] = b1.z; cb0[7] = b1.w;
        }
        for (int iter = 0; iter < 8; ++iter) {
            int l = iter * 32 + (t >> 3);
            int row = row0 + l;
            float acc[8];
#pragma unroll
            for (int j = 0; j < 8; ++j) acc[j] = cb0[j];
#pragma unroll
            for (int k = 0; k < DCONV; ++k) {
                int ls = l + k - (DCONV - 1);
                if (ls >= 0) {
                    const ushort* zr = zx + (long)(row + k - (DCONV - 1)) * DINP + DINNER + cxbc;
                    ushort4 a = *(const ushort4*)zr;
                    ushort4 b = *(const ushort4*)(zr + 4);
                    acc[0] += bf2f(a.x) * ((const float*)&cwv[0])[k];
                    acc[1] += bf2f(a.y) * ((const float*)&cwv[1])[k];
                    acc[2] += bf2f(a.z) * ((const float*)&cwv[2])[k];
                    acc[3] += bf2f(a.w) * ((const float*)&cwv[3])[k];
                    acc[4] += bf2f(b.x) * ((const float*)&cwv[4])[k];
                    acc[5] += bf2f(b.y) * ((const float*)&cwv[5])[k];
                    acc[6] += bf2f(b.z) * ((const float*)&cwv[6])[k];
                    acc[7] += bf2f(b.w) * ((const float*)&cwv[7])[k];
                }
            }
#pragma unroll
            for (int j = 0; j < 8; ++j)
                tB[(cc8 + j) * TPAD + l] = (ushort)tb(acc[j] / (1.f + __expf(-acc[j])));
        }
        __syncthreads();
        int r = t >> 2, seg = (t & 3) * 64;
        ushort* dst = Bt + ((long)bc * DSTATE + half * 64 + r) * CHUNK + seg;
        const ushort* s1 = &tB[r * TPAD + seg];
#pragma unroll
        for (int q = 0; q < 16; ++q)
            *(ushort4*)(dst + q * 4) = *(const ushort4*)(s1 + q * 4);
    }
}

// ============================================================
// Chunk state via MFMA with in-LDS X transpose:
//   S_t[p][n] = sum_l exp(T-acs_l)*dt_l*X[l,p] * Bt[n][l]  -> bf16
// ============================================================
__global__ __launch_bounds__(256) void chunk_state_mfma_kernel(
    const ushort* __restrict__ xBC_bf, const ushort* __restrict__ Bt,
    const float* __restrict__ dtv, const float* __restrict__ acs,
    ushort* __restrict__ state)
{
    int bc = blockIdx.x, h = blockIdx.y;
    int t = threadIdx.x, lane = t & 63, w = t >> 6;
    int lm = lane & 15, quad = lane >> 4;
    int row0 = bc * CHUNK;
    __shared__ ushort xt[64 * TPAD];
    __shared__ float cl[CHUNK];
    {
        float a = acs[(bc * NHEADS + h) * CHUNK + t];
        float T = acs[(bc * NHEADS + h) * CHUNK + CHUNK - 1];
        cl[t] = __expf(T - a) * dtv[(row0 + t) * NHEADS + h];
    }
    __syncthreads();
    for (int iter = 0; iter < 8; ++iter) {
        int l = iter * 32 + (t >> 3);
        int cc = (t & 7) * 8;
        ushort u[8];
        *(ushort4*)&u[0] = *(const ushort4*)(xBC_bf + (long)(row0 + l) * CONVD + h * HEADDIM + cc);
        *(ushort4*)&u[4] = *(const ushort4*)(xBC_bf + (long)(row0 + l) * CONVD + h * HEADDIM + cc + 4);
        float sc = cl[l];
#pragma unroll
        for (int j = 0; j < 8; ++j)
            xt[(cc + j) * TPAD + l] = (ushort)tb(bf2f(u[j]) * sc);
    }
    __syncthreads();

    const ushort* Bb = Bt + (long)bc * DSTATE * CHUNK;
    f32x4 acc[4][2];
    f32x4 zero4 = {0.f, 0.f, 0.f, 0.f};
#pragma unroll
    for (int i = 0; i < 4; ++i) { acc[i][0] = zero4; acc[i][1] = zero4; }

    for (int kt = 0; kt < 8; ++kt) {
        int k = kt * 32 + quad * 8;
        bf16x8 af[4], bfr[2];
#pragma unroll
        for (int mi = 0; mi < 4; ++mi)
            af[mi] = *(const bf16x8*)&xt[(mi * 16 + lm) * TPAD + k];
#pragma unroll
        for (int nj = 0; nj < 2; ++nj)
            bfr[nj] = *(const bf16x8*)(Bb + (long)(w * 32 + nj * 16 + lm) * CHUNK + k);
#pragma unroll
        for (int mi = 0; mi < 4; ++mi)
#pragma unroll
            for (int nj = 0; nj < 2; ++nj)
                acc[mi][nj] = __builtin_amdgcn_mfma_f32_16x16x32_bf16(
                    af[mi], bfr[nj], acc[mi][nj], 0, 0, 0);
    }
    ushort* sp = state + (long)(bc * NHEADS + h) * (DSTATE * HEADDIM);
#pragma unroll
    for (int mi = 0; mi < 4; ++mi)
#pragma unroll
        for (int nj = 0; nj < 2; ++nj) {
            int n = w * 32 + nj * 16 + lm;
#pragma unroll
            for (int i = 0; i < 4; ++i) {
                int p = mi * 16 + quad * 4 + i;
                sp[p * DSTATE + n] = f2bf(acc[mi][nj][i]);
            }
        }
}

// ============================================================
// Inter-chunk scan (in place on bf16 states, fp32 accumulator)
// ============================================================
__global__ __launch_bounds__(256) void state_scan_kernel(
    ushort* __restrict__ state, const float* __restrict__ Acs)
{
    long flat = (long)blockIdx.x * 256 + threadIdx.x;
    int e = (int)(flat & 8191);
    int bh = (int)(flat >> 13);
    int b = bh >> 5, h = bh & 31;
    float S = 0.f;
    for (int c = 0; c < NCH; ++c) {
        int bc = b * NCH + c;
        long idx = ((long)(bc * NHEADS + h)) * 8192 + e;
        float T = Acs[(bc * NHEADS + h) * CHUNK + CHUNK - 1];
        float tmp = bf2f(state[idx]);
        state[idx] = f2bf(S);
        S = S * __expf(T) + tmp;
    }
}

// ============================================================
// SSD Y via MFMA (in-LDS Xdt transpose): Y = P@Xdt + (C*eAl)@S^T,
// then +D*xh, silu(z) gate, bf16 store + per-row ssq atomics.
// P-build uses factored exps: exp(al-a8[j]) = exp(al-base)*exp(base-a8[j])
// (base = a8[0], cumsum non-increasing => both factors bounded; args clamped)
// ============================================================
__global__ __launch_bounds__(256) void ssd_y_mfma_kernel(
    const ushort* __restrict__ xBC_bf, const ushort* __restrict__ G2b,
    const float* __restrict__ acs, const ushort* __restrict__ state,
    const ushort* __restrict__ zxb, const float* __restrict__ dtv,
    const float* __restrict__ Dh, ushort* __restrict__ ybf,
    float* __restrict__ ssq)
{
    int bc = blockIdx.x, h = blockIdx.y;
    int t = threadIdx.x, lane = t & 63, w = t >> 6;
    int lm = lane & 15, quad = lane >> 4;
    int row0 = bc * CHUNK;
    __shared__ ushort xt[64 * TPAD];
    __shared__ float acs_s[CHUNK];
    __shared__ float dl[CHUNK];
    acs_s[t] = acs[(bc * NHEADS + h) * CHUNK + t];
    dl[t] = dtv[(row0 + t) * NHEADS + h];
    __syncthreads();
    // transpose X chunk (dt-scaled) into LDS [p][l]
    for (int iter = 0; iter < 8; ++iter) {
        int l = iter * 32 + (t >> 3);
        int cc = (t & 7) * 8;
        ushort u[8];
        *(ushort4*)&u[0] = *(const ushort4*)(xBC_bf + (long)(row0 + l) * CONVD + h * HEADDIM + cc);
        *(ushort4*)&u[4] = *(const ushort4*)(xBC_bf + (long)(row0 + l) * CONVD + h * HEADDIM + cc + 4);
        float sd = dl[l];
#pragma unroll
        for (int j = 0; j < 8; ++j)
            xt[(cc + j) * TPAD + l] = (ushort)tb(bf2f(u[j]) * sd);
    }
    __syncthreads();

    int lbase = w * 64;
    float acs_l[4], eAl[4];
#pragma unroll
    for (int mi = 0; mi < 4; ++mi) {
        acs_l[mi] = acs_s[lbase + mi * 16 + lm];
        eAl[mi] = __expf(acs_l[mi]);
    }
    f32x4 acc[4][4];
    f32x4 zero4 = {0.f, 0.f, 0.f, 0.f};
#pragma unroll
    for (int i = 0; i < 4; ++i)
#pragma unroll
        for (int j = 0; j < 4; ++j) acc[i][j] = zero4;

    const ushort* g2 = G2b + (long)bc * (CHUNK * CHUNK);

    // ---- phase A: diagonal (causal), factored exps ----
    for (int ks = 0; ks <= 2 * w + 1; ++ks) {
        int sq = ks * 32 + quad * 8;
        bf16x8 bfr[4];
#pragma unroll
        for (int ni = 0; ni < 4; ++ni)
            bfr[ni] = *(const bf16x8*)&xt[(ni * 16 + lm) * TPAD + sq];
        float base = acs_s[sq];
        float e8[8];
        e8[0] = 1.f;
#pragma unroll
        for (int j = 1; j < 8; ++j)
            e8[j] = __expf(fminf(base - acs_s[sq + j], 80.f));
#pragma unroll
        for (int mi = 0; mi < 4; ++mi) {
            int lmin = lbase + mi * 16;
            if (ks * 32 > lmin + 15) continue;
            int lv = lmin + lm;
            float em = __expf(fminf(acs_l[mi] - base, 0.f));
            bf16x8 g8 = *(const bf16x8*)(g2 + (long)lv * CHUNK + sq);
            bf16x8 af;
#pragma unroll
            for (int j = 0; j < 8; ++j) {
                float v = bf2f((ushort)g8[j]) * (em * e8[j]);
                af[j] = (sq + j > lv) ? (short)0 : tb(v);
            }
#pragma unroll
            for (int ni = 0; ni < 4; ++ni)
                acc[mi][ni] = __builtin_amdgcn_mfma_f32_16x16x32_bf16(
                    af, bfr[ni], acc[mi][ni], 0, 0, 0);
        }
    }

    // ---- phase B: off-diagonal (C*eAl @ S^T), bf16 state loads ----
    const ushort* sp = state + (long)(bc * NHEADS + h) * (DSTATE * HEADDIM);
    const ushort* Cb = xBC_bf + (long)row0 * CONVD + DINNER + DSTATE;
    for (int kt = 0; kt < 4; ++kt) {
        int n0 = kt * 32 + quad * 8;
        bf16x8 bfr[4];
#pragma unroll
        for (int ni = 0; ni < 4; ++ni)
            bfr[ni] = *(const bf16x8*)(sp + (long)(ni * 16 + lm) * DSTATE + n0);
#pragma unroll
        for (int mi = 0; mi < 4; ++mi) {
            int lv = lbase + mi * 16 + lm;
            bf16x8 cu = *(const bf16x8*)(Cb + (long)lv * CONVD + n0);
            bf16x8 ce;
            float e = eAl[mi];
#pragma unroll
            for (int j = 0; j < 8; ++j) ce[j] = tb(bf2f((ushort)cu[j]) * e);
#pragma unroll
            for (int ni = 0; ni < 4; ++ni)
                acc[mi][ni] = __builtin_amdgcn_mfma_f32_16x16x32_bf16(
                    ce, bfr[ni], acc[mi][ni], 0, 0, 0);
        }
    }

    // ---- epilogue: +D*xh, silu(z) gate, bf16 store + ssq ----
    float Dv = Dh[h];
#pragma unroll
    for (int mi = 0; mi < 4; ++mi)
#pragma unroll
        for (int i = 0; i < 4; ++i) {
            int l = lbase + mi * 16 + quad * 4 + i;
            long row = row0 + l;
            float ps = 0.f;
#pragma unroll
            for (int ni = 0; ni < 4; ++ni) {
                int p = ni * 16 + lm;
                float xh = bf2f(xBC_bf[row * CONVD + h * HEADDIM + p]);
                float z = bf2f(zxb[row * DINP + h * HEADDIM + p]);
                float o = (acc[mi][ni][i] + Dv * xh) * (z / (1.f + __expf(-z)));
                ps += o * o;
                ybf[row * DINNER + h * HEADDIM + p] = f2bf(o);
            }
#pragma unroll
            for (int m = 1; m < 16; m <<= 1) ps += __shfl_xor(ps, m, 64);
            if (lm == 0) atomicAdd(&ssq[row], ps);
        }
}

// ============================================================
// launch
// ============================================================
extern "C" void kernel_launch(void* const* d_in, const int* in_sizes, int n_in,
                              void* d_out, int out_size, void* d_ws, size_t ws_size,
                              hipStream_t stream)
{
    (void)in_sizes; (void)n_in; (void)out_size; (void)ws_size;
    const float* x          = (const float*)d_in[0];
    const float* norm_w     = (const float*)d_in[1];
    const float* in_proj_w  = (const float*)d_in[2];
    const float* conv_w     = (const float*)d_in[3];
    const float* conv_b     = (const float*)d_in[4];
    const float* dt_bias    = (const float*)d_in[5];
    const float* A_log      = (const float*)d_in[6];
    const float* Dh         = (const float*)d_in[7];
    const float* gnorm_w    = (const float*)d_in[8];
    const float* out_proj_w = (const float*)d_in[9];
    float* out = (float*)d_out;
    float* ws = (float*)d_ws;

    // workspace layout (float slots); total ~90 MB
    float* zxb_f   = ws;                       //  8,978,432 (bf16 4096x4384)
    float* xbc_f   = zxb_f   + 8978432;        //  4,718,592 (bf16 4096x2304)
    float* dtv     = xbc_f   + 4718592;        //    131,072
    float* acs     = dtv     + 131072;         //    131,072
    float* g2_f    = acs     + 131072;         //    524,288 (bf16 [bc][l][s])
    float* state_f = g2_f    + 524288;         //  2,097,152 (bf16 [bc][h][p][n])
    float* bt_f    = state_f + 2097152;        //    262,144 (bf16 [bc][n][l])
    float* regU    = bt_f    + 262144;         //  4,390,912 (xn_bf+wi_bf, later ybf)
    float* wo_f    = regU    + 4390912;        //  1,048,576 (wo_bf)
    float* ssq     = wo_f    + 1048576;        //      4,096

    ushort* zxb_bf = (ushort*)zxb_f;
    ushort* xBC_bf = (ushort*)xbc_f;
    ushort* G2b    = (ushort*)g2_f;
    ushort* state  = (ushort*)state_f;
    ushort* Bt     = (ushort*)bt_f;
    ushort* xn_bf  = (ushort*)regU;                 // 4096x1024 [dead after in_proj]
    ushort* wi_bf  = (ushort*)(regU + 2097152);     // 4416x1024 [dead after in_proj]
    ushort* ybf    = (ushort*)regU;                 // 4096x2048 [born at ssd_y]
    ushort* wo_bf  = (ushort*)wo_f;

    // 0. prologue (wi cvt, wo'·gw cvt, rmsnorm, ssq=0)
    prologue_kernel<<<dim3(10576), 256, 0, stream>>>(
        x, norm_w, in_proj_w, out_proj_w, gnorm_w, xn_bf, wi_bf, wo_bf, ssq);

    // 1. zxbcdt = xn @ in_proj_w^T -> bf16 (M=4096, N=4384 pad 4416, K=1024)
    gemm_bf16_kernel<<<dim3(32 * 69), 256, 0, stream>>>(
        xn_bf, DMODEL, 0, wi_bf, DMODEL, 0,
        zxb_bf, DINP, 0, 1, nullptr, nullptr, 32, 69, DINP, DMODEL);

    // 2. conv(vec8)+tail, dt-softplus+cumsum, prep_b (one launch)
    conv_acs_kernel<<<dim3(2 * NROWS + BB * NCH * NHEADS + BB * NCH * 2), 256, 0, stream>>>(
        zxb_bf, conv_w, conv_b, xBC_bf, dt_bias, A_log, dtv, acs, Bt);

    // 3. G2[bc][l][s] = C_l . B_s -> bf16 (batched; M=N=256, K=128)
    gemm_bf16_kernel<<<dim3(8, 1, BB * NCH), 256, 0, stream>>>(
        xBC_bf + DINNER + DSTATE, CONVD, (long)CHUNK * CONVD,
        xBC_bf + DINNER, CONVD, (long)CHUNK * CONVD,
        G2b, CHUNK, (long)CHUNK * CHUNK, 1, nullptr, nullptr, 2, 4, CHUNK, DSTATE);

    // 4. chunk states (MFMA, in-LDS transpose) -> bf16 state
    chunk_state_mfma_kernel<<<dim3(BB * NCH, NHEADS), 256, 0, stream>>>(
        xBC_bf, Bt, dtv, acs, state);

    // 5. inter-chunk scan (in place, bf16)
    state_scan_kernel<<<dim3(BB * NHEADS * 8192 / 256), 256, 0, stream>>>(state, acs);

    // 6. Y (MFMA diag+off) + D*xh, silu(z) gate -> ybf + ssq
    ssd_y_mfma_kernel<<<dim3(BB * NCH, NHEADS), 256, 0, stream>>>(
        xBC_bf, G2b, acs, state, zxb_bf, dtv, Dh, ybf, ssq);

    // 7. out = x + rsqrt(ssq/D+eps)*(y @ (gw·Wo)^T)  (fused gnorm)
    gemm_bf16_kernel<<<dim3(32 * 16), 256, 0, stream>>>(
        ybf, DINNER, 0, wo_bf, DINNER, 0,
        out, DMODEL, 0, 0, x, ssq, 32, 16, DMODEL, DINNER);
}

// Round 10
// 300.985 us; speedup vs baseline: 4.3678x; 1.0133x over previous
//
#include <hip/hip_runtime.h>
#include <hip/hip_bf16.h>

// ---- problem constants ----
#define BB      2
#define LSEQ    2048
#define DMODEL  1024
#define DSTATE  128
#define DCONV   4
#define HEADDIM 64
#define DINNER  2048      // EXP*DMODEL
#define NHEADS  32        // DINNER/HEADDIM
#define CONVD   2304      // DINNER + 2*DSTATE
#define DINP    4384      // 2*DINNER + 2*DSTATE + NHEADS
#define CHUNK   256
#define NCH     8         // LSEQ/CHUNK
#define NROWS   4096      // BB*LSEQ
#define EPSF    1e-5f
#define TPAD    264       // LDS transpose row pitch (ushort)

typedef __attribute__((ext_vector_type(8))) short bf16x8;
typedef __attribute__((ext_vector_type(4))) float f32x4;

#define ASYNC_COPY16(gptr, lptr) \
    __builtin_amdgcn_global_load_lds((const __attribute__((address_space(1))) void*)(gptr), \
                                     (__attribute__((address_space(3))) void*)(lptr), 16, 0, 0)

__device__ __forceinline__ ushort f2bf(float f) {
    __hip_bfloat16 h = __float2bfloat16(f);
    return *(ushort*)&h;
}
__device__ __forceinline__ float bf2f(ushort u) {
    return __uint_as_float(((unsigned)u) << 16);
}
__device__ __forceinline__ short fb(float f) { return (short)f2bf(f); }
// truncation (toward zero) float->bf16: 1 op, <=2^-8 rel err — hot paths only
__device__ __forceinline__ short tb(float f) { return (short)(__float_as_uint(f) >> 16); }

// ============================================================
// Prologue: wi cvt (padded), wo cvt (pre-scaled by gnorm_w),
// rmsnorm->bf16, ssq zeroing.
// grid: [0,4416) wi | [4416,6464) wo | [6464,10560) rmsnorm | [10560,10576) ssq=0
// ============================================================
__global__ __launch_bounds__(256) void prologue_kernel(
    const float* __restrict__ x, const float* __restrict__ norm_w,
    const float* __restrict__ in_proj_w, const float* __restrict__ out_proj_w,
    const float* __restrict__ gnorm_w,
    ushort* __restrict__ xn_bf, ushort* __restrict__ wi_bf,
    ushort* __restrict__ wo_bf, float* __restrict__ ssq)
{
    int bid = blockIdx.x;
    if (bid < 4416) {                 // wi: 4416x1024 bf16, zero-pad rows >= 4384
        long i4 = ((long)bid * 256 + threadIdx.x) * 4;
        int n = (int)(i4 >> 10);
        long k = i4 & 1023;
        ushort4 o;
        if (n < DINP) {
            float4 v = *(const float4*)(in_proj_w + ((long)n << 10) + k);
            o.x = f2bf(v.x); o.y = f2bf(v.y); o.z = f2bf(v.z); o.w = f2bf(v.w);
        } else { o.x = o.y = o.z = o.w = 0; }
        *(ushort4*)(wi_bf + i4) = o;
    } else if (bid < 6464) {          // wo': 1024x2048 bf16, folded gnorm_w
        long i4 = ((long)(bid - 4416) * 256 + threadIdx.x) * 4;
        int k = (int)(i4 & 2047);
        float4 v = *(const float4*)(out_proj_w + i4);
        float4 g = *(const float4*)(gnorm_w + k);
        ushort4 o;
        o.x = f2bf(v.x * g.x); o.y = f2bf(v.y * g.y);
        o.z = f2bf(v.z * g.z); o.w = f2bf(v.w * g.w);
        *(ushort4*)(wo_bf + i4) = o;
    } else if (bid < 10560) {         // rmsnorm row -> bf16
        int row = bid - 6464;
        const float* xr = x + (long)row * DMODEL;
        float4 v = *(const float4*)(xr + threadIdx.x * 4);
        float ss = v.x*v.x + v.y*v.y + v.z*v.z + v.w*v.w;
        for (int off = 32; off; off >>= 1) ss += __shfl_down(ss, off, 64);
        __shared__ float red[4];
        if ((threadIdx.x & 63) == 0) red[threadIdx.x >> 6] = ss;
        __syncthreads();
        float tot = red[0] + red[1] + red[2] + red[3];
        float scale = rsqrtf(tot / (float)DMODEL + EPSF);
        float4 wv = *(const float4*)(norm_w + threadIdx.x * 4);
        ushort4 o;
        o.x = f2bf(v.x * scale * wv.x); o.y = f2bf(v.y * scale * wv.y);
        o.z = f2bf(v.z * scale * wv.z); o.w = f2bf(v.w * scale * wv.w);
        *(ushort4*)(xn_bf + (long)row * DMODEL + threadIdx.x * 4) = o;
    } else {                          // ssq = 0
        ssq[(bid - 10560) * 256 + threadIdx.x] = 0.f;
    }
}

// ============================================================
// bf16 MFMA NT GEMM (batched, strided, swizzled 1D grid):
//   C[m,n] = sum_k A[m,k]*W[n,k]  (*rowscale[m] +resid, fp32 out)
// 128x64 tile, BK=64, mfma_f32_16x16x32_bf16, XOR-swizzled
// global_load_lds(16B) staging, LDS-bounce coalesced epilogue.
// ============================================================
__global__ __launch_bounds__(256, 4) void gemm_bf16_kernel(
    const ushort* __restrict__ A, int lda, long sA,
    const ushort* __restrict__ W, int ldw, long sW,
    void* __restrict__ Cout, int ldc, long sC, int c_bf16,
    const float* __restrict__ resid, const float* __restrict__ rowscale,
    int mtiles, int ntiles, int N, int K)
{
    __shared__ __align__(16) char smem[24576];
    ushort* As = (ushort*)smem;          // 128*64 ushort = 16 KB
    ushort* Bs = As + 128 * 64;          //  64*64 ushort =  8 KB
    ushort* tu = (ushort*)smem;          // epilogue bf16 tile [128][72]
    float*  tf = (float*)smem;           // epilogue fp32 tile [64][68]

    const int t = threadIdx.x;
    const int lane = t & 63;
    const int w = t >> 6;
    const int wm = w & 1, wn = w >> 1;
    const int lm = lane & 15, quad = lane >> 4;

    int pid = blockIdx.x;
    const int GM = 8;
    int width = GM * ntiles;
    int group = pid / width;
    int first_m = group * GM;
    int gsz = mtiles - first_m; if (gsz > GM) gsz = GM;
    int mt = first_m + (pid % width) % gsz;
    int nt = (pid % width) / gsz;
    const int m0 = mt * 128, n0 = nt * 64;

    A += (long)blockIdx.z * sA;
    W += (long)blockIdx.z * sW;

    const ushort* ga[4]; const ushort* gw[2];
#pragma unroll
    for (int i = 0; i < 4; ++i) {
        int s = i * 256 + t;
        int row = s >> 3;
        int kseg = (s & 7) ^ (row & 7);
        ga[i] = A + (long)(m0 + row) * lda + kseg * 8;
    }
#pragma unroll
    for (int i = 0; i < 2; ++i) {
        int s = i * 256 + t;
        int row = s >> 3;
        int kseg = (s & 7) ^ (row & 7);
        gw[i] = W + (long)(n0 + row) * ldw + kseg * 8;
    }

    f32x4 acc[4][2];
    f32x4 zero4 = {0.f, 0.f, 0.f, 0.f};
#pragma unroll
    for (int i = 0; i < 4; ++i) { acc[i][0] = zero4; acc[i][1] = zero4; }

    int arow8[4], arow7[4], brow8[2], brow7[2];
#pragma unroll
    for (int i = 0; i < 4; ++i) {
        int ar = wm * 64 + i * 16 + lm;
        arow8[i] = ar * 8; arow7[i] = ar & 7;
    }
#pragma unroll
    for (int i = 0; i < 2; ++i) {
        int br = wn * 32 + i * 16 + lm;
        brow8[i] = br * 8; brow7[i] = br & 7;
    }

    for (int k0 = 0; k0 < K; k0 += 64) {
#pragma unroll
        for (int i = 0; i < 4; ++i) {
            ASYNC_COPY16(ga[i], &As[(i * 256 + w * 64) * 8]);
            ga[i] += 64;
        }
#pragma unroll
        for (int i = 0; i < 2; ++i) {
            ASYNC_COPY16(gw[i], &Bs[(i * 256 + w * 64) * 8]);
            gw[i] += 64;
        }
        __syncthreads();
#pragma unroll
        for (int ks = 0; ks < 2; ++ks) {
            bf16x8 af[4], bfr[2];
#pragma unroll
            for (int i = 0; i < 4; ++i)
                af[i]  = *(const bf16x8*)&As[(arow8[i] + ((ks * 4 + quad) ^ arow7[i])) * 8];
#pragma unroll
            for (int i = 0; i < 2; ++i)
                bfr[i] = *(const bf16x8*)&Bs[(brow8[i] + ((ks * 4 + quad) ^ brow7[i])) * 8];
#pragma unroll
            for (int im = 0; im < 4; ++im)
#pragma unroll
                for (int in = 0; in < 2; ++in)
                    acc[im][in] = __builtin_amdgcn_mfma_f32_16x16x32_bf16(
                        af[im], bfr[in], acc[im][in], 0, 0, 0);
        }
        __syncthreads();
    }

    // ---- epilogue: LDS bounce -> coalesced full-line stores ----
    if (c_bf16) {
        ushort* C = (ushort*)Cout + (long)blockIdx.z * sC;
#pragma unroll
        for (int mi = 0; mi < 4; ++mi)
#pragma unroll
            for (int ni = 0; ni < 2; ++ni) {
                int c = wn * 32 + ni * 16 + lm;
#pragma unroll
                for (int i = 0; i < 4; ++i) {
                    int r = wm * 64 + mi * 16 + quad * 4 + i;
                    tu[r * 72 + c] = f2bf(acc[mi][ni][i]);
                }
            }
        __syncthreads();
        int r = t >> 1, cb = (t & 1) * 32;
        long rowbase = (long)(m0 + r) * ldc + n0 + cb;
#pragma unroll
        for (int q = 0; q < 4; ++q) {
            int gcol = n0 + cb + q * 8;
            if (gcol < N)
                *(bf16x8*)(C + rowbase + q * 8) =
                    *(const bf16x8*)&tu[r * 72 + cb + q * 8];
        }
    } else {
        float* C = (float*)Cout + (long)blockIdx.z * sC;
#pragma unroll
        for (int p = 0; p < 2; ++p) {
            if (wm == p) {
#pragma unroll
                for (int mi = 0; mi < 4; ++mi)
#pragma unroll
                    for (int i = 0; i < 4; ++i) {
                        int r = mi * 16 + quad * 4 + i;
                        float s = 1.f;
                        if (rowscale)
                            s = rsqrtf(rowscale[m0 + p * 64 + r] * (1.f / (float)DINNER) + EPSF);
#pragma unroll
                        for (int ni = 0; ni < 2; ++ni) {
                            int c = wn * 32 + ni * 16 + lm;
                            tf[r * 68 + c] = acc[mi][ni][i] * s;
                        }
                    }
            }
            __syncthreads();
            int r2 = t >> 2, cb = (t & 3) * 16;
            long gbase = (long)(m0 + p * 64 + r2) * ldc + n0 + cb;
#pragma unroll
            for (int q = 0; q < 4; ++q) {
                float4 v = *(const float4*)&tf[r2 * 68 + cb + q * 4];
                if (resid) {
                    float4 rv = *(const float4*)(resid + gbase + q * 4);
                    v.x += rv.x; v.y += rv.y; v.z += rv.z; v.w += rv.w;
                }
                *(float4*)(C + gbase + q * 4) = v;
            }
            __syncthreads();
        }
    }
}

// ============================================================
// Merged: vectorized conv+SiLU (8ch/thread, full 2304 ch via t<32
// double-duty) and dt-softplus + per-chunk cumsum.
// grid: [0,4096) conv | [4096,4608) acs.  Static LDS = 2 KB only.
// ============================================================
__device__ __forceinline__ void conv8_row(
    const ushort* __restrict__ zx, const float* __restrict__ cw,
    const float* __restrict__ cb, ushort* __restrict__ xBC_bf,
    int row, int l, int c)
{
    float4 cwv[8];
#pragma unroll
    for (int j = 0; j < 8; ++j) cwv[j] = *(const float4*)(cw + (c + j) * 4);
    float acc[8];
    {
        float4 b0 = *(const float4*)(cb + c);
        float4 b1 = *(const float4*)(cb + c + 4);
        acc[0] = b0.x; acc[1] = b0.y; acc[2] = b0.z; acc[3] = b0.w;
        acc[4] = b1.x; acc[5] = b1.y; acc[6] = b1.z; acc[7] = b1.w;
    }
#pragma unroll
    for (int k = 0; k < DCONV; ++k) {
        int ls = l + k - (DCONV - 1);
        if (ls >= 0) {
            const ushort* zr = zx + (long)(row + k - (DCONV - 1)) * DINP + DINNER + c;
            ushort4 a = *(const ushort4*)zr;
            ushort4 b = *(const ushort4*)(zr + 4);
            acc[0] += bf2f(a.x) * ((const float*)&cwv[0])[k];
            acc[1] += bf2f(a.y) * ((const float*)&cwv[1])[k];
            acc[2] += bf2f(a.z) * ((const float*)&cwv[2])[k];
            acc[3] += bf2f(a.w) * ((const float*)&cwv[3])[k];
            acc[4] += bf2f(b.x) * ((const float*)&cwv[4])[k];
            acc[5] += bf2f(b.y) * ((const float*)&cwv[5])[k];
            acc[6] += bf2f(b.z) * ((const float*)&cwv[6])[k];
            acc[7] += bf2f(b.w) * ((const float*)&cwv[7])[k];
        }
    }
    ushort o[8];
#pragma unroll
    for (int j = 0; j < 8; ++j)
        o[j] = f2bf(acc[j] / (1.f + __expf(-acc[j])));
    ushort* dst = xBC_bf + (long)row * CONVD + c;
    *(ushort4*)dst = *(ushort4*)&o[0];
    *(ushort4*)(dst + 4) = *(ushort4*)&o[4];
}

__global__ __launch_bounds__(256) void conv_acs_kernel(
    const ushort* __restrict__ zx, const float* __restrict__ cw,
    const float* __restrict__ cb, ushort* __restrict__ xBC_bf,
    const float* __restrict__ dt_bias, const float* __restrict__ A_log,
    float* __restrict__ dtv, float* __restrict__ Acs)
{
    int bid = blockIdx.x;
    int t = threadIdx.x;
    if (bid < NROWS) {
        // ---- conv: ch 0..2047 (all threads) + ch 2048..2303 (t<32) ----
        int row = bid;
        int l = row & (LSEQ - 1);
        conv8_row(zx, cw, cb, xBC_bf, row, l, t * 8);
        if (t < 32)
            conv8_row(zx, cw, cb, xBC_bf, row, l, 2048 + t * 8);
    } else {
        // ---- dt softplus + per-chunk cumsum ----
        __shared__ float buf[2 * CHUNK];
        int idx = bid - NROWS;
        int bc = idx >> 5, h = idx & 31;
        int l = t;
        int row = bc * CHUNK + l;
        float v = bf2f(zx[(long)row * DINP + (DINP - NHEADS) + h]) + dt_bias[h];
        float d = (v > 20.f) ? v : log1pf(__expf(v));
        dtv[row * NHEADS + h] = d;
        float a = -d * __expf(A_log[h]);
        buf[l] = a; __syncthreads();
        int src = 0;
        for (int off = 1; off < CHUNK; off <<= 1) {
            float vv = buf[src * CHUNK + l];
            if (l >= off) vv += buf[src * CHUNK + l - off];
            buf[(src ^ 1) * CHUNK + l] = vv;
            __syncthreads();
            src ^= 1;
        }
        Acs[(bc * NHEADS + h) * CHUNK + l] = buf[src * CHUNK + l];
    }
}

// ============================================================
// Bt[bc][n][l] = B[l][n] (K-contiguous operand, shared by all heads)
// grid (bc, half); reads conv'd xBC_bf (separate launch -> no race)
// ============================================================
__global__ __launch_bounds__(256) void prep_b_kernel(
    const ushort* __restrict__ xBC_bf, ushort* __restrict__ Bt)
{
    int bc = blockIdx.x, half = blockIdx.y;
    int t = threadIdx.x;
    int row0 = bc * CHUNK;
    __shared__ ushort tB[64 * TPAD];
    int src_c0 = DINNER + half * 64;
    for (int iter = 0; iter < 8; ++iter) {
        int l = iter * 32 + (t >> 3);
        int cc = (t & 7) * 8;
        ushort u[8];
        *(ushort4*)&u[0] = *(const ushort4*)(xBC_bf + (long)(row0 + l) * CONVD + src_c0 + cc);
        *(ushort4*)&u[4] = *(const ushort4*)(xBC_bf + (long)(row0 + l) * CONVD + src_c0 + cc + 4);
#pragma unroll
        for (int j = 0; j < 8; ++j) tB[(cc + j) * TPAD + l] = u[j];
    }
    __syncthreads();
    int r = t >> 2, seg = (t & 3) * 64;
    ushort* dst = Bt + ((long)bc * DSTATE + half * 64 + r) * CHUNK + seg;
    const ushort* s1 = &tB[r * TPAD + seg];
#pragma unroll
    for (int q = 0; q < 16; ++q)
        *(ushort4*)(dst + q * 4) = *(const ushort4*)(s1 + q * 4);
}

// ============================================================
// Chunk state via MFMA with in-LDS X transpose:
//   S_t[p][n] = sum_l exp(T-acs_l)*dt_l*X[l,p] * Bt[n][l]  -> bf16
// ============================================================
__global__ __launch_bounds__(256) void chunk_state_mfma_kernel(
    const ushort* __restrict__ xBC_bf, const ushort* __restrict__ Bt,
    const float* __restrict__ dtv, const float* __restrict__ acs,
    ushort* __restrict__ state)
{
    int bc = blockIdx.x, h = blockIdx.y;
    int t = threadIdx.x, lane = t & 63, w = t >> 6;
    int lm = lane & 15, quad = lane >> 4;
    int row0 = bc * CHUNK;
    __shared__ ushort xt[64 * TPAD];
    __shared__ float cl[CHUNK];
    {
        float a = acs[(bc * NHEADS + h) * CHUNK + t];
        float T = acs[(bc * NHEADS + h) * CHUNK + CHUNK - 1];
        cl[t] = __expf(T - a) * dtv[(row0 + t) * NHEADS + h];
    }
    __syncthreads();
    for (int iter = 0; iter < 8; ++iter) {
        int l = iter * 32 + (t >> 3);
        int cc = (t & 7) * 8;
        ushort u[8];
        *(ushort4*)&u[0] = *(const ushort4*)(xBC_bf + (long)(row0 + l) * CONVD + h * HEADDIM + cc);
        *(ushort4*)&u[4] = *(const ushort4*)(xBC_bf + (long)(row0 + l) * CONVD + h * HEADDIM + cc + 4);
        float sc = cl[l];
#pragma unroll
        for (int j = 0; j < 8; ++j)
            xt[(cc + j) * TPAD + l] = (ushort)tb(bf2f(u[j]) * sc);
    }
    __syncthreads();

    const ushort* Bb = Bt + (long)bc * DSTATE * CHUNK;
    f32x4 acc[4][2];
    f32x4 zero4 = {0.f, 0.f, 0.f, 0.f};
#pragma unroll
    for (int i = 0; i < 4; ++i) { acc[i][0] = zero4; acc[i][1] = zero4; }

    for (int kt = 0; kt < 8; ++kt) {
        int k = kt * 32 + quad * 8;
        bf16x8 af[4], bfr[2];
#pragma unroll
        for (int mi = 0; mi < 4; ++mi)
            af[mi] = *(const bf16x8*)&xt[(mi * 16 + lm) * TPAD + k];
#pragma unroll
        for (int nj = 0; nj < 2; ++nj)
            bfr[nj] = *(const bf16x8*)(Bb + (long)(w * 32 + nj * 16 + lm) * CHUNK + k);
#pragma unroll
        for (int mi = 0; mi < 4; ++mi)
#pragma unroll
            for (int nj = 0; nj < 2; ++nj)
                acc[mi][nj] = __builtin_amdgcn_mfma_f32_16x16x32_bf16(
                    af[mi], bfr[nj], acc[mi][nj], 0, 0, 0);
    }
    ushort* sp = state + (long)(bc * NHEADS + h) * (DSTATE * HEADDIM);
#pragma unroll
    for (int mi = 0; mi < 4; ++mi)
#pragma unroll
        for (int nj = 0; nj < 2; ++nj) {
            int n = w * 32 + nj * 16 + lm;
#pragma unroll
            for (int i = 0; i < 4; ++i) {
                int p = mi * 16 + quad * 4 + i;
                sp[p * DSTATE + n] = f2bf(acc[mi][nj][i]);
            }
        }
}

// ============================================================
// Inter-chunk scan (in place on bf16 states, fp32 accumulator)
// ============================================================
__global__ __launch_bounds__(256) void state_scan_kernel(
    ushort* __restrict__ state, const float* __restrict__ Acs)
{
    long flat = (long)blockIdx.x * 256 + threadIdx.x;
    int e = (int)(flat & 8191);
    int bh = (int)(flat >> 13);
    int b = bh >> 5, h = bh & 31;
    float S = 0.f;
    for (int c = 0; c < NCH; ++c) {
        int bc = b * NCH + c;
        long idx = ((long)(bc * NHEADS + h)) * 8192 + e;
        float T = Acs[(bc * NHEADS + h) * CHUNK + CHUNK - 1];
        float tmp = bf2f(state[idx]);
        state[idx] = f2bf(S);
        S = S * __expf(T) + tmp;
    }
}

// ============================================================
// SSD Y via MFMA (in-LDS Xdt transpose): Y = P@Xdt + (C*eAl)@S^T,
// then +D*xh, silu(z) gate, bf16 store + per-row ssq atomics.
// P-build uses factored exps: exp(al-a8[j]) = exp(al-base)*exp(base-a8[j])
// ============================================================
__global__ __launch_bounds__(256) void ssd_y_mfma_kernel(
    const ushort* __restrict__ xBC_bf, const ushort* __restrict__ G2b,
    const float* __restrict__ acs, const ushort* __restrict__ state,
    const ushort* __restrict__ zxb, const float* __restrict__ dtv,
    const float* __restrict__ Dh, ushort* __restrict__ ybf,
    float* __restrict__ ssq)
{
    int bc = blockIdx.x, h = blockIdx.y;
    int t = threadIdx.x, lane = t & 63, w = t >> 6;
    int lm = lane & 15, quad = lane >> 4;
    int row0 = bc * CHUNK;
    __shared__ ushort xt[64 * TPAD];
    __shared__ float acs_s[CHUNK];
    __shared__ float dl[CHUNK];
    acs_s[t] = acs[(bc * NHEADS + h) * CHUNK + t];
    dl[t] = dtv[(row0 + t) * NHEADS + h];
    __syncthreads();
    // transpose X chunk (dt-scaled) into LDS [p][l]
    for (int iter = 0; iter < 8; ++iter) {
        int l = iter * 32 + (t >> 3);
        int cc = (t & 7) * 8;
        ushort u[8];
        *(ushort4*)&u[0] = *(const ushort4*)(xBC_bf + (long)(row0 + l) * CONVD + h * HEADDIM + cc);
        *(ushort4*)&u[4] = *(const ushort4*)(xBC_bf + (long)(row0 + l) * CONVD + h * HEADDIM + cc + 4);
        float sd = dl[l];
#pragma unroll
        for (int j = 0; j < 8; ++j)
            xt[(cc + j) * TPAD + l] = (ushort)tb(bf2f(u[j]) * sd);
    }
    __syncthreads();

    int lbase = w * 64;
    float acs_l[4], eAl[4];
#pragma unroll
    for (int mi = 0; mi < 4; ++mi) {
        acs_l[mi] = acs_s[lbase + mi * 16 + lm];
        eAl[mi] = __expf(acs_l[mi]);
    }
    f32x4 acc[4][4];
    f32x4 zero4 = {0.f, 0.f, 0.f, 0.f};
#pragma unroll
    for (int i = 0; i < 4; ++i)
#pragma unroll
        for (int j = 0; j < 4; ++j) acc[i][j] = zero4;

    const ushort* g2 = G2b + (long)bc * (CHUNK * CHUNK);

    // ---- phase A: diagonal (causal), factored exps ----
    for (int ks = 0; ks <= 2 * w + 1; ++ks) {
        int sq = ks * 32 + quad * 8;
        bf16x8 bfr[4];
#pragma unroll
        for (int ni = 0; ni < 4; ++ni)
            bfr[ni] = *(const bf16x8*)&xt[(ni * 16 + lm) * TPAD + sq];
        float base = acs_s[sq];
        float e8[8];
        e8[0] = 1.f;
#pragma unroll
        for (int j = 1; j < 8; ++j)
            e8[j] = __expf(fminf(base - acs_s[sq + j], 80.f));
#pragma unroll
        for (int mi = 0; mi < 4; ++mi) {
            int lmin = lbase + mi * 16;
            if (ks * 32 > lmin + 15) continue;
            int lv = lmin + lm;
            float em = __expf(fminf(acs_l[mi] - base, 0.f));
            bf16x8 g8 = *(const bf16x8*)(g2 + (long)lv * CHUNK + sq);
            bf16x8 af;
#pragma unroll
            for (int j = 0; j < 8; ++j) {
                float v = bf2f((ushort)g8[j]) * (em * e8[j]);
                af[j] = (sq + j > lv) ? (short)0 : tb(v);
            }
#pragma unroll
            for (int ni = 0; ni < 4; ++ni)
                acc[mi][ni] = __builtin_amdgcn_mfma_f32_16x16x32_bf16(
                    af, bfr[ni], acc[mi][ni], 0, 0, 0);
        }
    }

    // ---- phase B: off-diagonal (C*eAl @ S^T), bf16 state loads ----
    const ushort* sp = state + (long)(bc * NHEADS + h) * (DSTATE * HEADDIM);
    const ushort* Cb = xBC_bf + (long)row0 * CONVD + DINNER + DSTATE;
    for (int kt = 0; kt < 4; ++kt) {
        int n0 = kt * 32 + quad * 8;
        bf16x8 bfr[4];
#pragma unroll
        for (int ni = 0; ni < 4; ++ni)
            bfr[ni] = *(const bf16x8*)(sp + (long)(ni * 16 + lm) * DSTATE + n0);
#pragma unroll
        for (int mi = 0; mi < 4; ++mi) {
            int lv = lbase + mi * 16 + lm;
            bf16x8 cu = *(const bf16x8*)(Cb + (long)lv * CONVD + n0);
            bf16x8 ce;
            float e = eAl[mi];
#pragma unroll
            for (int j = 0; j < 8; ++j) ce[j] = tb(bf2f((ushort)cu[j]) * e);
#pragma unroll
            for (int ni = 0; ni < 4; ++ni)
                acc[mi][ni] = __builtin_amdgcn_mfma_f32_16x16x32_bf16(
                    ce, bfr[ni], acc[mi][ni], 0, 0, 0);
        }
    }

    // ---- epilogue: +D*xh, silu(z) gate, bf16 store + ssq ----
    float Dv = Dh[h];
#pragma unroll
    for (int mi = 0; mi < 4; ++mi)
#pragma unroll
        for (int i = 0; i < 4; ++i) {
            int l = lbase + mi * 16 + quad * 4 + i;
            long row = row0 + l;
            float ps = 0.f;
#pragma unroll
            for (int ni = 0; ni < 4; ++ni) {
                int p = ni * 16 + lm;
                float xh = bf2f(xBC_bf[row * CONVD + h * HEADDIM + p]);
                float z = bf2f(zxb[row * DINP + h * HEADDIM + p]);
                float o = (acc[mi][ni][i] + Dv * xh) * (z / (1.f + __expf(-z)));
                ps += o * o;
                ybf[row * DINNER + h * HEADDIM + p] = f2bf(o);
            }
#pragma unroll
            for (int m = 1; m < 16; m <<= 1) ps += __shfl_xor(ps, m, 64);
            if (lm == 0) atomicAdd(&ssq[row], ps);
        }
}

// ============================================================
// launch
// ============================================================
extern "C" void kernel_launch(void* const* d_in, const int* in_sizes, int n_in,
                              void* d_out, int out_size, void* d_ws, size_t ws_size,
                              hipStream_t stream)
{
    (void)in_sizes; (void)n_in; (void)out_size; (void)ws_size;
    const float* x          = (const float*)d_in[0];
    const float* norm_w     = (const float*)d_in[1];
    const float* in_proj_w  = (const float*)d_in[2];
    const float* conv_w     = (const float*)d_in[3];
    const float* conv_b     = (const float*)d_in[4];
    const float* dt_bias    = (const float*)d_in[5];
    const float* A_log      = (const float*)d_in[6];
    const float* Dh         = (const float*)d_in[7];
    const float* gnorm_w    = (const float*)d_in[8];
    const float* out_proj_w = (const float*)d_in[9];
    float* out = (float*)d_out;
    float* ws = (float*)d_ws;

    // workspace layout (float slots); total ~90 MB
    float* zxb_f   = ws;                       //  8,978,432 (bf16 4096x4384)
    float* xbc_f   = zxb_f   + 8978432;        //  4,718,592 (bf16 4096x2304)
    float* dtv     = xbc_f   + 4718592;        //    131,072
    float* acs     = dtv     + 131072;         //    131,072
    float* g2_f    = acs     + 131072;         //    524,288 (bf16 [bc][l][s])
    float* state_f = g2_f    + 524288;         //  2,097,152 (bf16 [bc][h][p][n])
    float* bt_f    = state_f + 2097152;        //    262,144 (bf16 [bc][n][l])
    float* regU    = bt_f    + 262144;         //  4,390,912 (xn_bf+wi_bf, later ybf)
    float* wo_f    = regU    + 4390912;        //  1,048,576 (wo_bf)
    float* ssq     = wo_f    + 1048576;        //      4,096

    ushort* zxb_bf = (ushort*)zxb_f;
    ushort* xBC_bf = (ushort*)xbc_f;
    ushort* G2b    = (ushort*)g2_f;
    ushort* state  = (ushort*)state_f;
    ushort* Bt     = (ushort*)bt_f;
    ushort* xn_bf  = (ushort*)regU;                 // 4096x1024 [dead after in_proj]
    ushort* wi_bf  = (ushort*)(regU + 2097152);     // 4416x1024 [dead after in_proj]
    ushort* ybf    = (ushort*)regU;                 // 4096x2048 [born at ssd_y]
    ushort* wo_bf  = (ushort*)wo_f;

    // 0. prologue (wi cvt, wo'·gw cvt, rmsnorm, ssq=0)
    prologue_kernel<<<dim3(10576), 256, 0, stream>>>(
        x, norm_w, in_proj_w, out_proj_w, gnorm_w, xn_bf, wi_bf, wo_bf, ssq);

    // 1. zxbcdt = xn @ in_proj_w^T -> bf16 (M=4096, N=4384 pad 4416, K=1024)
    gemm_bf16_kernel<<<dim3(32 * 69), 256, 0, stream>>>(
        xn_bf, DMODEL, 0, wi_bf, DMODEL, 0,
        zxb_bf, DINP, 0, 1, nullptr, nullptr, 32, 69, DINP, DMODEL);

    // 2. conv(vec8, all 2304 ch) + dt-softplus+cumsum (2 KB LDS)
    conv_acs_kernel<<<dim3(NROWS + BB * NCH * NHEADS), 256, 0, stream>>>(
        zxb_bf, conv_w, conv_b, xBC_bf, dt_bias, A_log, dtv, acs);

    // 3. Bt (B^T operand, reads conv'd xBC)
    prep_b_kernel<<<dim3(BB * NCH, 2), 256, 0, stream>>>(xBC_bf, Bt);

    // 4. G2[bc][l][s] = C_l . B_s -> bf16 (batched; M=N=256, K=128)
    gemm_bf16_kernel<<<dim3(8, 1, BB * NCH), 256, 0, stream>>>(
        xBC_bf + DINNER + DSTATE, CONVD, (long)CHUNK * CONVD,
        xBC_bf + DINNER, CONVD, (long)CHUNK * CONVD,
        G2b, CHUNK, (long)CHUNK * CHUNK, 1, nullptr, nullptr, 2, 4, CHUNK, DSTATE);

    // 5. chunk states (MFMA, in-LDS transpose) -> bf16 state
    chunk_state_mfma_kernel<<<dim3(BB * NCH, NHEADS), 256, 0, stream>>>(
        xBC_bf, Bt, dtv, acs, state);

    // 6. inter-chunk scan (in place, bf16)
    state_scan_kernel<<<dim3(BB * NHEADS * 8192 / 256), 256, 0, stream>>>(state, acs);

    // 7. Y (MFMA diag+off) + D*xh, silu(z) gate -> ybf + ssq
    ssd_y_mfma_kernel<<<dim3(BB * NCH, NHEADS), 256, 0, stream>>>(
        xBC_bf, G2b, acs, state, zxb_bf, dtv, Dh, ybf, ssq);

    // 8. out = x + rsqrt(ssq/D+eps)*(y @ (gw·Wo)^T)  (fused gnorm)
    gemm_bf16_kernel<<<dim3(32 * 16), 256, 0, stream>>>(
        ybf, DINNER, 0, wo_bf, DINNER, 0,
        out, DMODEL, 0, 0, x, ssq, 32, 16, DMODEL, DINNER);
}